// Round 5
// baseline (718.900 us; speedup 1.0000x reference)
//
#include <hip/hip_runtime.h>
#include <math.h>

constexpr float INV_R   = 0.2f;                     // 1/R_MAX
constexpr float PI_F    = 3.14159265358979323846f;
constexpr float C0      = 0.632455532033675866f;    // sqrt(2/R_MAX)
constexpr float INV_AVG = 1.0f / 16.0f;             // 1/AVG_NEIGH

__device__ __forceinline__ float sigm(float x) { return 1.0f / (1.0f + __expf(-x)); }

// ef[n] = sqrt(2/R) * sin((n+1)*pi*u) / L * fc(u),  via Chebyshev recurrence
__device__ __forceinline__ void radial_ef(float u, float invL, float* ef) {
    float u2 = u * u, u4 = u2 * u2, u5 = u4 * u;
    float fc = 1.f - 21.f * u5 + 35.f * u5 * u - 15.f * u5 * u2;
    float sp, cp;
    sincosf(PI_F * u, &sp, &cp);
    float pref = C0 * invL * fc;
    float twoc = 2.f * cp;
    float s_nm1 = 0.f, s_n = sp;
    ef[0] = pref * s_n;
#pragma unroll
    for (int n = 2; n <= 8; n++) {
        float s_np = twoc * s_n - s_nm1;
        s_nm1 = s_n; s_n = s_np;
        ef[n - 1] = pref * s_n;
    }
}

// ef plus d(ef)/dL
__device__ __forceinline__ void radial_ef_d(float u, float invL, float* ef, float* dd) {
    float u2 = u * u, u4 = u2 * u2, u5 = u4 * u;
    float fc  = 1.f - 21.f * u5 + 35.f * u5 * u - 15.f * u5 * u2;
    float om  = 1.f - u;
    float fcp = -105.f * u4 * om * om;   // dfc/du
    float sp, cp;
    sincosf(PI_F * u, &sp, &cp);
    float twoc = 2.f * cp;
    float a = C0 * invL;
    float s_nm1 = 0.f, s_n = sp, c_nm1 = 1.f, c_n = cp;
#pragma unroll
    for (int n = 1; n <= 8; n++) {
        ef[n - 1] = a * s_n * fc;
        dd[n - 1] = a * fc * ((float)n * PI_F * INV_R * c_n - s_n * invL)
                  + a * s_n * fcp * INV_R;
        if (n < 8) {
            float sn2 = twoc * s_n - s_nm1; s_nm1 = s_n; s_n = sn2;
            float cn2 = twoc * c_n - c_nm1; c_nm1 = c_n; c_n = cn2;
        }
    }
}

__global__ __launch_bounds__(256) void k_embed(
    const float* __restrict__ attrs, const float* __restrict__ ae,
    const float* __restrict__ Wemb, float* __restrict__ h,
    float* __restrict__ e0, int N)
{
    int i = blockIdx.x * blockDim.x + threadIdx.x;
    if (i >= N) return;
    float a[10];
#pragma unroll
    for (int k = 0; k < 10; k++) a[k] = attrs[i * 10 + k];
    float e = 0.f;
#pragma unroll
    for (int k = 0; k < 10; k++) e += a[k] * ae[k];
    e0[i] = e;
#pragma unroll
    for (int c = 0; c < 32; c++) {
        float v = 0.f;
#pragma unroll
        for (int k = 0; k < 10; k++) v += a[k] * Wemb[k * 32 + c];
        h[i * 32 + c] = v;
    }
}

// pass 0: find active edges, histogram receivers and senders
__global__ __launch_bounds__(256) void k_build(
    const float* __restrict__ pos, const float* __restrict__ shifts,
    const int* __restrict__ ei, int E,
    int* __restrict__ ulist, int* __restrict__ cnt,
    int* __restrict__ hist_r, int* __restrict__ hist_s)
{
    int e = blockIdx.x * 256 + threadIdx.x;
    if (e >= E) return;
    int s = ei[e], r = ei[E + e];
    float vx = pos[3 * r + 0] - pos[3 * s + 0] + shifts[3 * e + 0];
    float vy = pos[3 * r + 1] - pos[3 * s + 1] + shifts[3 * e + 1];
    float vz = pos[3 * r + 2] - pos[3 * s + 2] + shifts[3 * e + 2];
    float ss2 = vx * vx + vy * vy + vz * vz;
    float L = sqrtf(fmaxf(ss2, 1e-12f));
    if (L * INV_R < 1.f) {
        ulist[atomicAdd(cnt, 1)] = e;    // wave-coalesced by compiler
        atomicAdd(&hist_r[r], 1);
        atomicAdd(&hist_s[s], 1);
    }
}

// exclusive prefix sums of both histograms -> cursor arrays (1 block each)
__global__ __launch_bounds__(1024) void k_scan(
    const int* __restrict__ hist_r, int* __restrict__ cur_r,
    const int* __restrict__ hist_s, int* __restrict__ cur_s, int n)
{
    const int* hist = blockIdx.x ? hist_s : hist_r;
    int*       cur  = blockIdx.x ? cur_s  : cur_r;
    __shared__ int part[1024];
    int tid = threadIdx.x;
    int per = (n + 1023) >> 10;
    int start = tid * per;
    int end = min(start + per, n);
    int sum = 0;
    for (int k = start; k < end; k++) sum += hist[k];
    part[tid] = sum;
    __syncthreads();
    for (int off = 1; off < 1024; off <<= 1) {
        int v = (tid >= off) ? part[tid - off] : 0;
        __syncthreads();
        part[tid] += v;
        __syncthreads();
    }
    int run = part[tid] - sum;           // exclusive base of this chunk
    for (int k = start; k < end; k++) { cur[k] = run; run += hist[k]; }
}

// scatter into receiver-sorted and sender-sorted lists
__global__ __launch_bounds__(256) void k_sort(
    const int* __restrict__ ei, int E,
    const int* __restrict__ ulist, const int* __restrict__ cnt,
    int* __restrict__ cur_r, int* __restrict__ cur_s,
    int* __restrict__ rlist, int* __restrict__ slist)
{
    int na = *cnt;
    int i = blockIdx.x * 256 + threadIdx.x;
    if (i >= na) return;
    int e = ulist[i];
    int s = ei[e], r = ei[E + e];
    rlist[atomicAdd(&cur_r[r], 1)] = e;
    slist[atomicAdd(&cur_s[s], 1)] = e;
}

// sorted-list edge MLP: tw = silu(ef@W1)@W2[:,:32]; acc[scatter] += feat[gather]*tw
// list sorted by the scatter key -> run-length pre-reduced coalesced atomics.
// swapdir=0: gather=sender, scatter=receiver; swapdir=1: reverse.
__global__ __launch_bounds__(256) void k_edge_mlp_s(
    const float* __restrict__ pos, const float* __restrict__ shifts,
    const int* __restrict__ ei, const float* __restrict__ W1,
    const float* __restrict__ W2, const float* __restrict__ feat,
    float* __restrict__ acc, int E,
    const int* __restrict__ list, const int* __restrict__ cnt, int swapdir)
{
    __shared__ float m_lds[256][33];
    __shared__ int   dst_lds[256];

    int na = *cnt;
    if ((int)(blockIdx.x * 256) >= na) return;
    int tid = threadIdx.x;
    int i = blockIdx.x * 256 + tid;
    int dst = -1;

    if (i < na) {
        int e = list[i];
        int s = ei[e], r = ei[E + e];
        float vx = pos[3 * r + 0] - pos[3 * s + 0] + shifts[3 * e + 0];
        float vy = pos[3 * r + 1] - pos[3 * s + 1] + shifts[3 * e + 1];
        float vz = pos[3 * r + 2] - pos[3 * s + 2] + shifts[3 * e + 2];
        float ss2 = vx * vx + vy * vy + vz * vz;
        float L = sqrtf(fmaxf(ss2, 1e-12f));
        float u = L * INV_R;
        float invL = 1.f / L;

        int gn = swapdir ? r : s;
        dst = swapdir ? s : r;
        // prefetch gather row early: latency hides under the j-loop
        const float4* fp = (const float4*)(feat + (size_t)gn * 32);
        float fbuf[32];
#pragma unroll
        for (int q = 0; q < 8; q++) {
            float4 v = fp[q];
            fbuf[4 * q + 0] = v.x; fbuf[4 * q + 1] = v.y;
            fbuf[4 * q + 2] = v.z; fbuf[4 * q + 3] = v.w;
        }

        float ef[8];
        radial_ef(u, invL, ef);

        float tw[32];
#pragma unroll
        for (int c = 0; c < 32; c++) tw[c] = 0.f;
        for (int j = 0; j < 64; j++) {
            float s1 = 0.f;
#pragma unroll
            for (int k = 0; k < 8; k++) s1 += ef[k] * W1[k * 64 + j];
            float act = s1 * sigm(s1);
            const float* w2 = W2 + j * 96;
#pragma unroll
            for (int c = 0; c < 32; c++) tw[c] += act * w2[c];
        }
#pragma unroll
        for (int c = 0; c < 32; c++) m_lds[tid][c] = fbuf[c] * tw[c];
    }
    dst_lds[tid] = dst;
    __syncthreads();

    // run-length pre-reduced channel-parallel atomics: lane c scans 32
    // sorted edges; equal-dst runs combine in-register before one atomic.
    int grp = tid >> 5;
    int c   = tid & 31;
    int base = grp * 32;
    int cur = -1; float run = 0.f;
    for (int k = 0; k < 32; k++) {
        int d = dst_lds[base + k];
        if (d != cur) {
            if (cur >= 0) unsafeAtomicAdd(&acc[(size_t)cur * 32 + c], run);
            cur = d;
            run = (d >= 0) ? m_lds[base + k][c] : 0.f;
        } else if (d >= 0) {
            run += m_lds[base + k][c];
        }
    }
    if (cur >= 0) unsafeAtomicAdd(&acc[(size_t)cur * 32 + c], run);
}

__global__ __launch_bounds__(256) void k_node1(
    const float* __restrict__ h, float* __restrict__ A1,
    const float* __restrict__ Wr1, float* __restrict__ e1, int N)
{
    int i = blockIdx.x * blockDim.x + threadIdx.x;
    if (i >= N) return;
    float dot = 0.f;
#pragma unroll
    for (int c = 0; c < 32; c++) {
        float v = A1[i * 32 + c] * INV_AVG + h[i * 32 + c];
        A1[i * 32 + c] = v;
        dot += v * Wr1[c];
    }
    e1[i] = dot;
}

__global__ __launch_bounds__(256) void k_node2(
    const float* __restrict__ A2acc, const float* __restrict__ A1,
    const float* __restrict__ Wm1, const float* __restrict__ Wm2,
    const float* __restrict__ e0, const float* __restrict__ e1,
    float* __restrict__ g2, float* __restrict__ node_e,
    float* __restrict__ total, const int* __restrict__ batch, int N)
{
    __shared__ float bins[32];
    if (threadIdx.x < 32) bins[threadIdx.x] = 0.f;
    __syncthreads();
    int i = blockIdx.x * blockDim.x + threadIdx.x;
    if (i < N) {
        float A2[32];
#pragma unroll
        for (int c = 0; c < 32; c++)
            A2[c] = A2acc[i * 32 + c] * INV_AVG + A1[i * 32 + c];
        float z[16];
#pragma unroll
        for (int k = 0; k < 16; k++) {
            float v = 0.f;
#pragma unroll
            for (int c = 0; c < 32; c++) v += A2[c] * Wm1[c * 16 + k];
            z[k] = v;
        }
        float e2 = 0.f;
        float wk[16];
#pragma unroll
        for (int k = 0; k < 16; k++) {
            float sg = sigm(z[k]);
            float m2 = Wm2[k];
            e2 += z[k] * sg * m2;
            wk[k] = m2 * sg * (1.f + z[k] * (1.f - sg));  // Wm2 * silu'(z)
        }
#pragma unroll
        for (int c = 0; c < 32; c++) {
            float v = 0.f;
#pragma unroll
            for (int k = 0; k < 16; k++) v += Wm1[c * 16 + k] * wk[k];
            g2[i * 32 + c] = v;
        }
        float ne = e0[i] + e1[i] + e2;
        node_e[i] = ne;
        atomicAdd(&bins[batch[i]], ne);
    }
    __syncthreads();
    if (threadIdx.x < 32) unsafeAtomicAdd(&total[threadIdx.x], bins[threadIdx.x]);
}

__global__ __launch_bounds__(256) void k_node3(
    float* __restrict__ g1, const float* __restrict__ g2,
    const float* __restrict__ Wr1, int N)
{
    int i = blockIdx.x * blockDim.x + threadIdx.x;
    if (i >= N) return;
#pragma unroll
    for (int c = 0; c < 32; c++)
        g1[i * 32 + c] = g1[i * 32 + c] * INV_AVG + g2[i * 32 + c] + Wr1[c];
}

// force kernel over receiver-sorted list: receiver gathers L1-hot,
// receiver atomics run-length pre-reduced; sender side random (unavoidable).
__global__ __launch_bounds__(256) void k_force_s(
    const float* __restrict__ pos, const float* __restrict__ shifts,
    const int* __restrict__ ei,
    const float* __restrict__ W1a, const float* __restrict__ W1b,
    const float* __restrict__ W2a, const float* __restrict__ W2b,
    const float* __restrict__ h, const float* __restrict__ A1,
    const float* __restrict__ g1, const float* __restrict__ g2,
    float* __restrict__ forces, int E,
    const int* __restrict__ rlist, const int* __restrict__ cnt)
{
    __shared__ float w2a_s[64 * 32];
    __shared__ float w2b_s[64 * 32];
    __shared__ float f_lds[256][4];
    __shared__ int   dst_lds[256];

    int na = *cnt;
    if ((int)(blockIdx.x * 256) >= na) return;
    int tid = threadIdx.x;
#pragma unroll
    for (int idx = tid; idx < 512; idx += 256) {
        int j = idx >> 3, q = idx & 7;
        *(float4*)(&w2a_s[j * 32 + q * 4]) = *(const float4*)(W2a + j * 96 + q * 4);
        *(float4*)(&w2b_s[j * 32 + q * 4]) = *(const float4*)(W2b + j * 96 + q * 4);
    }
    __syncthreads();

    int i = blockIdx.x * 256 + tid;
    int dstf = -1;
    float fx = 0.f, fy = 0.f, fz = 0.f;

    if (i < na) {
        int e = rlist[i];
        int s = ei[e], r = ei[E + e];
        float vx = pos[3 * r + 0] - pos[3 * s + 0] + shifts[3 * e + 0];
        float vy = pos[3 * r + 1] - pos[3 * s + 1] + shifts[3 * e + 1];
        float vz = pos[3 * r + 2] - pos[3 * s + 2] + shifts[3 * e + 2];
        float ss2 = vx * vx + vy * vy + vz * vz;
        if (ss2 > 1e-12f) {              // else grad of maximum() is 0
            float L = sqrtf(ss2);
            float u = L * INV_R;
            float invL = 1.f / L;

            // all gathers up front (float4); r-side rows shared across lanes
            const float4* pa = (const float4*)(g1 + (size_t)r * 32);
            const float4* pb = (const float4*)(h  + (size_t)s * 32);
            const float4* pc = (const float4*)(g2 + (size_t)r * 32);
            const float4* pd = (const float4*)(A1 + (size_t)s * 32);

            float dtw_a[32], dtw_b[32];
#pragma unroll
            for (int q = 0; q < 8; q++) {
                float4 x = pa[q], y = pb[q];
                dtw_a[4 * q + 0] = x.x * y.x; dtw_a[4 * q + 1] = x.y * y.y;
                dtw_a[4 * q + 2] = x.z * y.z; dtw_a[4 * q + 3] = x.w * y.w;
            }
#pragma unroll
            for (int q = 0; q < 8; q++) {
                float4 x = pc[q], y = pd[q];
                dtw_b[4 * q + 0] = x.x * y.x; dtw_b[4 * q + 1] = x.y * y.y;
                dtw_b[4 * q + 2] = x.z * y.z; dtw_b[4 * q + 3] = x.w * y.w;
            }

            float ef[8], dd[8], def[8];
            radial_ef_d(u, invL, ef, dd);
#pragma unroll
            for (int k = 0; k < 8; k++) def[k] = 0.f;

#pragma unroll 4
            for (int j = 0; j < 64; j++) {
                float s1 = 0.f;
#pragma unroll
                for (int k = 0; k < 8; k++) s1 += ef[k] * W1a[k * 64 + j];
                float da = 0.f;
                const float4* w2r = (const float4*)(&w2a_s[j * 32]);
#pragma unroll
                for (int q = 0; q < 8; q++) {
                    float4 wv = w2r[q];
                    da += wv.x * dtw_a[4 * q + 0] + wv.y * dtw_a[4 * q + 1]
                        + wv.z * dtw_a[4 * q + 2] + wv.w * dtw_a[4 * q + 3];
                }
                float sg = sigm(s1);
                float ds = sg * (1.f + s1 * (1.f - sg)) * da;   // silu'(s1)*da
#pragma unroll
                for (int k = 0; k < 8; k++) def[k] += W1a[k * 64 + j] * ds;
            }
#pragma unroll 4
            for (int j = 0; j < 64; j++) {
                float s1 = 0.f;
#pragma unroll
                for (int k = 0; k < 8; k++) s1 += ef[k] * W1b[k * 64 + j];
                float da = 0.f;
                const float4* w2r = (const float4*)(&w2b_s[j * 32]);
#pragma unroll
                for (int q = 0; q < 8; q++) {
                    float4 wv = w2r[q];
                    da += wv.x * dtw_b[4 * q + 0] + wv.y * dtw_b[4 * q + 1]
                        + wv.z * dtw_b[4 * q + 2] + wv.w * dtw_b[4 * q + 3];
                }
                float sg = sigm(s1);
                float ds = sg * (1.f + s1 * (1.f - sg)) * da;
#pragma unroll
                for (int k = 0; k < 8; k++) def[k] += W1b[k * 64 + j] * ds;
            }

            float dL = 0.f;
#pragma unroll
            for (int k = 0; k < 8; k++) dL += def[k] * dd[k];

            float sc = -INV_AVG * dL * invL;
            fx = sc * vx; fy = sc * vy; fz = sc * vz;
            dstf = r;
            // sender side: random, apply directly
            unsafeAtomicAdd(&forces[3 * s + 0], -fx);
            unsafeAtomicAdd(&forces[3 * s + 1], -fy);
            unsafeAtomicAdd(&forces[3 * s + 2], -fz);
        }
    }
    f_lds[tid][0] = fx; f_lds[tid][1] = fy; f_lds[tid][2] = fz;
    dst_lds[tid] = dstf;
    __syncthreads();

    // receiver side: run-length pre-reduced (list sorted by r)
    int grp = tid >> 5;
    int c   = tid & 31;
    if (c < 3) {
        int base = grp * 32;
        int cur = -1; float run = 0.f;
        for (int k = 0; k < 32; k++) {
            int d = dst_lds[base + k];
            if (d != cur) {
                if (cur >= 0) unsafeAtomicAdd(&forces[3 * cur + c], run);
                cur = d;
                run = (d >= 0) ? f_lds[base + k][c] : 0.f;
            } else if (d >= 0) {
                run += f_lds[base + k][c];
            }
        }
        if (cur >= 0) unsafeAtomicAdd(&forces[3 * cur + c], run);
    }
}

extern "C" void kernel_launch(void* const* d_in, const int* in_sizes, int n_in,
                              void* d_out, int out_size, void* d_ws, size_t ws_size,
                              hipStream_t stream)
{
    const float* pos    = (const float*)d_in[0];
    const float* attrs  = (const float*)d_in[1];
    const float* shifts = (const float*)d_in[2];
    const float* ae     = (const float*)d_in[3];
    const float* Wemb   = (const float*)d_in[4];
    const float* W1a    = (const float*)d_in[5];
    const float* W2a    = (const float*)d_in[6];
    const float* Wr1    = (const float*)d_in[7];
    const float* W1b    = (const float*)d_in[8];
    const float* W2b    = (const float*)d_in[9];
    const float* Wm1    = (const float*)d_in[10];
    const float* Wm2    = (const float*)d_in[11];
    const int*   ei     = (const int*)d_in[12];
    const int*   batch  = (const int*)d_in[13];

    int N = in_sizes[13];
    int E = in_sizes[12] / 2;

    float* out    = (float*)d_out;
    float* total  = out;                 // 32
    float* node_e = out + 32;            // N
    float* forces = out + 32 + N;        // 3N

    float* ws = (float*)d_ws;
    size_t NC = (size_t)N * 32;
    float* h  = ws;            // N*32
    float* A1 = h  + NC;       // N*32 : acc then A1_0 in place
    float* A2 = A1 + NC;       // N*32 : acc
    float* g2 = A2 + NC;       // N*32
    float* g1 = g2 + NC;       // N*32 : acc then final in place
    float* e0 = g1 + NC;       // N
    float* e1 = e0 + N;        // N
    int* ib     = (int*)(e1 + N);
    int* ulist  = ib;               // E
    int* rlist  = ulist + E;        // E
    int* slist  = rlist + E;        // E
    int* hist_r = slist + E;        // N
    int* hist_s = hist_r + N;       // N
    int* cur_r  = hist_s + N;       // N
    int* cur_s  = cur_r + N;        // N
    int* cnt    = cur_s + N;        // 1

    hipMemsetAsync(A1, 0, NC * sizeof(float), stream);
    hipMemsetAsync(A2, 0, NC * sizeof(float), stream);
    hipMemsetAsync(g1, 0, NC * sizeof(float), stream);
    hipMemsetAsync(total, 0, 32 * sizeof(float), stream);
    hipMemsetAsync(forces, 0, (size_t)N * 3 * sizeof(float), stream);
    hipMemsetAsync(hist_r, 0, (size_t)N * 2 * sizeof(int), stream);  // hist_r+hist_s
    hipMemsetAsync(cnt, 0, sizeof(int), stream);

    int nb_n = (N + 255) / 256;
    int nb_e = (E + 255) / 256;

    k_embed<<<nb_n, 256, 0, stream>>>(attrs, ae, Wemb, h, e0, N);
    k_build<<<nb_e, 256, 0, stream>>>(pos, shifts, ei, E, ulist, cnt, hist_r, hist_s);
    k_scan<<<2, 1024, 0, stream>>>(hist_r, cur_r, hist_s, cur_s, N);
    k_sort<<<nb_e, 256, 0, stream>>>(ei, E, ulist, cnt, cur_r, cur_s, rlist, slist);

    k_edge_mlp_s<<<nb_e, 256, 0, stream>>>(pos, shifts, ei, W1a, W2a, h, A1,
                                           E, rlist, cnt, 0);
    k_node1<<<nb_n, 256, 0, stream>>>(h, A1, Wr1, e1, N);
    k_edge_mlp_s<<<nb_e, 256, 0, stream>>>(pos, shifts, ei, W1b, W2b, A1, A2,
                                           E, rlist, cnt, 0);
    k_node2<<<nb_n, 256, 0, stream>>>(A2, A1, Wm1, Wm2, e0, e1, g2, node_e, total, batch, N);
    k_edge_mlp_s<<<nb_e, 256, 0, stream>>>(pos, shifts, ei, W1b, W2b, g2, g1,
                                           E, slist, cnt, 1);
    k_node3<<<nb_n, 256, 0, stream>>>(g1, g2, Wr1, N);
    k_force_s<<<nb_e, 256, 0, stream>>>(pos, shifts, ei, W1a, W1b, W2a, W2b,
                                        h, A1, g1, g2, forces, E, rlist, cnt);
}

// Round 6
// 681.063 us; speedup vs baseline: 1.0556x; 1.0556x over previous
//
#include <hip/hip_runtime.h>
#include <math.h>

constexpr float INV_R   = 0.2f;                     // 1/R_MAX
constexpr float PI_F    = 3.14159265358979323846f;
constexpr float C0      = 0.632455532033675866f;    // sqrt(2/R_MAX)
constexpr float INV_AVG = 1.0f / 16.0f;             // 1/AVG_NEIGH

__device__ __forceinline__ float sigm(float x) { return 1.0f / (1.0f + __expf(-x)); }

// ef[n] = sqrt(2/R) * sin((n+1)*pi*u) / L * fc(u),  via Chebyshev recurrence
__device__ __forceinline__ void radial_ef(float u, float invL, float* ef) {
    float u2 = u * u, u4 = u2 * u2, u5 = u4 * u;
    float fc = 1.f - 21.f * u5 + 35.f * u5 * u - 15.f * u5 * u2;
    float sp, cp;
    sincosf(PI_F * u, &sp, &cp);
    float pref = C0 * invL * fc;
    float twoc = 2.f * cp;
    float s_nm1 = 0.f, s_n = sp;
    ef[0] = pref * s_n;
#pragma unroll
    for (int n = 2; n <= 8; n++) {
        float s_np = twoc * s_n - s_nm1;
        s_nm1 = s_n; s_n = s_np;
        ef[n - 1] = pref * s_n;
    }
}

// ef plus d(ef)/dL
__device__ __forceinline__ void radial_ef_d(float u, float invL, float* ef, float* dd) {
    float u2 = u * u, u4 = u2 * u2, u5 = u4 * u;
    float fc  = 1.f - 21.f * u5 + 35.f * u5 * u - 15.f * u5 * u2;
    float om  = 1.f - u;
    float fcp = -105.f * u4 * om * om;   // dfc/du
    float sp, cp;
    sincosf(PI_F * u, &sp, &cp);
    float twoc = 2.f * cp;
    float a = C0 * invL;
    float s_nm1 = 0.f, s_n = sp, c_nm1 = 1.f, c_n = cp;
#pragma unroll
    for (int n = 1; n <= 8; n++) {
        ef[n - 1] = a * s_n * fc;
        dd[n - 1] = a * fc * ((float)n * PI_F * INV_R * c_n - s_n * invL)
                  + a * s_n * fcp * INV_R;
        if (n < 8) {
            float sn2 = twoc * s_n - s_nm1; s_nm1 = s_n; s_n = sn2;
            float cn2 = twoc * c_n - c_nm1; c_nm1 = c_n; c_n = cn2;
        }
    }
}

__global__ __launch_bounds__(256) void k_embed(
    const float* __restrict__ attrs, const float* __restrict__ ae,
    const float* __restrict__ Wemb, float* __restrict__ h,
    float* __restrict__ e0, int N)
{
    int i = blockIdx.x * blockDim.x + threadIdx.x;
    if (i >= N) return;
    float a[10];
#pragma unroll
    for (int k = 0; k < 10; k++) a[k] = attrs[i * 10 + k];
    float e = 0.f;
#pragma unroll
    for (int k = 0; k < 10; k++) e += a[k] * ae[k];
    e0[i] = e;
#pragma unroll
    for (int c = 0; c < 32; c++) {
        float v = 0.f;
#pragma unroll
        for (int k = 0; k < 10; k++) v += a[k] * Wemb[k * 32 + c];
        h[i * 32 + c] = v;
    }
}

// pass 0: count active edges, histogram receivers and senders
__global__ __launch_bounds__(256) void k_build(
    const float* __restrict__ pos, const float* __restrict__ shifts,
    const int* __restrict__ ei, int E,
    int* __restrict__ cnt, int* __restrict__ hist_r, int* __restrict__ hist_s)
{
    int e = blockIdx.x * 256 + threadIdx.x;
    if (e >= E) return;
    int s = ei[e], r = ei[E + e];
    float vx = pos[3 * r + 0] - pos[3 * s + 0] + shifts[3 * e + 0];
    float vy = pos[3 * r + 1] - pos[3 * s + 1] + shifts[3 * e + 1];
    float vz = pos[3 * r + 2] - pos[3 * s + 2] + shifts[3 * e + 2];
    float ss2 = vx * vx + vy * vy + vz * vz;
    float L = sqrtf(fmaxf(ss2, 1e-12f));
    if (L * INV_R < 1.f) {
        atomicAdd(cnt, 1);               // wave-coalesced by compiler
        atomicAdd(&hist_r[r], 1);
        atomicAdd(&hist_s[s], 1);
    }
}

// exclusive prefix sums of both histograms -> cursor arrays (1 block each)
__global__ __launch_bounds__(1024) void k_scan(
    const int* __restrict__ hist_r, int* __restrict__ cur_r,
    const int* __restrict__ hist_s, int* __restrict__ cur_s, int n)
{
    const int* hist = blockIdx.x ? hist_s : hist_r;
    int*       cur  = blockIdx.x ? cur_s  : cur_r;
    __shared__ int part[1024];
    int tid = threadIdx.x;
    int per = (n + 1023) >> 10;
    int start = tid * per;
    int end = min(start + per, n);
    int sum = 0;
    for (int k = start; k < end; k++) sum += hist[k];
    part[tid] = sum;
    __syncthreads();
    for (int off = 1; off < 1024; off <<= 1) {
        int v = (tid >= off) ? part[tid - off] : 0;
        __syncthreads();
        part[tid] += v;
        __syncthreads();
    }
    int run = part[tid] - sum;           // exclusive base of this chunk
    for (int k = start; k < end; k++) { cur[k] = run; run += hist[k]; }
}

// pass 0b: materialize sorted edge records. One float4 per record:
// {vx, vy, vz, pack16(gather<<16 | scatter)}. rrec sorted by receiver
// (gather=sender), srec sorted by sender (gather=receiver).
__global__ __launch_bounds__(256) void k_sort(
    const float* __restrict__ pos, const float* __restrict__ shifts,
    const int* __restrict__ ei, int E,
    int* __restrict__ cur_r, int* __restrict__ cur_s,
    float4* __restrict__ rrec, float4* __restrict__ srec)
{
    int e = blockIdx.x * 256 + threadIdx.x;
    if (e >= E) return;
    int s = ei[e], r = ei[E + e];
    float vx = pos[3 * r + 0] - pos[3 * s + 0] + shifts[3 * e + 0];
    float vy = pos[3 * r + 1] - pos[3 * s + 1] + shifts[3 * e + 1];
    float vz = pos[3 * r + 2] - pos[3 * s + 2] + shifts[3 * e + 2];
    float ss2 = vx * vx + vy * vy + vz * vz;
    float L = sqrtf(fmaxf(ss2, 1e-12f));
    if (L * INV_R >= 1.f) return;
    int rp = atomicAdd(&cur_r[r], 1);
    int sp = atomicAdd(&cur_s[s], 1);
    rrec[rp] = make_float4(vx, vy, vz,
                           __uint_as_float(((unsigned)s << 16) | (unsigned)r));
    srec[sp] = make_float4(vx, vy, vz,
                           __uint_as_float(((unsigned)r << 16) | (unsigned)s));
}

// record-driven edge MLP: tw = silu(ef@W1)@W2[:,:32];
// acc[scatter] += feat[gather]*tw. Records sorted by scatter key ->
// run-length pre-reduced coalesced atomics. All reads coalesced or L1-hot.
__global__ __launch_bounds__(256) void k_edge_mlp_rec(
    const float4* __restrict__ rec, const int* __restrict__ cnt,
    const float* __restrict__ W1, const float* __restrict__ W2,
    const float* __restrict__ feat, float* __restrict__ acc)
{
    __shared__ float m_lds[256][33];
    __shared__ int   dst_lds[256];

    int na = *cnt;
    int tid = threadIdx.x;
    int stride = gridDim.x * 256;

    for (int base = blockIdx.x * 256; base < na; base += stride) {
        int i = base + tid;
        int dst = -1;
        if (i < na) {
            float4 rv = rec[i];
            unsigned pk = __float_as_uint(rv.w);
            int gn = pk >> 16;
            dst = (int)(pk & 0xffffu);
            float ss2 = rv.x * rv.x + rv.y * rv.y + rv.z * rv.z;
            float L = sqrtf(fmaxf(ss2, 1e-12f));
            float u = L * INV_R;
            float invL = 1.f / L;

            // gather row early: latency hides under the j-loop
            const float4* fp = (const float4*)(feat + (size_t)gn * 32);
            float fbuf[32];
#pragma unroll
            for (int q = 0; q < 8; q++) {
                float4 v = fp[q];
                fbuf[4 * q + 0] = v.x; fbuf[4 * q + 1] = v.y;
                fbuf[4 * q + 2] = v.z; fbuf[4 * q + 3] = v.w;
            }

            float ef[8];
            radial_ef(u, invL, ef);

            float tw[32];
#pragma unroll
            for (int c = 0; c < 32; c++) tw[c] = 0.f;
            for (int j = 0; j < 64; j++) {
                float s1 = 0.f;
#pragma unroll
                for (int k = 0; k < 8; k++) s1 += ef[k] * W1[k * 64 + j];
                float act = s1 * sigm(s1);
                const float* w2 = W2 + j * 96;
#pragma unroll
                for (int c = 0; c < 32; c++) tw[c] += act * w2[c];
            }
#pragma unroll
            for (int c = 0; c < 32; c++) m_lds[tid][c] = fbuf[c] * tw[c];
        }
        dst_lds[tid] = dst;
        __syncthreads();

        // run-length pre-reduced channel-parallel atomics
        int grp = tid >> 5;
        int c   = tid & 31;
        int b32 = grp * 32;
        int cur = -1; float run = 0.f;
        for (int k = 0; k < 32; k++) {
            int d = dst_lds[b32 + k];
            if (d != cur) {
                if (cur >= 0) unsafeAtomicAdd(&acc[(size_t)cur * 32 + c], run);
                cur = d;
                run = (d >= 0) ? m_lds[b32 + k][c] : 0.f;
            } else if (d >= 0) {
                run += m_lds[b32 + k][c];
            }
        }
        if (cur >= 0) unsafeAtomicAdd(&acc[(size_t)cur * 32 + c], run);
        __syncthreads();
    }
}

__global__ __launch_bounds__(256) void k_node1(
    const float* __restrict__ h, float* __restrict__ A1,
    const float* __restrict__ Wr1, float* __restrict__ e1, int N)
{
    int i = blockIdx.x * blockDim.x + threadIdx.x;
    if (i >= N) return;
    float dot = 0.f;
#pragma unroll
    for (int c = 0; c < 32; c++) {
        float v = A1[i * 32 + c] * INV_AVG + h[i * 32 + c];
        A1[i * 32 + c] = v;
        dot += v * Wr1[c];
    }
    e1[i] = dot;
}

// A2 buffer is read, then overwritten in place with g2
__global__ __launch_bounds__(256) void k_node2(
    float* __restrict__ A2g2, const float* __restrict__ A1,
    const float* __restrict__ Wm1, const float* __restrict__ Wm2,
    const float* __restrict__ e0, const float* __restrict__ e1,
    float* __restrict__ node_e, float* __restrict__ total,
    const int* __restrict__ batch, int N)
{
    __shared__ float bins[32];
    if (threadIdx.x < 32) bins[threadIdx.x] = 0.f;
    __syncthreads();
    int i = blockIdx.x * blockDim.x + threadIdx.x;
    if (i < N) {
        float A2[32];
#pragma unroll
        for (int c = 0; c < 32; c++)
            A2[c] = A2g2[i * 32 + c] * INV_AVG + A1[i * 32 + c];
        float z[16];
#pragma unroll
        for (int k = 0; k < 16; k++) {
            float v = 0.f;
#pragma unroll
            for (int c = 0; c < 32; c++) v += A2[c] * Wm1[c * 16 + k];
            z[k] = v;
        }
        float e2 = 0.f;
        float wk[16];
#pragma unroll
        for (int k = 0; k < 16; k++) {
            float sg = sigm(z[k]);
            float m2 = Wm2[k];
            e2 += z[k] * sg * m2;
            wk[k] = m2 * sg * (1.f + z[k] * (1.f - sg));  // Wm2 * silu'(z)
        }
#pragma unroll
        for (int c = 0; c < 32; c++) {
            float v = 0.f;
#pragma unroll
            for (int k = 0; k < 16; k++) v += Wm1[c * 16 + k] * wk[k];
            A2g2[i * 32 + c] = v;                          // g2 in place
        }
        float ne = e0[i] + e1[i] + e2;
        node_e[i] = ne;
        atomicAdd(&bins[batch[i]], ne);
    }
    __syncthreads();
    if (threadIdx.x < 32) unsafeAtomicAdd(&total[threadIdx.x], bins[threadIdx.x]);
}

__global__ __launch_bounds__(256) void k_node3(
    float* __restrict__ g1, const float* __restrict__ g2,
    const float* __restrict__ Wr1, int N)
{
    int i = blockIdx.x * blockDim.x + threadIdx.x;
    if (i >= N) return;
#pragma unroll
    for (int c = 0; c < 32; c++)
        g1[i * 32 + c] = g1[i * 32 + c] * INV_AVG + g2[i * 32 + c] + Wr1[c];
}

// force over receiver-sorted records: receiver gathers L1-hot, receiver
// atomics run-length pre-reduced; sender side random (unavoidable).
__global__ __launch_bounds__(256) void k_force_rec(
    const float4* __restrict__ rec, const int* __restrict__ cnt,
    const float* __restrict__ W1a, const float* __restrict__ W1b,
    const float* __restrict__ W2a, const float* __restrict__ W2b,
    const float* __restrict__ h, const float* __restrict__ A1,
    const float* __restrict__ g1, const float* __restrict__ g2,
    float* __restrict__ forces)
{
    __shared__ float w2a_s[64 * 32];
    __shared__ float w2b_s[64 * 32];
    __shared__ float f_lds[256][4];
    __shared__ int   dst_lds[256];

    int na = *cnt;
    int tid = threadIdx.x;
#pragma unroll
    for (int idx = tid; idx < 512; idx += 256) {
        int j = idx >> 3, q = idx & 7;
        *(float4*)(&w2a_s[j * 32 + q * 4]) = *(const float4*)(W2a + j * 96 + q * 4);
        *(float4*)(&w2b_s[j * 32 + q * 4]) = *(const float4*)(W2b + j * 96 + q * 4);
    }
    __syncthreads();

    int stride = gridDim.x * 256;
    for (int base = blockIdx.x * 256; base < na; base += stride) {
        int i = base + tid;
        int dstf = -1;
        float fx = 0.f, fy = 0.f, fz = 0.f;

        if (i < na) {
            float4 rv = rec[i];
            unsigned pk = __float_as_uint(rv.w);
            int s = pk >> 16;
            int r = (int)(pk & 0xffffu);
            float vx = rv.x, vy = rv.y, vz = rv.z;
            float ss2 = vx * vx + vy * vy + vz * vz;
            if (ss2 > 1e-12f) {          // else grad of maximum() is 0
                float L = sqrtf(ss2);
                float u = L * INV_R;
                float invL = 1.f / L;

                const float4* pa = (const float4*)(g1 + (size_t)r * 32);
                const float4* pb = (const float4*)(h  + (size_t)s * 32);
                const float4* pc = (const float4*)(g2 + (size_t)r * 32);
                const float4* pd = (const float4*)(A1 + (size_t)s * 32);

                float dtw_a[32], dtw_b[32];
#pragma unroll
                for (int q = 0; q < 8; q++) {
                    float4 x = pa[q], y = pb[q];
                    dtw_a[4 * q + 0] = x.x * y.x; dtw_a[4 * q + 1] = x.y * y.y;
                    dtw_a[4 * q + 2] = x.z * y.z; dtw_a[4 * q + 3] = x.w * y.w;
                }
#pragma unroll
                for (int q = 0; q < 8; q++) {
                    float4 x = pc[q], y = pd[q];
                    dtw_b[4 * q + 0] = x.x * y.x; dtw_b[4 * q + 1] = x.y * y.y;
                    dtw_b[4 * q + 2] = x.z * y.z; dtw_b[4 * q + 3] = x.w * y.w;
                }

                float ef[8], dd[8], def[8];
                radial_ef_d(u, invL, ef, dd);
#pragma unroll
                for (int k = 0; k < 8; k++) def[k] = 0.f;

#pragma unroll 4
                for (int j = 0; j < 64; j++) {
                    float s1 = 0.f;
#pragma unroll
                    for (int k = 0; k < 8; k++) s1 += ef[k] * W1a[k * 64 + j];
                    float da = 0.f;
                    const float4* w2r = (const float4*)(&w2a_s[j * 32]);
#pragma unroll
                    for (int q = 0; q < 8; q++) {
                        float4 wv = w2r[q];
                        da += wv.x * dtw_a[4 * q + 0] + wv.y * dtw_a[4 * q + 1]
                            + wv.z * dtw_a[4 * q + 2] + wv.w * dtw_a[4 * q + 3];
                    }
                    float sg = sigm(s1);
                    float ds = sg * (1.f + s1 * (1.f - sg)) * da;
#pragma unroll
                    for (int k = 0; k < 8; k++) def[k] += W1a[k * 64 + j] * ds;
                }
#pragma unroll 4
                for (int j = 0; j < 64; j++) {
                    float s1 = 0.f;
#pragma unroll
                    for (int k = 0; k < 8; k++) s1 += ef[k] * W1b[k * 64 + j];
                    float da = 0.f;
                    const float4* w2r = (const float4*)(&w2b_s[j * 32]);
#pragma unroll
                    for (int q = 0; q < 8; q++) {
                        float4 wv = w2r[q];
                        da += wv.x * dtw_b[4 * q + 0] + wv.y * dtw_b[4 * q + 1]
                            + wv.z * dtw_b[4 * q + 2] + wv.w * dtw_b[4 * q + 3];
                    }
                    float sg = sigm(s1);
                    float ds = sg * (1.f + s1 * (1.f - sg)) * da;
#pragma unroll
                    for (int k = 0; k < 8; k++) def[k] += W1b[k * 64 + j] * ds;
                }

                float dL = 0.f;
#pragma unroll
                for (int k = 0; k < 8; k++) dL += def[k] * dd[k];

                float sc = -INV_AVG * dL * invL;
                fx = sc * vx; fy = sc * vy; fz = sc * vz;
                dstf = r;
                // sender side: random, apply directly
                unsafeAtomicAdd(&forces[3 * s + 0], -fx);
                unsafeAtomicAdd(&forces[3 * s + 1], -fy);
                unsafeAtomicAdd(&forces[3 * s + 2], -fz);
            }
        }
        f_lds[tid][0] = fx; f_lds[tid][1] = fy; f_lds[tid][2] = fz;
        dst_lds[tid] = dstf;
        __syncthreads();

        // receiver side: run-length pre-reduced (records sorted by r)
        int grp = tid >> 5;
        int c   = tid & 31;
        if (c < 3) {
            int b32 = grp * 32;
            int cur = -1; float run = 0.f;
            for (int k = 0; k < 32; k++) {
                int d = dst_lds[b32 + k];
                if (d != cur) {
                    if (cur >= 0) unsafeAtomicAdd(&forces[3 * cur + c], run);
                    cur = d;
                    run = (d >= 0) ? f_lds[b32 + k][c] : 0.f;
                } else if (d >= 0) {
                    run += f_lds[b32 + k][c];
                }
            }
            if (cur >= 0) unsafeAtomicAdd(&forces[3 * cur + c], run);
        }
        __syncthreads();
    }
}

extern "C" void kernel_launch(void* const* d_in, const int* in_sizes, int n_in,
                              void* d_out, int out_size, void* d_ws, size_t ws_size,
                              hipStream_t stream)
{
    const float* pos    = (const float*)d_in[0];
    const float* attrs  = (const float*)d_in[1];
    const float* shifts = (const float*)d_in[2];
    const float* ae     = (const float*)d_in[3];
    const float* Wemb   = (const float*)d_in[4];
    const float* W1a    = (const float*)d_in[5];
    const float* W2a    = (const float*)d_in[6];
    const float* Wr1    = (const float*)d_in[7];
    const float* W1b    = (const float*)d_in[8];
    const float* W2b    = (const float*)d_in[9];
    const float* Wm1    = (const float*)d_in[10];
    const float* Wm2    = (const float*)d_in[11];
    const int*   ei     = (const int*)d_in[12];
    const int*   batch  = (const int*)d_in[13];

    int N = in_sizes[13];
    int E = in_sizes[12] / 2;

    float* out    = (float*)d_out;
    float* total  = out;                 // 32
    float* node_e = out + 32;            // N
    float* forces = out + 32 + N;        // 3N

    float* ws = (float*)d_ws;
    size_t NC = (size_t)N * 32;
    float* h    = ws;            // N*32
    float* A1   = h  + NC;       // N*32 : acc then A1_0 in place
    float* A2g2 = A1 + NC;       // N*32 : A2 acc, then g2 in place
    float* g1   = A2g2 + NC;     // N*32 : acc then final in place
    float* e0   = g1 + NC;       // N
    float* e1   = e0 + N;        // N
    int* hist_r = (int*)(e1 + N);   // N
    int* hist_s = hist_r + N;       // N
    int* cur_r  = hist_s + N;       // N
    int* cur_s  = cur_r + N;        // N
    int* cnt    = cur_s + N;        // 1
    // align records to 16 B
    size_t ioff = ((size_t)(cnt + 1 - (int*)ws) + 3) & ~(size_t)3;
    float4* rrec = (float4*)(ws + ioff);   // E float4
    float4* srec = rrec + E;               // E float4

    hipMemsetAsync(A1, 0, NC * sizeof(float), stream);
    hipMemsetAsync(A2g2, 0, NC * sizeof(float), stream);
    hipMemsetAsync(g1, 0, NC * sizeof(float), stream);
    hipMemsetAsync(total, 0, 32 * sizeof(float), stream);
    hipMemsetAsync(forces, 0, (size_t)N * 3 * sizeof(float), stream);
    hipMemsetAsync(hist_r, 0, (size_t)N * 2 * sizeof(int), stream);
    hipMemsetAsync(cnt, 0, sizeof(int), stream);

    int nb_n = (N + 255) / 256;
    int nb_e = (E + 255) / 256;
    int nb_g = nb_e < 2048 ? nb_e : 2048;   // grid-stride for edge passes

    k_embed<<<nb_n, 256, 0, stream>>>(attrs, ae, Wemb, h, e0, N);
    k_build<<<nb_e, 256, 0, stream>>>(pos, shifts, ei, E, cnt, hist_r, hist_s);
    k_scan<<<2, 1024, 0, stream>>>(hist_r, cur_r, hist_s, cur_s, N);
    k_sort<<<nb_e, 256, 0, stream>>>(pos, shifts, ei, E, cur_r, cur_s, rrec, srec);

    k_edge_mlp_rec<<<nb_g, 256, 0, stream>>>(rrec, cnt, W1a, W2a, h, A1);
    k_node1<<<nb_n, 256, 0, stream>>>(h, A1, Wr1, e1, N);
    k_edge_mlp_rec<<<nb_g, 256, 0, stream>>>(rrec, cnt, W1b, W2b, A1, A2g2);
    k_node2<<<nb_n, 256, 0, stream>>>(A2g2, A1, Wm1, Wm2, e0, e1, node_e, total, batch, N);
    k_edge_mlp_rec<<<nb_g, 256, 0, stream>>>(srec, cnt, W1b, W2b, A2g2, g1);
    k_node3<<<nb_n, 256, 0, stream>>>(g1, A2g2, Wr1, N);
    k_force_rec<<<nb_g, 256, 0, stream>>>(rrec, cnt, W1a, W1b, W2a, W2b,
                                          h, A1, g1, A2g2, forces);
}

// Round 7
// 596.584 us; speedup vs baseline: 1.2050x; 1.1416x over previous
//
#include <hip/hip_runtime.h>
#include <math.h>

constexpr float R_MAX   = 5.0f;
constexpr float INV_R   = 0.2f;                     // 1/R_MAX
constexpr float PI_F    = 3.14159265358979323846f;
constexpr float C0      = 0.632455532033675866f;    // sqrt(2/R_MAX)
constexpr float INV_AVG = 1.0f / 16.0f;             // 1/AVG_NEIGH
constexpr int   TBL     = 4096;                     // table resolution

__device__ __forceinline__ float sigm(float x) { return 1.0f / (1.0f + __expf(-x)); }

// ef plus d(ef)/dL (exact, used only in the table-build kernel)
__device__ __forceinline__ void radial_ef_d(float u, float invL, float* ef, float* dd) {
    float u2 = u * u, u4 = u2 * u2, u5 = u4 * u;
    float fc  = 1.f - 21.f * u5 + 35.f * u5 * u - 15.f * u5 * u2;
    float om  = 1.f - u;
    float fcp = -105.f * u4 * om * om;   // dfc/du
    float sp, cp;
    sincosf(PI_F * u, &sp, &cp);
    float twoc = 2.f * cp;
    float a = C0 * invL;
    float s_nm1 = 0.f, s_n = sp, c_nm1 = 1.f, c_n = cp;
#pragma unroll
    for (int n = 1; n <= 8; n++) {
        ef[n - 1] = a * s_n * fc;
        dd[n - 1] = a * fc * ((float)n * PI_F * INV_R * c_n - s_n * invL)
                  + a * s_n * fcp * INV_R;
        if (n < 8) {
            float sn2 = twoc * s_n - s_nm1; s_nm1 = s_n; s_n = sn2;
            float cn2 = twoc * c_n - c_nm1; c_nm1 = c_n; c_n = cn2;
        }
    }
}

// Build tw(u) and d tw/du tables for both layers. tw = silu(ef@W1)@W2[:,:32].
__global__ __launch_bounds__(256) void k_table(
    const float* __restrict__ W1a, const float* __restrict__ W2a,
    const float* __restrict__ W1b, const float* __restrict__ W2b,
    float* __restrict__ twa, float* __restrict__ dta,
    float* __restrict__ twb, float* __restrict__ dtb)
{
    int t = blockIdx.x * 256 + threadIdx.x;
    if (t > TBL) return;
    float u = fmaxf((float)t / (float)TBL, 1e-4f);  // clamp avoids 0/0 at t=0
    float L = u * R_MAX;
    float invL = 1.f / L;
    float ef[8], dd[8], efu[8];
    radial_ef_d(u, invL, ef, dd);
#pragma unroll
    for (int k = 0; k < 8; k++) efu[k] = dd[k] * R_MAX;   // d ef/du

#pragma unroll
    for (int l = 0; l < 2; l++) {
        const float* W1 = l ? W1b : W1a;
        const float* W2 = l ? W2b : W2a;
        float*       tw_o = l ? twb : twa;
        float*       dt_o = l ? dtb : dta;
        float tw[32], dt[32];
#pragma unroll
        for (int c = 0; c < 32; c++) { tw[c] = 0.f; dt[c] = 0.f; }
        for (int j = 0; j < 64; j++) {
            float s1 = 0.f, du = 0.f;
#pragma unroll
            for (int k = 0; k < 8; k++) {
                float w = W1[k * 64 + j];
                s1 += ef[k] * w; du += efu[k] * w;
            }
            float sg  = sigm(s1);
            float act = s1 * sg;
            float dj  = sg * (1.f + s1 * (1.f - sg)) * du;  // silu'(s1)*ds1/du
            const float* w2 = W2 + j * 96;
#pragma unroll
            for (int c = 0; c < 32; c++) {
                tw[c] += act * w2[c];
                dt[c] += dj * w2[c];
            }
        }
#pragma unroll
        for (int c = 0; c < 32; c++) {
            tw_o[(size_t)t * 32 + c] = tw[c];
            dt_o[(size_t)t * 32 + c] = dt[c];
        }
    }
}

__global__ __launch_bounds__(256) void k_embed(
    const float* __restrict__ attrs, const float* __restrict__ ae,
    const float* __restrict__ Wemb, float* __restrict__ h,
    float* __restrict__ e0, int N)
{
    int i = blockIdx.x * blockDim.x + threadIdx.x;
    if (i >= N) return;
    float a[10];
#pragma unroll
    for (int k = 0; k < 10; k++) a[k] = attrs[i * 10 + k];
    float e = 0.f;
#pragma unroll
    for (int k = 0; k < 10; k++) e += a[k] * ae[k];
    e0[i] = e;
#pragma unroll
    for (int c = 0; c < 32; c++) {
        float v = 0.f;
#pragma unroll
        for (int k = 0; k < 10; k++) v += a[k] * Wemb[k * 32 + c];
        h[i * 32 + c] = v;
    }
}

// pass 0: count active edges, histogram receivers and senders
__global__ __launch_bounds__(256) void k_build(
    const float* __restrict__ pos, const float* __restrict__ shifts,
    const int* __restrict__ ei, int E,
    int* __restrict__ cnt, int* __restrict__ hist_r, int* __restrict__ hist_s)
{
    int e = blockIdx.x * 256 + threadIdx.x;
    if (e >= E) return;
    int s = ei[e], r = ei[E + e];
    float vx = pos[3 * r + 0] - pos[3 * s + 0] + shifts[3 * e + 0];
    float vy = pos[3 * r + 1] - pos[3 * s + 1] + shifts[3 * e + 1];
    float vz = pos[3 * r + 2] - pos[3 * s + 2] + shifts[3 * e + 2];
    float ss2 = vx * vx + vy * vy + vz * vz;
    float L = sqrtf(fmaxf(ss2, 1e-12f));
    if (L * INV_R < 1.f) {
        atomicAdd(cnt, 1);               // wave-coalesced by compiler
        atomicAdd(&hist_r[r], 1);
        atomicAdd(&hist_s[s], 1);
    }
}

// exclusive prefix sums of both histograms -> cursor arrays (1 block each)
__global__ __launch_bounds__(1024) void k_scan(
    const int* __restrict__ hist_r, int* __restrict__ cur_r,
    const int* __restrict__ hist_s, int* __restrict__ cur_s, int n)
{
    const int* hist = blockIdx.x ? hist_s : hist_r;
    int*       cur  = blockIdx.x ? cur_s  : cur_r;
    __shared__ int part[1024];
    int tid = threadIdx.x;
    int per = (n + 1023) >> 10;
    int start = tid * per;
    int end = min(start + per, n);
    int sum = 0;
    for (int k = start; k < end; k++) sum += hist[k];
    part[tid] = sum;
    __syncthreads();
    for (int off = 1; off < 1024; off <<= 1) {
        int v = (tid >= off) ? part[tid - off] : 0;
        __syncthreads();
        part[tid] += v;
        __syncthreads();
    }
    int run = part[tid] - sum;           // exclusive base of this chunk
    for (int k = start; k < end; k++) { cur[k] = run; run += hist[k]; }
}

// pass 0b: materialize sorted edge records {vx,vy,vz, pack(other<<16|own)}.
// rrec sorted by receiver (own=r, other=s); srec sorted by sender (own=s).
__global__ __launch_bounds__(256) void k_sort(
    const float* __restrict__ pos, const float* __restrict__ shifts,
    const int* __restrict__ ei, int E,
    int* __restrict__ cur_r, int* __restrict__ cur_s,
    float4* __restrict__ rrec, float4* __restrict__ srec)
{
    int e = blockIdx.x * 256 + threadIdx.x;
    if (e >= E) return;
    int s = ei[e], r = ei[E + e];
    float vx = pos[3 * r + 0] - pos[3 * s + 0] + shifts[3 * e + 0];
    float vy = pos[3 * r + 1] - pos[3 * s + 1] + shifts[3 * e + 1];
    float vz = pos[3 * r + 2] - pos[3 * s + 2] + shifts[3 * e + 2];
    float ss2 = vx * vx + vy * vy + vz * vz;
    float L = sqrtf(fmaxf(ss2, 1e-12f));
    if (L * INV_R >= 1.f) return;
    int rp = atomicAdd(&cur_r[r], 1);
    int sp = atomicAdd(&cur_s[s], 1);
    rrec[rp] = make_float4(vx, vy, vz,
                           __uint_as_float(((unsigned)s << 16) | (unsigned)r));
    srec[sp] = make_float4(vx, vy, vz,
                           __uint_as_float(((unsigned)r << 16) | (unsigned)s));
}

// table-driven edge MLP: m = feat[gather] * lerp(tw_tbl, u);
// records sorted by scatter key -> run-length pre-reduced coalesced atomics.
__global__ __launch_bounds__(256) void k_edge_mlp_t(
    const float4* __restrict__ rec, const int* __restrict__ cnt,
    const float* __restrict__ tw_tbl, const float* __restrict__ feat,
    float* __restrict__ acc)
{
    __shared__ float m_lds[256][33];
    __shared__ int   dst_lds[256];

    int na = *cnt;
    int tid = threadIdx.x;
    int stride = gridDim.x * 256;

    for (int base = blockIdx.x * 256; base < na; base += stride) {
        int i = base + tid;
        int dst = -1;
        if (i < na) {
            float4 rv = rec[i];
            unsigned pk = __float_as_uint(rv.w);
            int gn = pk >> 16;
            dst = (int)(pk & 0xffffu);
            float ss2 = rv.x * rv.x + rv.y * rv.y + rv.z * rv.z;
            float L = sqrtf(fmaxf(ss2, 1e-12f));
            float x = fminf(L * (INV_R * (float)TBL), (float)TBL - 1e-3f);
            int   i0 = (int)x;
            float f  = x - (float)i0;

            const float4* r0 = (const float4*)(tw_tbl + (size_t)i0 * 32);
            const float4* r1 = r0 + 8;
            const float4* fp = (const float4*)(feat + (size_t)gn * 32);
#pragma unroll
            for (int q = 0; q < 8; q++) {
                float4 a = r0[q], b = r1[q], fv = fp[q];
                m_lds[tid][4 * q + 0] = fv.x * (a.x + f * (b.x - a.x));
                m_lds[tid][4 * q + 1] = fv.y * (a.y + f * (b.y - a.y));
                m_lds[tid][4 * q + 2] = fv.z * (a.z + f * (b.z - a.z));
                m_lds[tid][4 * q + 3] = fv.w * (a.w + f * (b.w - a.w));
            }
        }
        dst_lds[tid] = dst;
        __syncthreads();

        // run-length pre-reduced channel-parallel atomics
        int grp = tid >> 5;
        int c   = tid & 31;
        int b32 = grp * 32;
        int cur = -1; float run = 0.f;
        for (int k = 0; k < 32; k++) {
            int d = dst_lds[b32 + k];
            if (d != cur) {
                if (cur >= 0) unsafeAtomicAdd(&acc[(size_t)cur * 32 + c], run);
                cur = d;
                run = (d >= 0) ? m_lds[b32 + k][c] : 0.f;
            } else if (d >= 0) {
                run += m_lds[b32 + k][c];
            }
        }
        if (cur >= 0) unsafeAtomicAdd(&acc[(size_t)cur * 32 + c], run);
        __syncthreads();
    }
}

__global__ __launch_bounds__(256) void k_node1(
    const float* __restrict__ h, float* __restrict__ A1,
    const float* __restrict__ Wr1, float* __restrict__ e1, int N)
{
    int i = blockIdx.x * blockDim.x + threadIdx.x;
    if (i >= N) return;
    float dot = 0.f;
#pragma unroll
    for (int c = 0; c < 32; c++) {
        float v = A1[i * 32 + c] * INV_AVG + h[i * 32 + c];
        A1[i * 32 + c] = v;
        dot += v * Wr1[c];
    }
    e1[i] = dot;
}

// A2 buffer is read, then overwritten in place with g2
__global__ __launch_bounds__(256) void k_node2(
    float* __restrict__ A2g2, const float* __restrict__ A1,
    const float* __restrict__ Wm1, const float* __restrict__ Wm2,
    const float* __restrict__ e0, const float* __restrict__ e1,
    float* __restrict__ node_e, float* __restrict__ total,
    const int* __restrict__ batch, int N)
{
    __shared__ float bins[32];
    if (threadIdx.x < 32) bins[threadIdx.x] = 0.f;
    __syncthreads();
    int i = blockIdx.x * blockDim.x + threadIdx.x;
    if (i < N) {
        float A2[32];
#pragma unroll
        for (int c = 0; c < 32; c++)
            A2[c] = A2g2[i * 32 + c] * INV_AVG + A1[i * 32 + c];
        float z[16];
#pragma unroll
        for (int k = 0; k < 16; k++) {
            float v = 0.f;
#pragma unroll
            for (int c = 0; c < 32; c++) v += A2[c] * Wm1[c * 16 + k];
            z[k] = v;
        }
        float e2 = 0.f;
        float wk[16];
#pragma unroll
        for (int k = 0; k < 16; k++) {
            float sg = sigm(z[k]);
            float m2 = Wm2[k];
            e2 += z[k] * sg * m2;
            wk[k] = m2 * sg * (1.f + z[k] * (1.f - sg));  // Wm2 * silu'(z)
        }
#pragma unroll
        for (int c = 0; c < 32; c++) {
            float v = 0.f;
#pragma unroll
            for (int k = 0; k < 16; k++) v += Wm1[c * 16 + k] * wk[k];
            A2g2[i * 32 + c] = v;                          // g2 in place
        }
        float ne = e0[i] + e1[i] + e2;
        node_e[i] = ne;
        atomicAdd(&bins[batch[i]], ne);
    }
    __syncthreads();
    if (threadIdx.x < 32) unsafeAtomicAdd(&total[threadIdx.x], bins[threadIdx.x]);
}

__global__ __launch_bounds__(256) void k_node3(
    float* __restrict__ g1, const float* __restrict__ g2,
    const float* __restrict__ Wr1, int N)
{
    int i = blockIdx.x * blockDim.x + threadIdx.x;
    if (i >= N) return;
#pragma unroll
    for (int c = 0; c < 32; c++)
        g1[i * 32 + c] = g1[i * 32 + c] * INV_AVG + g2[i * 32 + c] + Wr1[c];
}

// table-driven force, one scatter side per launch:
// recv_side=1: rec=rrec (own=r), apply +f to receivers (pre-reduced)
// recv_side=0: rec=srec (own=s), apply -f to senders   (pre-reduced)
__global__ __launch_bounds__(256) void k_force_t(
    const float4* __restrict__ rec, const int* __restrict__ cnt,
    const float* __restrict__ dta, const float* __restrict__ dtb,
    const float* __restrict__ h, const float* __restrict__ A1,
    const float* __restrict__ g1, const float* __restrict__ g2,
    float* __restrict__ forces, int recv_side)
{
    __shared__ float f_lds[256][4];
    __shared__ int   dst_lds[256];

    int na = *cnt;
    int tid = threadIdx.x;
    int stride = gridDim.x * 256;

    for (int base = blockIdx.x * 256; base < na; base += stride) {
        int i = base + tid;
        int dstf = -1;
        float fx = 0.f, fy = 0.f, fz = 0.f;

        if (i < na) {
            float4 rv = rec[i];
            unsigned pk = __float_as_uint(rv.w);
            int own   = (int)(pk & 0xffffu);
            int other = (int)(pk >> 16);
            int r = recv_side ? own : other;
            int s = recv_side ? other : own;
            float vx = rv.x, vy = rv.y, vz = rv.z;
            float ss2 = vx * vx + vy * vy + vz * vz;
            if (ss2 > 1e-12f) {          // else grad of maximum() is 0
                float L = sqrtf(ss2);
                float invL = 1.f / L;
                float x = fminf(L * (INV_R * (float)TBL), (float)TBL - 1e-3f);
                int   i0 = (int)x;
                float f  = x - (float)i0;

                const float4* a0 = (const float4*)(dta + (size_t)i0 * 32);
                const float4* a1 = a0 + 8;
                const float4* b0 = (const float4*)(dtb + (size_t)i0 * 32);
                const float4* b1 = b0 + 8;
                const float4* pa = (const float4*)(g1 + (size_t)r * 32);
                const float4* pb = (const float4*)(h  + (size_t)s * 32);
                const float4* pc = (const float4*)(g2 + (size_t)r * 32);
                const float4* pd = (const float4*)(A1 + (size_t)s * 32);

                float dot = 0.f;
#pragma unroll
                for (int q = 0; q < 8; q++) {
                    float4 xg = pa[q], yg = pb[q], t0 = a0[q], t1 = a1[q];
                    dot += xg.x * yg.x * (t0.x + f * (t1.x - t0.x))
                         + xg.y * yg.y * (t0.y + f * (t1.y - t0.y))
                         + xg.z * yg.z * (t0.z + f * (t1.z - t0.z))
                         + xg.w * yg.w * (t0.w + f * (t1.w - t0.w));
                }
#pragma unroll
                for (int q = 0; q < 8; q++) {
                    float4 xg = pc[q], yg = pd[q], t0 = b0[q], t1 = b1[q];
                    dot += xg.x * yg.x * (t0.x + f * (t1.x - t0.x))
                         + xg.y * yg.y * (t0.y + f * (t1.y - t0.y))
                         + xg.z * yg.z * (t0.z + f * (t1.z - t0.z))
                         + xg.w * yg.w * (t0.w + f * (t1.w - t0.w));
                }

                float dLdl = INV_AVG * INV_R * dot;        // dE/dL
                float sc = (recv_side ? -1.f : 1.f) * dLdl * invL;
                fx = sc * vx; fy = sc * vy; fz = sc * vz;
                dstf = own;
            }
        }
        f_lds[tid][0] = fx; f_lds[tid][1] = fy; f_lds[tid][2] = fz;
        dst_lds[tid] = dstf;
        __syncthreads();

        // run-length pre-reduced scatter (records sorted by own)
        int grp = tid >> 5;
        int c   = tid & 31;
        if (c < 3) {
            int b32 = grp * 32;
            int cur = -1; float run = 0.f;
            for (int k = 0; k < 32; k++) {
                int d = dst_lds[b32 + k];
                if (d != cur) {
                    if (cur >= 0) unsafeAtomicAdd(&forces[3 * cur + c], run);
                    cur = d;
                    run = (d >= 0) ? f_lds[b32 + k][c] : 0.f;
                } else if (d >= 0) {
                    run += f_lds[b32 + k][c];
                }
            }
            if (cur >= 0) unsafeAtomicAdd(&forces[3 * cur + c], run);
        }
        __syncthreads();
    }
}

extern "C" void kernel_launch(void* const* d_in, const int* in_sizes, int n_in,
                              void* d_out, int out_size, void* d_ws, size_t ws_size,
                              hipStream_t stream)
{
    const float* pos    = (const float*)d_in[0];
    const float* attrs  = (const float*)d_in[1];
    const float* shifts = (const float*)d_in[2];
    const float* ae     = (const float*)d_in[3];
    const float* Wemb   = (const float*)d_in[4];
    const float* W1a    = (const float*)d_in[5];
    const float* W2a    = (const float*)d_in[6];
    const float* Wr1    = (const float*)d_in[7];
    const float* W1b    = (const float*)d_in[8];
    const float* W2b    = (const float*)d_in[9];
    const float* Wm1    = (const float*)d_in[10];
    const float* Wm2    = (const float*)d_in[11];
    const int*   ei     = (const int*)d_in[12];
    const int*   batch  = (const int*)d_in[13];

    int N = in_sizes[13];
    int E = in_sizes[12] / 2;

    float* out    = (float*)d_out;
    float* total  = out;                 // 32
    float* node_e = out + 32;            // N
    float* forces = out + 32 + N;        // 3N

    float* ws = (float*)d_ws;
    size_t NC = (size_t)N * 32;
    float* h    = ws;            // N*32
    float* A1   = h  + NC;       // N*32 : acc then A1_0 in place
    float* A2g2 = A1 + NC;       // N*32 : A2 acc, then g2 in place
    float* g1   = A2g2 + NC;     // N*32 : acc then final in place
    float* e0   = g1 + NC;       // N
    float* e1   = e0 + N;        // N
    int* hist_r = (int*)(e1 + N);   // N
    int* hist_s = hist_r + N;       // N
    int* cur_r  = hist_s + N;       // N
    int* cur_s  = cur_r + N;        // N
    int* cnt    = cur_s + N;        // 1
    // align records to 16 B
    size_t ioff = ((size_t)(cnt + 1 - (int*)ws) + 3) & ~(size_t)3;
    float4* rrec = (float4*)(ws + ioff);   // E float4
    float4* srec = rrec + E;               // E float4
    float* tbl  = (float*)(srec + E);      // 4 tables of (TBL+1)*32
    size_t tstride = (size_t)(TBL + 1) * 32;
    float* twa = tbl;
    float* dta = twa + tstride;
    float* twb = dta + tstride;
    float* dtb = twb + tstride;

    hipMemsetAsync(A1, 0, NC * sizeof(float), stream);
    hipMemsetAsync(A2g2, 0, NC * sizeof(float), stream);
    hipMemsetAsync(g1, 0, NC * sizeof(float), stream);
    hipMemsetAsync(total, 0, 32 * sizeof(float), stream);
    hipMemsetAsync(forces, 0, (size_t)N * 3 * sizeof(float), stream);
    hipMemsetAsync(hist_r, 0, (size_t)N * 2 * sizeof(int), stream);
    hipMemsetAsync(cnt, 0, sizeof(int), stream);

    int nb_n = (N + 255) / 256;
    int nb_e = (E + 255) / 256;
    int nb_g = nb_e < 2048 ? nb_e : 2048;   // grid-stride for edge passes
    int nb_t = (TBL + 1 + 255) / 256;

    k_table<<<nb_t, 256, 0, stream>>>(W1a, W2a, W1b, W2b, twa, dta, twb, dtb);
    k_embed<<<nb_n, 256, 0, stream>>>(attrs, ae, Wemb, h, e0, N);
    k_build<<<nb_e, 256, 0, stream>>>(pos, shifts, ei, E, cnt, hist_r, hist_s);
    k_scan<<<2, 1024, 0, stream>>>(hist_r, cur_r, hist_s, cur_s, N);
    k_sort<<<nb_e, 256, 0, stream>>>(pos, shifts, ei, E, cur_r, cur_s, rrec, srec);

    k_edge_mlp_t<<<nb_g, 256, 0, stream>>>(rrec, cnt, twa, h, A1);
    k_node1<<<nb_n, 256, 0, stream>>>(h, A1, Wr1, e1, N);
    k_edge_mlp_t<<<nb_g, 256, 0, stream>>>(rrec, cnt, twb, A1, A2g2);
    k_node2<<<nb_n, 256, 0, stream>>>(A2g2, A1, Wm1, Wm2, e0, e1, node_e, total, batch, N);
    k_edge_mlp_t<<<nb_g, 256, 0, stream>>>(srec, cnt, twb, A2g2, g1);
    k_node3<<<nb_n, 256, 0, stream>>>(g1, A2g2, Wr1, N);
    k_force_t<<<nb_g, 256, 0, stream>>>(rrec, cnt, dta, dtb, h, A1, g1, A2g2,
                                        forces, 1);
    k_force_t<<<nb_g, 256, 0, stream>>>(srec, cnt, dta, dtb, h, A1, g1, A2g2,
                                        forces, 0);
}

// Round 8
// 502.496 us; speedup vs baseline: 1.4307x; 1.1872x over previous
//
#include <hip/hip_runtime.h>
#include <math.h>

constexpr float R_MAX   = 5.0f;
constexpr float INV_R   = 0.2f;                     // 1/R_MAX
constexpr float PI_F    = 3.14159265358979323846f;
constexpr float C0      = 0.632455532033675866f;    // sqrt(2/R_MAX)
constexpr float INV_AVG = 1.0f / 16.0f;             // 1/AVG_NEIGH
constexpr int   TBL     = 4096;                     // table resolution

__device__ __forceinline__ float sigm(float x) { return 1.0f / (1.0f + __expf(-x)); }

// ef plus d(ef)/dL (exact, used only in the table-build kernel)
__device__ __forceinline__ void radial_ef_d(float u, float invL, float* ef, float* dd) {
    float u2 = u * u, u4 = u2 * u2, u5 = u4 * u;
    float fc  = 1.f - 21.f * u5 + 35.f * u5 * u - 15.f * u5 * u2;
    float om  = 1.f - u;
    float fcp = -105.f * u4 * om * om;   // dfc/du
    float sp, cp;
    sincosf(PI_F * u, &sp, &cp);
    float twoc = 2.f * cp;
    float a = C0 * invL;
    float s_nm1 = 0.f, s_n = sp, c_nm1 = 1.f, c_n = cp;
#pragma unroll
    for (int n = 1; n <= 8; n++) {
        ef[n - 1] = a * s_n * fc;
        dd[n - 1] = a * fc * ((float)n * PI_F * INV_R * c_n - s_n * invL)
                  + a * s_n * fcp * INV_R;
        if (n < 8) {
            float sn2 = twoc * s_n - s_nm1; s_nm1 = s_n; s_n = sn2;
            float cn2 = twoc * c_n - c_nm1; c_nm1 = c_n; c_n = cn2;
        }
    }
}

// Build tw(u) and d tw/du tables for both layers. tw = silu(ef@W1)@W2[:,:32].
__global__ __launch_bounds__(256) void k_table(
    const float* __restrict__ W1a, const float* __restrict__ W2a,
    const float* __restrict__ W1b, const float* __restrict__ W2b,
    float* __restrict__ twa, float* __restrict__ dta,
    float* __restrict__ twb, float* __restrict__ dtb)
{
    int t = blockIdx.x * 256 + threadIdx.x;
    if (t > TBL) return;
    float u = fmaxf((float)t / (float)TBL, 1e-4f);  // clamp avoids 0/0 at t=0
    float L = u * R_MAX;
    float invL = 1.f / L;
    float ef[8], dd[8], efu[8];
    radial_ef_d(u, invL, ef, dd);
#pragma unroll
    for (int k = 0; k < 8; k++) efu[k] = dd[k] * R_MAX;   // d ef/du

#pragma unroll
    for (int l = 0; l < 2; l++) {
        const float* W1 = l ? W1b : W1a;
        const float* W2 = l ? W2b : W2a;
        float*       tw_o = l ? twb : twa;
        float*       dt_o = l ? dtb : dta;
        float tw[32], dt[32];
#pragma unroll
        for (int c = 0; c < 32; c++) { tw[c] = 0.f; dt[c] = 0.f; }
        for (int j = 0; j < 64; j++) {
            float s1 = 0.f, du = 0.f;
#pragma unroll
            for (int k = 0; k < 8; k++) {
                float w = W1[k * 64 + j];
                s1 += ef[k] * w; du += efu[k] * w;
            }
            float sg  = sigm(s1);
            float act = s1 * sg;
            float dj  = sg * (1.f + s1 * (1.f - sg)) * du;  // silu'(s1)*ds1/du
            const float* w2 = W2 + j * 96;
#pragma unroll
            for (int c = 0; c < 32; c++) {
                tw[c] += act * w2[c];
                dt[c] += dj * w2[c];
            }
        }
#pragma unroll
        for (int c = 0; c < 32; c++) {
            tw_o[(size_t)t * 32 + c] = tw[c];
            dt_o[(size_t)t * 32 + c] = dt[c];
        }
    }
}

__global__ __launch_bounds__(256) void k_embed(
    const float* __restrict__ attrs, const float* __restrict__ ae,
    const float* __restrict__ Wemb, float* __restrict__ h,
    float* __restrict__ e0, int N)
{
    int i = blockIdx.x * blockDim.x + threadIdx.x;
    if (i >= N) return;
    float a[10];
#pragma unroll
    for (int k = 0; k < 10; k++) a[k] = attrs[i * 10 + k];
    float e = 0.f;
#pragma unroll
    for (int k = 0; k < 10; k++) e += a[k] * ae[k];
    e0[i] = e;
#pragma unroll
    for (int c = 0; c < 32; c++) {
        float v = 0.f;
#pragma unroll
        for (int k = 0; k < 10; k++) v += a[k] * Wemb[k * 32 + c];
        h[i * 32 + c] = v;
    }
}

// pass 0: histogram active-edge receivers and senders.
// NOTE: no single-address counter here — a same-address atomicAdd from every
// wave serializes at the L2 point (~15-20ns each => ~125us). Total count is
// derived in k_scan from the histogram instead.
__global__ __launch_bounds__(256) void k_build(
    const float* __restrict__ pos, const float* __restrict__ shifts,
    const int* __restrict__ ei, int E,
    int* __restrict__ hist_r, int* __restrict__ hist_s)
{
    int e = blockIdx.x * 256 + threadIdx.x;
    if (e >= E) return;
    int s = ei[e], r = ei[E + e];
    float vx = pos[3 * r + 0] - pos[3 * s + 0] + shifts[3 * e + 0];
    float vy = pos[3 * r + 1] - pos[3 * s + 1] + shifts[3 * e + 1];
    float vz = pos[3 * r + 2] - pos[3 * s + 2] + shifts[3 * e + 2];
    float ss2 = vx * vx + vy * vy + vz * vz;
    float L = sqrtf(fmaxf(ss2, 1e-12f));
    if (L * INV_R < 1.f) {
        atomicAdd(&hist_r[r], 1);
        atomicAdd(&hist_s[s], 1);
    }
}

// exclusive prefix sums of both histograms -> cursor arrays (1 block each).
// Block 0 additionally writes the total active count to cnt.
__global__ __launch_bounds__(1024) void k_scan(
    const int* __restrict__ hist_r, int* __restrict__ cur_r,
    const int* __restrict__ hist_s, int* __restrict__ cur_s, int n,
    int* __restrict__ cnt)
{
    const int* hist = blockIdx.x ? hist_s : hist_r;
    int*       cur  = blockIdx.x ? cur_s  : cur_r;
    __shared__ int part[1024];
    int tid = threadIdx.x;
    int per = (n + 1023) >> 10;
    int start = tid * per;
    int end = min(start + per, n);
    int sum = 0;
    for (int k = start; k < end; k++) sum += hist[k];
    part[tid] = sum;
    __syncthreads();
    for (int off = 1; off < 1024; off <<= 1) {
        int v = (tid >= off) ? part[tid - off] : 0;
        __syncthreads();
        part[tid] += v;
        __syncthreads();
    }
    if (blockIdx.x == 0 && tid == 1023) *cnt = part[1023];  // total active
    int run = part[tid] - sum;           // exclusive base of this chunk
    for (int k = start; k < end; k++) { cur[k] = run; run += hist[k]; }
}

// pass 0b: materialize sorted edge records {vx,vy,vz, pack(other<<16|own)}.
// rrec sorted by receiver (own=r, other=s); srec sorted by sender (own=s).
__global__ __launch_bounds__(256) void k_sort(
    const float* __restrict__ pos, const float* __restrict__ shifts,
    const int* __restrict__ ei, int E,
    int* __restrict__ cur_r, int* __restrict__ cur_s,
    float4* __restrict__ rrec, float4* __restrict__ srec)
{
    int e = blockIdx.x * 256 + threadIdx.x;
    if (e >= E) return;
    int s = ei[e], r = ei[E + e];
    float vx = pos[3 * r + 0] - pos[3 * s + 0] + shifts[3 * e + 0];
    float vy = pos[3 * r + 1] - pos[3 * s + 1] + shifts[3 * e + 1];
    float vz = pos[3 * r + 2] - pos[3 * s + 2] + shifts[3 * e + 2];
    float ss2 = vx * vx + vy * vy + vz * vz;
    float L = sqrtf(fmaxf(ss2, 1e-12f));
    if (L * INV_R >= 1.f) return;
    int rp = atomicAdd(&cur_r[r], 1);
    int sp = atomicAdd(&cur_s[s], 1);
    rrec[rp] = make_float4(vx, vy, vz,
                           __uint_as_float(((unsigned)s << 16) | (unsigned)r));
    srec[sp] = make_float4(vx, vy, vz,
                           __uint_as_float(((unsigned)r << 16) | (unsigned)s));
}

// table-driven edge MLP: m = feat[gather] * lerp(tw_tbl, u);
// records sorted by scatter key -> run-length pre-reduced coalesced atomics.
__global__ __launch_bounds__(256) void k_edge_mlp_t(
    const float4* __restrict__ rec, const int* __restrict__ cnt,
    const float* __restrict__ tw_tbl, const float* __restrict__ feat,
    float* __restrict__ acc)
{
    __shared__ float m_lds[256][33];
    __shared__ int   dst_lds[256];

    int na = *cnt;
    int tid = threadIdx.x;
    int stride = gridDim.x * 256;

    for (int base = blockIdx.x * 256; base < na; base += stride) {
        int i = base + tid;
        int dst = -1;
        if (i < na) {
            float4 rv = rec[i];
            unsigned pk = __float_as_uint(rv.w);
            int gn = pk >> 16;
            dst = (int)(pk & 0xffffu);
            float ss2 = rv.x * rv.x + rv.y * rv.y + rv.z * rv.z;
            float L = sqrtf(fmaxf(ss2, 1e-12f));
            float x = fminf(L * (INV_R * (float)TBL), (float)TBL - 1e-3f);
            int   i0 = (int)x;
            float f  = x - (float)i0;

            const float4* r0 = (const float4*)(tw_tbl + (size_t)i0 * 32);
            const float4* r1 = r0 + 8;
            const float4* fp = (const float4*)(feat + (size_t)gn * 32);
#pragma unroll
            for (int q = 0; q < 8; q++) {
                float4 a = r0[q], b = r1[q], fv = fp[q];
                m_lds[tid][4 * q + 0] = fv.x * (a.x + f * (b.x - a.x));
                m_lds[tid][4 * q + 1] = fv.y * (a.y + f * (b.y - a.y));
                m_lds[tid][4 * q + 2] = fv.z * (a.z + f * (b.z - a.z));
                m_lds[tid][4 * q + 3] = fv.w * (a.w + f * (b.w - a.w));
            }
        }
        dst_lds[tid] = dst;
        __syncthreads();

        // run-length pre-reduced channel-parallel atomics
        int grp = tid >> 5;
        int c   = tid & 31;
        int b32 = grp * 32;
        int cur = -1; float run = 0.f;
        for (int k = 0; k < 32; k++) {
            int d = dst_lds[b32 + k];
            if (d != cur) {
                if (cur >= 0) unsafeAtomicAdd(&acc[(size_t)cur * 32 + c], run);
                cur = d;
                run = (d >= 0) ? m_lds[b32 + k][c] : 0.f;
            } else if (d >= 0) {
                run += m_lds[b32 + k][c];
            }
        }
        if (cur >= 0) unsafeAtomicAdd(&acc[(size_t)cur * 32 + c], run);
        __syncthreads();
    }
}

__global__ __launch_bounds__(256) void k_node1(
    const float* __restrict__ h, float* __restrict__ A1,
    const float* __restrict__ Wr1, float* __restrict__ e1, int N)
{
    int i = blockIdx.x * blockDim.x + threadIdx.x;
    if (i >= N) return;
    float dot = 0.f;
#pragma unroll
    for (int c = 0; c < 32; c++) {
        float v = A1[i * 32 + c] * INV_AVG + h[i * 32 + c];
        A1[i * 32 + c] = v;
        dot += v * Wr1[c];
    }
    e1[i] = dot;
}

// A2 buffer is read, then overwritten in place with g2
__global__ __launch_bounds__(256) void k_node2(
    float* __restrict__ A2g2, const float* __restrict__ A1,
    const float* __restrict__ Wm1, const float* __restrict__ Wm2,
    const float* __restrict__ e0, const float* __restrict__ e1,
    float* __restrict__ node_e, float* __restrict__ total,
    const int* __restrict__ batch, int N)
{
    __shared__ float bins[32];
    if (threadIdx.x < 32) bins[threadIdx.x] = 0.f;
    __syncthreads();
    int i = blockIdx.x * blockDim.x + threadIdx.x;
    if (i < N) {
        float A2[32];
#pragma unroll
        for (int c = 0; c < 32; c++)
            A2[c] = A2g2[i * 32 + c] * INV_AVG + A1[i * 32 + c];
        float z[16];
#pragma unroll
        for (int k = 0; k < 16; k++) {
            float v = 0.f;
#pragma unroll
            for (int c = 0; c < 32; c++) v += A2[c] * Wm1[c * 16 + k];
            z[k] = v;
        }
        float e2 = 0.f;
        float wk[16];
#pragma unroll
        for (int k = 0; k < 16; k++) {
            float sg = sigm(z[k]);
            float m2 = Wm2[k];
            e2 += z[k] * sg * m2;
            wk[k] = m2 * sg * (1.f + z[k] * (1.f - sg));  // Wm2 * silu'(z)
        }
#pragma unroll
        for (int c = 0; c < 32; c++) {
            float v = 0.f;
#pragma unroll
            for (int k = 0; k < 16; k++) v += Wm1[c * 16 + k] * wk[k];
            A2g2[i * 32 + c] = v;                          // g2 in place
        }
        float ne = e0[i] + e1[i] + e2;
        node_e[i] = ne;
        atomicAdd(&bins[batch[i]], ne);
    }
    __syncthreads();
    if (threadIdx.x < 32) unsafeAtomicAdd(&total[threadIdx.x], bins[threadIdx.x]);
}

__global__ __launch_bounds__(256) void k_node3(
    float* __restrict__ g1, const float* __restrict__ g2,
    const float* __restrict__ Wr1, int N)
{
    int i = blockIdx.x * blockDim.x + threadIdx.x;
    if (i >= N) return;
#pragma unroll
    for (int c = 0; c < 32; c++)
        g1[i * 32 + c] = g1[i * 32 + c] * INV_AVG + g2[i * 32 + c] + Wr1[c];
}

// table-driven force, one scatter side per launch:
// recv_side=1: rec=rrec (own=r), apply +f to receivers (pre-reduced)
// recv_side=0: rec=srec (own=s), apply -f to senders   (pre-reduced)
__global__ __launch_bounds__(256) void k_force_t(
    const float4* __restrict__ rec, const int* __restrict__ cnt,
    const float* __restrict__ dta, const float* __restrict__ dtb,
    const float* __restrict__ h, const float* __restrict__ A1,
    const float* __restrict__ g1, const float* __restrict__ g2,
    float* __restrict__ forces, int recv_side)
{
    __shared__ float f_lds[256][4];
    __shared__ int   dst_lds[256];

    int na = *cnt;
    int tid = threadIdx.x;
    int stride = gridDim.x * 256;

    for (int base = blockIdx.x * 256; base < na; base += stride) {
        int i = base + tid;
        int dstf = -1;
        float fx = 0.f, fy = 0.f, fz = 0.f;

        if (i < na) {
            float4 rv = rec[i];
            unsigned pk = __float_as_uint(rv.w);
            int own   = (int)(pk & 0xffffu);
            int other = (int)(pk >> 16);
            int r = recv_side ? own : other;
            int s = recv_side ? other : own;
            float vx = rv.x, vy = rv.y, vz = rv.z;
            float ss2 = vx * vx + vy * vy + vz * vz;
            if (ss2 > 1e-12f) {          // else grad of maximum() is 0
                float L = sqrtf(ss2);
                float invL = 1.f / L;
                float x = fminf(L * (INV_R * (float)TBL), (float)TBL - 1e-3f);
                int   i0 = (int)x;
                float f  = x - (float)i0;

                const float4* a0 = (const float4*)(dta + (size_t)i0 * 32);
                const float4* a1 = a0 + 8;
                const float4* b0 = (const float4*)(dtb + (size_t)i0 * 32);
                const float4* b1 = b0 + 8;
                const float4* pa = (const float4*)(g1 + (size_t)r * 32);
                const float4* pb = (const float4*)(h  + (size_t)s * 32);
                const float4* pc = (const float4*)(g2 + (size_t)r * 32);
                const float4* pd = (const float4*)(A1 + (size_t)s * 32);

                float dot = 0.f;
#pragma unroll
                for (int q = 0; q < 8; q++) {
                    float4 xg = pa[q], yg = pb[q], t0 = a0[q], t1 = a1[q];
                    dot += xg.x * yg.x * (t0.x + f * (t1.x - t0.x))
                         + xg.y * yg.y * (t0.y + f * (t1.y - t0.y))
                         + xg.z * yg.z * (t0.z + f * (t1.z - t0.z))
                         + xg.w * yg.w * (t0.w + f * (t1.w - t0.w));
                }
#pragma unroll
                for (int q = 0; q < 8; q++) {
                    float4 xg = pc[q], yg = pd[q], t0 = b0[q], t1 = b1[q];
                    dot += xg.x * yg.x * (t0.x + f * (t1.x - t0.x))
                         + xg.y * yg.y * (t0.y + f * (t1.y - t0.y))
                         + xg.z * yg.z * (t0.z + f * (t1.z - t0.z))
                         + xg.w * yg.w * (t0.w + f * (t1.w - t0.w));
                }

                float dLdl = INV_AVG * INV_R * dot;        // dE/dL
                float sc = (recv_side ? -1.f : 1.f) * dLdl * invL;
                fx = sc * vx; fy = sc * vy; fz = sc * vz;
                dstf = own;
            }
        }
        f_lds[tid][0] = fx; f_lds[tid][1] = fy; f_lds[tid][2] = fz;
        dst_lds[tid] = dstf;
        __syncthreads();

        // run-length pre-reduced scatter (records sorted by own)
        int grp = tid >> 5;
        int c   = tid & 31;
        if (c < 3) {
            int b32 = grp * 32;
            int cur = -1; float run = 0.f;
            for (int k = 0; k < 32; k++) {
                int d = dst_lds[b32 + k];
                if (d != cur) {
                    if (cur >= 0) unsafeAtomicAdd(&forces[3 * cur + c], run);
                    cur = d;
                    run = (d >= 0) ? f_lds[b32 + k][c] : 0.f;
                } else if (d >= 0) {
                    run += f_lds[b32 + k][c];
                }
            }
            if (cur >= 0) unsafeAtomicAdd(&forces[3 * cur + c], run);
        }
        __syncthreads();
    }
}

extern "C" void kernel_launch(void* const* d_in, const int* in_sizes, int n_in,
                              void* d_out, int out_size, void* d_ws, size_t ws_size,
                              hipStream_t stream)
{
    const float* pos    = (const float*)d_in[0];
    const float* attrs  = (const float*)d_in[1];
    const float* shifts = (const float*)d_in[2];
    const float* ae     = (const float*)d_in[3];
    const float* Wemb   = (const float*)d_in[4];
    const float* W1a    = (const float*)d_in[5];
    const float* W2a    = (const float*)d_in[6];
    const float* Wr1    = (const float*)d_in[7];
    const float* W1b    = (const float*)d_in[8];
    const float* W2b    = (const float*)d_in[9];
    const float* Wm1    = (const float*)d_in[10];
    const float* Wm2    = (const float*)d_in[11];
    const int*   ei     = (const int*)d_in[12];
    const int*   batch  = (const int*)d_in[13];

    int N = in_sizes[13];
    int E = in_sizes[12] / 2;

    float* out    = (float*)d_out;
    float* total  = out;                 // 32
    float* node_e = out + 32;            // N
    float* forces = out + 32 + N;        // 3N

    float* ws = (float*)d_ws;
    size_t NC = (size_t)N * 32;
    float* h    = ws;            // N*32
    float* A1   = h  + NC;       // N*32 : acc then A1_0 in place
    float* A2g2 = A1 + NC;       // N*32 : A2 acc, then g2 in place
    float* g1   = A2g2 + NC;     // N*32 : acc then final in place
    float* e0   = g1 + NC;       // N
    float* e1   = e0 + N;        // N
    int* hist_r = (int*)(e1 + N);   // N
    int* hist_s = hist_r + N;       // N
    int* cur_r  = hist_s + N;       // N
    int* cur_s  = cur_r + N;        // N
    int* cnt    = cur_s + N;        // 1
    // align records to 16 B
    size_t ioff = ((size_t)(cnt + 1 - (int*)ws) + 3) & ~(size_t)3;
    float4* rrec = (float4*)(ws + ioff);   // E float4
    float4* srec = rrec + E;               // E float4
    float* tbl  = (float*)(srec + E);      // 4 tables of (TBL+1)*32
    size_t tstride = (size_t)(TBL + 1) * 32;
    float* twa = tbl;
    float* dta = twa + tstride;
    float* twb = dta + tstride;
    float* dtb = twb + tstride;

    hipMemsetAsync(A1, 0, NC * sizeof(float), stream);
    hipMemsetAsync(A2g2, 0, NC * sizeof(float), stream);
    hipMemsetAsync(g1, 0, NC * sizeof(float), stream);
    hipMemsetAsync(total, 0, 32 * sizeof(float), stream);
    hipMemsetAsync(forces, 0, (size_t)N * 3 * sizeof(float), stream);
    hipMemsetAsync(hist_r, 0, (size_t)N * 2 * sizeof(int), stream);

    int nb_n = (N + 255) / 256;
    int nb_e = (E + 255) / 256;
    int nb_g = nb_e < 2048 ? nb_e : 2048;   // grid-stride for edge passes
    int nb_t = (TBL + 1 + 255) / 256;

    k_table<<<nb_t, 256, 0, stream>>>(W1a, W2a, W1b, W2b, twa, dta, twb, dtb);
    k_embed<<<nb_n, 256, 0, stream>>>(attrs, ae, Wemb, h, e0, N);
    k_build<<<nb_e, 256, 0, stream>>>(pos, shifts, ei, E, hist_r, hist_s);
    k_scan<<<2, 1024, 0, stream>>>(hist_r, cur_r, hist_s, cur_s, N, cnt);
    k_sort<<<nb_e, 256, 0, stream>>>(pos, shifts, ei, E, cur_r, cur_s, rrec, srec);

    k_edge_mlp_t<<<nb_g, 256, 0, stream>>>(rrec, cnt, twa, h, A1);
    k_node1<<<nb_n, 256, 0, stream>>>(h, A1, Wr1, e1, N);
    k_edge_mlp_t<<<nb_g, 256, 0, stream>>>(rrec, cnt, twb, A1, A2g2);
    k_node2<<<nb_n, 256, 0, stream>>>(A2g2, A1, Wm1, Wm2, e0, e1, node_e, total, batch, N);
    k_edge_mlp_t<<<nb_g, 256, 0, stream>>>(srec, cnt, twb, A2g2, g1);
    k_node3<<<nb_n, 256, 0, stream>>>(g1, A2g2, Wr1, N);
    k_force_t<<<nb_g, 256, 0, stream>>>(rrec, cnt, dta, dtb, h, A1, g1, A2g2,
                                        forces, 1);
    k_force_t<<<nb_g, 256, 0, stream>>>(srec, cnt, dta, dtb, h, A1, g1, A2g2,
                                        forces, 0);
}

// Round 9
// 404.183 us; speedup vs baseline: 1.7787x; 1.2432x over previous
//
#include <hip/hip_runtime.h>
#include <math.h>

constexpr float R_MAX   = 5.0f;
constexpr float INV_R   = 0.2f;                     // 1/R_MAX
constexpr float PI_F    = 3.14159265358979323846f;
constexpr float C0      = 0.632455532033675866f;    // sqrt(2/R_MAX)
constexpr float INV_AVG = 1.0f / 16.0f;             // 1/AVG_NEIGH
constexpr int   TBL     = 4096;                     // table resolution

__device__ __forceinline__ float sigm(float x) { return 1.0f / (1.0f + __expf(-x)); }

// ef plus d(ef)/dL (exact, used only in the table-build kernel)
__device__ __forceinline__ void radial_ef_d(float u, float invL, float* ef, float* dd) {
    float u2 = u * u, u4 = u2 * u2, u5 = u4 * u;
    float fc  = 1.f - 21.f * u5 + 35.f * u5 * u - 15.f * u5 * u2;
    float om  = 1.f - u;
    float fcp = -105.f * u4 * om * om;   // dfc/du
    float sp, cp;
    sincosf(PI_F * u, &sp, &cp);
    float twoc = 2.f * cp;
    float a = C0 * invL;
    float s_nm1 = 0.f, s_n = sp, c_nm1 = 1.f, c_n = cp;
#pragma unroll
    for (int n = 1; n <= 8; n++) {
        ef[n - 1] = a * s_n * fc;
        dd[n - 1] = a * fc * ((float)n * PI_F * INV_R * c_n - s_n * invL)
                  + a * s_n * fcp * INV_R;
        if (n < 8) {
            float sn2 = twoc * s_n - s_nm1; s_nm1 = s_n; s_n = sn2;
            float cn2 = twoc * c_n - c_nm1; c_nm1 = c_n; c_n = cn2;
        }
    }
}

// Build tw(u) and d tw/du tables. Parallelized 16x: one thread per
// (t, layer, 4-channel group) -> 65552 threads, all CUs engaged.
// (previous 1-thread-per-t version: 17 blocks, 0.7% occupancy, 75us latency)
__global__ __launch_bounds__(256) void k_table(
    const float* __restrict__ W1a, const float* __restrict__ W2a,
    const float* __restrict__ W1b, const float* __restrict__ W2b,
    float* __restrict__ twa, float* __restrict__ dta,
    float* __restrict__ twb, float* __restrict__ dtb)
{
    int gid = blockIdx.x * 256 + threadIdx.x;
    if (gid >= (TBL + 1) * 16) return;
    int cg = gid & 7;            // 4-channel group
    int l  = (gid >> 3) & 1;     // layer
    int t  = gid >> 4;           // table index
    float u = fmaxf((float)t / (float)TBL, 1e-4f);  // clamp avoids 0/0 at t=0
    float L = u * R_MAX;
    float invL = 1.f / L;
    float ef[8], dd[8], efu[8];
    radial_ef_d(u, invL, ef, dd);
#pragma unroll
    for (int k = 0; k < 8; k++) efu[k] = dd[k] * R_MAX;   // d ef/du

    const float* W1 = l ? W1b : W1a;
    const float* W2 = l ? W2b : W2a;
    float*     tw_o = l ? twb : twa;
    float*     dt_o = l ? dtb : dta;
    float tw[4] = {0.f, 0.f, 0.f, 0.f};
    float dt[4] = {0.f, 0.f, 0.f, 0.f};
    for (int j = 0; j < 64; j++) {
        float s1 = 0.f, du = 0.f;
#pragma unroll
        for (int k = 0; k < 8; k++) {
            float w = W1[k * 64 + j];
            s1 += ef[k] * w; du += efu[k] * w;
        }
        float sg  = sigm(s1);
        float act = s1 * sg;
        float dj  = sg * (1.f + s1 * (1.f - sg)) * du;  // silu'(s1)*ds1/du
        const float* w2 = W2 + j * 96 + cg * 4;
#pragma unroll
        for (int q = 0; q < 4; q++) {
            tw[q] += act * w2[q];
            dt[q] += dj * w2[q];
        }
    }
#pragma unroll
    for (int q = 0; q < 4; q++) {
        tw_o[(size_t)t * 32 + cg * 4 + q] = tw[q];
        dt_o[(size_t)t * 32 + cg * 4 + q] = dt[q];
    }
}

__global__ __launch_bounds__(256) void k_embed(
    const float* __restrict__ attrs, const float* __restrict__ ae,
    const float* __restrict__ Wemb, float* __restrict__ h,
    float* __restrict__ e0, int N)
{
    int i = blockIdx.x * blockDim.x + threadIdx.x;
    if (i >= N) return;
    float a[10];
#pragma unroll
    for (int k = 0; k < 10; k++) a[k] = attrs[i * 10 + k];
    float e = 0.f;
#pragma unroll
    for (int k = 0; k < 10; k++) e += a[k] * ae[k];
    e0[i] = e;
#pragma unroll
    for (int c = 0; c < 32; c++) {
        float v = 0.f;
#pragma unroll
        for (int k = 0; k < 10; k++) v += a[k] * Wemb[k * 32 + c];
        h[i * 32 + c] = v;
    }
}

// pass 0: histogram active-edge receivers and senders.
// (no single-address counter: same-address atomics serialize ~125us; total
// is derived in k_scan from the histogram)
__global__ __launch_bounds__(256) void k_build(
    const float* __restrict__ pos, const float* __restrict__ shifts,
    const int* __restrict__ ei, int E,
    int* __restrict__ hist_r, int* __restrict__ hist_s)
{
    int e = blockIdx.x * 256 + threadIdx.x;
    if (e >= E) return;
    int s = ei[e], r = ei[E + e];
    float vx = pos[3 * r + 0] - pos[3 * s + 0] + shifts[3 * e + 0];
    float vy = pos[3 * r + 1] - pos[3 * s + 1] + shifts[3 * e + 1];
    float vz = pos[3 * r + 2] - pos[3 * s + 2] + shifts[3 * e + 2];
    float ss2 = vx * vx + vy * vy + vz * vz;
    float L = sqrtf(fmaxf(ss2, 1e-12f));
    if (L * INV_R < 1.f) {
        atomicAdd(&hist_r[r], 1);
        atomicAdd(&hist_s[s], 1);
    }
}

// exclusive prefix sums of both histograms -> cursor arrays (1 block each).
// Block 0 additionally writes the total active count to cnt.
__global__ __launch_bounds__(1024) void k_scan(
    const int* __restrict__ hist_r, int* __restrict__ cur_r,
    const int* __restrict__ hist_s, int* __restrict__ cur_s, int n,
    int* __restrict__ cnt)
{
    const int* hist = blockIdx.x ? hist_s : hist_r;
    int*       cur  = blockIdx.x ? cur_s  : cur_r;
    __shared__ int part[1024];
    int tid = threadIdx.x;
    int per = (n + 1023) >> 10;
    int start = tid * per;
    int end = min(start + per, n);
    int sum = 0;
    for (int k = start; k < end; k++) sum += hist[k];
    part[tid] = sum;
    __syncthreads();
    for (int off = 1; off < 1024; off <<= 1) {
        int v = (tid >= off) ? part[tid - off] : 0;
        __syncthreads();
        part[tid] += v;
        __syncthreads();
    }
    if (blockIdx.x == 0 && tid == 1023) *cnt = part[1023];  // total active
    int run = part[tid] - sum;           // exclusive base of this chunk
    for (int k = start; k < end; k++) { cur[k] = run; run += hist[k]; }
}

// pass 0b: materialize sorted edge records {vx,vy,vz, pack(other<<16|own)}.
// rrec sorted by receiver (own=r); srec sorted by sender (own=s).
// Also records the srec->rrec slot bijection for the force pass split.
__global__ __launch_bounds__(256) void k_sort(
    const float* __restrict__ pos, const float* __restrict__ shifts,
    const int* __restrict__ ei, int E,
    int* __restrict__ cur_r, int* __restrict__ cur_s,
    float4* __restrict__ rrec, float4* __restrict__ srec,
    int* __restrict__ map_sr)
{
    int e = blockIdx.x * 256 + threadIdx.x;
    if (e >= E) return;
    int s = ei[e], r = ei[E + e];
    float vx = pos[3 * r + 0] - pos[3 * s + 0] + shifts[3 * e + 0];
    float vy = pos[3 * r + 1] - pos[3 * s + 1] + shifts[3 * e + 1];
    float vz = pos[3 * r + 2] - pos[3 * s + 2] + shifts[3 * e + 2];
    float ss2 = vx * vx + vy * vy + vz * vz;
    float L = sqrtf(fmaxf(ss2, 1e-12f));
    if (L * INV_R >= 1.f) return;
    int rp = atomicAdd(&cur_r[r], 1);
    int sp = atomicAdd(&cur_s[s], 1);
    rrec[rp] = make_float4(vx, vy, vz,
                           __uint_as_float(((unsigned)s << 16) | (unsigned)r));
    srec[sp] = make_float4(vx, vy, vz,
                           __uint_as_float(((unsigned)r << 16) | (unsigned)s));
    map_sr[sp] = rp;
}

// table-driven edge MLP: m = feat[gather] * lerp(tw_tbl, u);
// records sorted by scatter key -> run-length pre-reduced coalesced atomics.
__global__ __launch_bounds__(256) void k_edge_mlp_t(
    const float4* __restrict__ rec, const int* __restrict__ cnt,
    const float* __restrict__ tw_tbl, const float* __restrict__ feat,
    float* __restrict__ acc)
{
    __shared__ float m_lds[256][33];
    __shared__ int   dst_lds[256];

    int na = *cnt;
    int tid = threadIdx.x;
    int stride = gridDim.x * 256;

    for (int base = blockIdx.x * 256; base < na; base += stride) {
        int i = base + tid;
        int dst = -1;
        if (i < na) {
            float4 rv = rec[i];
            unsigned pk = __float_as_uint(rv.w);
            int gn = pk >> 16;
            dst = (int)(pk & 0xffffu);
            float ss2 = rv.x * rv.x + rv.y * rv.y + rv.z * rv.z;
            float L = sqrtf(fmaxf(ss2, 1e-12f));
            float x = fminf(L * (INV_R * (float)TBL), (float)TBL - 1e-3f);
            int   i0 = (int)x;
            float f  = x - (float)i0;

            const float4* r0 = (const float4*)(tw_tbl + (size_t)i0 * 32);
            const float4* r1 = r0 + 8;
            const float4* fp = (const float4*)(feat + (size_t)gn * 32);
#pragma unroll
            for (int q = 0; q < 8; q++) {
                float4 a = r0[q], b = r1[q], fv = fp[q];
                m_lds[tid][4 * q + 0] = fv.x * (a.x + f * (b.x - a.x));
                m_lds[tid][4 * q + 1] = fv.y * (a.y + f * (b.y - a.y));
                m_lds[tid][4 * q + 2] = fv.z * (a.z + f * (b.z - a.z));
                m_lds[tid][4 * q + 3] = fv.w * (a.w + f * (b.w - a.w));
            }
        }
        dst_lds[tid] = dst;
        __syncthreads();

        // run-length pre-reduced channel-parallel atomics
        int grp = tid >> 5;
        int c   = tid & 31;
        int b32 = grp * 32;
        int cur = -1; float run = 0.f;
        for (int k = 0; k < 32; k++) {
            int d = dst_lds[b32 + k];
            if (d != cur) {
                if (cur >= 0) unsafeAtomicAdd(&acc[(size_t)cur * 32 + c], run);
                cur = d;
                run = (d >= 0) ? m_lds[b32 + k][c] : 0.f;
            } else if (d >= 0) {
                run += m_lds[b32 + k][c];
            }
        }
        if (cur >= 0) unsafeAtomicAdd(&acc[(size_t)cur * 32 + c], run);
        __syncthreads();
    }
}

__global__ __launch_bounds__(256) void k_node1(
    const float* __restrict__ h, float* __restrict__ A1,
    const float* __restrict__ Wr1, float* __restrict__ e1, int N)
{
    int i = blockIdx.x * blockDim.x + threadIdx.x;
    if (i >= N) return;
    float dot = 0.f;
#pragma unroll
    for (int c = 0; c < 32; c++) {
        float v = A1[i * 32 + c] * INV_AVG + h[i * 32 + c];
        A1[i * 32 + c] = v;
        dot += v * Wr1[c];
    }
    e1[i] = dot;
}

// A2 buffer is read, then overwritten in place with g2
__global__ __launch_bounds__(256) void k_node2(
    float* __restrict__ A2g2, const float* __restrict__ A1,
    const float* __restrict__ Wm1, const float* __restrict__ Wm2,
    const float* __restrict__ e0, const float* __restrict__ e1,
    float* __restrict__ node_e, float* __restrict__ total,
    const int* __restrict__ batch, int N)
{
    __shared__ float bins[32];
    if (threadIdx.x < 32) bins[threadIdx.x] = 0.f;
    __syncthreads();
    int i = blockIdx.x * blockDim.x + threadIdx.x;
    if (i < N) {
        float A2[32];
#pragma unroll
        for (int c = 0; c < 32; c++)
            A2[c] = A2g2[i * 32 + c] * INV_AVG + A1[i * 32 + c];
        float z[16];
#pragma unroll
        for (int k = 0; k < 16; k++) {
            float v = 0.f;
#pragma unroll
            for (int c = 0; c < 32; c++) v += A2[c] * Wm1[c * 16 + k];
            z[k] = v;
        }
        float e2 = 0.f;
        float wk[16];
#pragma unroll
        for (int k = 0; k < 16; k++) {
            float sg = sigm(z[k]);
            float m2 = Wm2[k];
            e2 += z[k] * sg * m2;
            wk[k] = m2 * sg * (1.f + z[k] * (1.f - sg));  // Wm2 * silu'(z)
        }
#pragma unroll
        for (int c = 0; c < 32; c++) {
            float v = 0.f;
#pragma unroll
            for (int k = 0; k < 16; k++) v += Wm1[c * 16 + k] * wk[k];
            A2g2[i * 32 + c] = v;                          // g2 in place
        }
        float ne = e0[i] + e1[i] + e2;
        node_e[i] = ne;
        atomicAdd(&bins[batch[i]], ne);
    }
    __syncthreads();
    if (threadIdx.x < 32) unsafeAtomicAdd(&total[threadIdx.x], bins[threadIdx.x]);
}

__global__ __launch_bounds__(256) void k_node3(
    float* __restrict__ g1, const float* __restrict__ g2,
    const float* __restrict__ Wr1, int N)
{
    int i = blockIdx.x * blockDim.x + threadIdx.x;
    if (i >= N) return;
#pragma unroll
    for (int c = 0; c < 32; c++)
        g1[i * 32 + c] = g1[i * 32 + c] * INV_AVG + g2[i * 32 + c] + Wr1[c];
}

// force pass 1 (receiver-sorted): full dot via tables+gathers, applies -scv*v
// to receivers (run-length pre-reduced), and caches scv per rrec slot so the
// sender pass never redoes the gathers.
__global__ __launch_bounds__(256) void k_force_r(
    const float4* __restrict__ rec, const int* __restrict__ cnt,
    const float* __restrict__ dta, const float* __restrict__ dtb,
    const float* __restrict__ h, const float* __restrict__ A1,
    const float* __restrict__ g1, const float* __restrict__ g2,
    float* __restrict__ forces, float* __restrict__ sc_buf)
{
    __shared__ float f_lds[256][4];
    __shared__ int   dst_lds[256];

    int na = *cnt;
    int tid = threadIdx.x;
    int stride = gridDim.x * 256;

    for (int base = blockIdx.x * 256; base < na; base += stride) {
        int i = base + tid;
        int dstf = -1;
        float fx = 0.f, fy = 0.f, fz = 0.f;

        if (i < na) {
            float4 rv = rec[i];
            unsigned pk = __float_as_uint(rv.w);
            int r = (int)(pk & 0xffffu);
            int s = (int)(pk >> 16);
            float vx = rv.x, vy = rv.y, vz = rv.z;
            float ss2 = vx * vx + vy * vy + vz * vz;
            float scv = 0.f;
            if (ss2 > 1e-12f) {          // else grad of maximum() is 0
                float L = sqrtf(ss2);
                float invL = 1.f / L;
                float x = fminf(L * (INV_R * (float)TBL), (float)TBL - 1e-3f);
                int   i0 = (int)x;
                float f  = x - (float)i0;

                const float4* a0 = (const float4*)(dta + (size_t)i0 * 32);
                const float4* a1 = a0 + 8;
                const float4* b0 = (const float4*)(dtb + (size_t)i0 * 32);
                const float4* b1 = b0 + 8;
                const float4* pa = (const float4*)(g1 + (size_t)r * 32);
                const float4* pb = (const float4*)(h  + (size_t)s * 32);
                const float4* pc = (const float4*)(g2 + (size_t)r * 32);
                const float4* pd = (const float4*)(A1 + (size_t)s * 32);

                float dot = 0.f;
#pragma unroll
                for (int q = 0; q < 8; q++) {
                    float4 xg = pa[q], yg = pb[q], t0 = a0[q], t1 = a1[q];
                    dot += xg.x * yg.x * (t0.x + f * (t1.x - t0.x))
                         + xg.y * yg.y * (t0.y + f * (t1.y - t0.y))
                         + xg.z * yg.z * (t0.z + f * (t1.z - t0.z))
                         + xg.w * yg.w * (t0.w + f * (t1.w - t0.w));
                }
#pragma unroll
                for (int q = 0; q < 8; q++) {
                    float4 xg = pc[q], yg = pd[q], t0 = b0[q], t1 = b1[q];
                    dot += xg.x * yg.x * (t0.x + f * (t1.x - t0.x))
                         + xg.y * yg.y * (t0.y + f * (t1.y - t0.y))
                         + xg.z * yg.z * (t0.z + f * (t1.z - t0.z))
                         + xg.w * yg.w * (t0.w + f * (t1.w - t0.w));
                }

                scv = INV_AVG * INV_R * dot * invL;        // dE/dL / L
                fx = -scv * vx; fy = -scv * vy; fz = -scv * vz;
                dstf = r;
            }
            sc_buf[i] = scv;             // coalesced; consumed by k_force_s2
        }
        f_lds[tid][0] = fx; f_lds[tid][1] = fy; f_lds[tid][2] = fz;
        dst_lds[tid] = dstf;
        __syncthreads();

        // receiver scatter: run-length pre-reduced (records sorted by r)
        int grp = tid >> 5;
        int c   = tid & 31;
        if (c < 3) {
            int b32 = grp * 32;
            int cur = -1; float run = 0.f;
            for (int k = 0; k < 32; k++) {
                int d = dst_lds[b32 + k];
                if (d != cur) {
                    if (cur >= 0) unsafeAtomicAdd(&forces[3 * cur + c], run);
                    cur = d;
                    run = (d >= 0) ? f_lds[b32 + k][c] : 0.f;
                } else if (d >= 0) {
                    run += f_lds[b32 + k][c];
                }
            }
            if (cur >= 0) unsafeAtomicAdd(&forces[3 * cur + c], run);
        }
        __syncthreads();
    }
}

// force pass 2 (sender-sorted): reads the cached scalar via the srec->rrec
// map (sc_buf is 1.6MB, L2-resident) and applies +scv*v to senders.
// No node-row gathers, no table reads.
__global__ __launch_bounds__(256) void k_force_s2(
    const float4* __restrict__ rec, const int* __restrict__ cnt,
    const int* __restrict__ map_sr, const float* __restrict__ sc_buf,
    float* __restrict__ forces)
{
    __shared__ float f_lds[256][4];
    __shared__ int   dst_lds[256];

    int na = *cnt;
    int tid = threadIdx.x;
    int stride = gridDim.x * 256;

    for (int base = blockIdx.x * 256; base < na; base += stride) {
        int i = base + tid;
        int dstf = -1;
        float fx = 0.f, fy = 0.f, fz = 0.f;
        if (i < na) {
            float4 rv = rec[i];
            unsigned pk = __float_as_uint(rv.w);
            float scv = sc_buf[map_sr[i]];
            fx = scv * rv.x; fy = scv * rv.y; fz = scv * rv.z;
            dstf = (int)(pk & 0xffffu);   // own = sender
        }
        f_lds[tid][0] = fx; f_lds[tid][1] = fy; f_lds[tid][2] = fz;
        dst_lds[tid] = dstf;
        __syncthreads();

        int grp = tid >> 5;
        int c   = tid & 31;
        if (c < 3) {
            int b32 = grp * 32;
            int cur = -1; float run = 0.f;
            for (int k = 0; k < 32; k++) {
                int d = dst_lds[b32 + k];
                if (d != cur) {
                    if (cur >= 0) unsafeAtomicAdd(&forces[3 * cur + c], run);
                    cur = d;
                    run = (d >= 0) ? f_lds[b32 + k][c] : 0.f;
                } else if (d >= 0) {
                    run += f_lds[b32 + k][c];
                }
            }
            if (cur >= 0) unsafeAtomicAdd(&forces[3 * cur + c], run);
        }
        __syncthreads();
    }
}

extern "C" void kernel_launch(void* const* d_in, const int* in_sizes, int n_in,
                              void* d_out, int out_size, void* d_ws, size_t ws_size,
                              hipStream_t stream)
{
    const float* pos    = (const float*)d_in[0];
    const float* attrs  = (const float*)d_in[1];
    const float* shifts = (const float*)d_in[2];
    const float* ae     = (const float*)d_in[3];
    const float* Wemb   = (const float*)d_in[4];
    const float* W1a    = (const float*)d_in[5];
    const float* W2a    = (const float*)d_in[6];
    const float* Wr1    = (const float*)d_in[7];
    const float* W1b    = (const float*)d_in[8];
    const float* W2b    = (const float*)d_in[9];
    const float* Wm1    = (const float*)d_in[10];
    const float* Wm2    = (const float*)d_in[11];
    const int*   ei     = (const int*)d_in[12];
    const int*   batch  = (const int*)d_in[13];

    int N = in_sizes[13];
    int E = in_sizes[12] / 2;

    float* out    = (float*)d_out;
    float* total  = out;                 // 32
    float* node_e = out + 32;            // N
    float* forces = out + 32 + N;        // 3N

    float* ws = (float*)d_ws;
    size_t NC = (size_t)N * 32;
    float* h    = ws;            // N*32
    float* A1   = h  + NC;       // N*32 : acc then A1_0 in place
    float* A2g2 = A1 + NC;       // N*32 : A2 acc, then g2 in place
    float* g1   = A2g2 + NC;     // N*32 : acc then final in place
    float* e0   = g1 + NC;       // N
    float* e1   = e0 + N;        // N
    int* hist_r = (int*)(e1 + N);   // N
    int* hist_s = hist_r + N;       // N
    int* cur_r  = hist_s + N;       // N
    int* cur_s  = cur_r + N;        // N
    int* cnt    = cur_s + N;        // 1
    // align records to 16 B
    size_t ioff = ((size_t)(cnt + 1 - (int*)ws) + 3) & ~(size_t)3;
    float4* rrec = (float4*)(ws + ioff);   // E float4
    float4* srec = rrec + E;               // E float4
    float* tbl  = (float*)(srec + E);      // 4 tables of (TBL+1)*32
    size_t tstride = (size_t)(TBL + 1) * 32;
    float* twa = tbl;
    float* dta = twa + tstride;
    float* twb = dta + tstride;
    float* dtb = twb + tstride;
    int*   map_sr = (int*)(dtb + tstride);   // E
    float* sc_buf = (float*)(map_sr + E);    // E

    hipMemsetAsync(A1, 0, NC * sizeof(float), stream);
    hipMemsetAsync(A2g2, 0, NC * sizeof(float), stream);
    hipMemsetAsync(g1, 0, NC * sizeof(float), stream);
    hipMemsetAsync(total, 0, 32 * sizeof(float), stream);
    hipMemsetAsync(forces, 0, (size_t)N * 3 * sizeof(float), stream);
    hipMemsetAsync(hist_r, 0, (size_t)N * 2 * sizeof(int), stream);

    int nb_n = (N + 255) / 256;
    int nb_e = (E + 255) / 256;
    int nb_g = nb_e < 2048 ? nb_e : 2048;   // grid-stride for edge passes
    int nb_t = ((TBL + 1) * 16 + 255) / 256;

    k_table<<<nb_t, 256, 0, stream>>>(W1a, W2a, W1b, W2b, twa, dta, twb, dtb);
    k_embed<<<nb_n, 256, 0, stream>>>(attrs, ae, Wemb, h, e0, N);
    k_build<<<nb_e, 256, 0, stream>>>(pos, shifts, ei, E, hist_r, hist_s);
    k_scan<<<2, 1024, 0, stream>>>(hist_r, cur_r, hist_s, cur_s, N, cnt);
    k_sort<<<nb_e, 256, 0, stream>>>(pos, shifts, ei, E, cur_r, cur_s,
                                     rrec, srec, map_sr);

    k_edge_mlp_t<<<nb_g, 256, 0, stream>>>(rrec, cnt, twa, h, A1);
    k_node1<<<nb_n, 256, 0, stream>>>(h, A1, Wr1, e1, N);
    k_edge_mlp_t<<<nb_g, 256, 0, stream>>>(rrec, cnt, twb, A1, A2g2);
    k_node2<<<nb_n, 256, 0, stream>>>(A2g2, A1, Wm1, Wm2, e0, e1, node_e, total, batch, N);
    k_edge_mlp_t<<<nb_g, 256, 0, stream>>>(srec, cnt, twb, A2g2, g1);
    k_node3<<<nb_n, 256, 0, stream>>>(g1, A2g2, Wr1, N);
    k_force_r<<<nb_g, 256, 0, stream>>>(rrec, cnt, dta, dtb, h, A1, g1, A2g2,
                                        forces, sc_buf);
    k_force_s2<<<nb_g, 256, 0, stream>>>(srec, cnt, map_sr, sc_buf, forces);
}

// Round 10
// 400.326 us; speedup vs baseline: 1.7958x; 1.0096x over previous
//
#include <hip/hip_runtime.h>
#include <math.h>

constexpr float R_MAX   = 5.0f;
constexpr float INV_R   = 0.2f;                     // 1/R_MAX
constexpr float PI_F    = 3.14159265358979323846f;
constexpr float C0      = 0.632455532033675866f;    // sqrt(2/R_MAX)
constexpr float INV_AVG = 1.0f / 16.0f;             // 1/AVG_NEIGH
constexpr int   TBL     = 4096;                     // table resolution

__device__ __forceinline__ float sigm(float x) { return 1.0f / (1.0f + __expf(-x)); }

// f32 -> bf16 (round-to-nearest-even)
__device__ __forceinline__ unsigned f2bf(float x) {
    unsigned u = __float_as_uint(x);
    u += 0x7fffu + ((u >> 16) & 1u);
    return u >> 16;
}
// pack a 32-float row into 64B of bf16 (4x uint4)
__device__ __forceinline__ void store_bf_row(unsigned short* dst, const float* v) {
    uint4* o = (uint4*)dst;
#pragma unroll
    for (int w = 0; w < 4; w++) {
        uint4 t;
        t.x = f2bf(v[8*w+0]) | (f2bf(v[8*w+1]) << 16);
        t.y = f2bf(v[8*w+2]) | (f2bf(v[8*w+3]) << 16);
        t.z = f2bf(v[8*w+4]) | (f2bf(v[8*w+5]) << 16);
        t.w = f2bf(v[8*w+6]) | (f2bf(v[8*w+7]) << 16);
        o[w] = t;
    }
}
// unpack a 64B bf16 row to 32 floats (4 cacheline-halves vs 8 for f32 rows)
__device__ __forceinline__ void load_bf_row(const unsigned short* src, float* v) {
    const uint4* p = (const uint4*)src;
#pragma unroll
    for (int w = 0; w < 4; w++) {
        uint4 t = p[w];
        v[8*w+0] = __uint_as_float(t.x << 16);
        v[8*w+1] = __uint_as_float(t.x & 0xffff0000u);
        v[8*w+2] = __uint_as_float(t.y << 16);
        v[8*w+3] = __uint_as_float(t.y & 0xffff0000u);
        v[8*w+4] = __uint_as_float(t.z << 16);
        v[8*w+5] = __uint_as_float(t.z & 0xffff0000u);
        v[8*w+6] = __uint_as_float(t.w << 16);
        v[8*w+7] = __uint_as_float(t.w & 0xffff0000u);
    }
}

// ef plus d(ef)/dL (exact, used only in the table-build kernel)
__device__ __forceinline__ void radial_ef_d(float u, float invL, float* ef, float* dd) {
    float u2 = u * u, u4 = u2 * u2, u5 = u4 * u;
    float fc  = 1.f - 21.f * u5 + 35.f * u5 * u - 15.f * u5 * u2;
    float om  = 1.f - u;
    float fcp = -105.f * u4 * om * om;   // dfc/du
    float sp, cp;
    sincosf(PI_F * u, &sp, &cp);
    float twoc = 2.f * cp;
    float a = C0 * invL;
    float s_nm1 = 0.f, s_n = sp, c_nm1 = 1.f, c_n = cp;
#pragma unroll
    for (int n = 1; n <= 8; n++) {
        ef[n - 1] = a * s_n * fc;
        dd[n - 1] = a * fc * ((float)n * PI_F * INV_R * c_n - s_n * invL)
                  + a * s_n * fcp * INV_R;
        if (n < 8) {
            float sn2 = twoc * s_n - s_nm1; s_nm1 = s_n; s_n = sn2;
            float cn2 = twoc * c_n - c_nm1; c_nm1 = c_n; c_n = cn2;
        }
    }
}

// Build tw(u) and d tw/du tables. One thread per (t, layer, 4-ch group).
__global__ __launch_bounds__(256) void k_table(
    const float* __restrict__ W1a, const float* __restrict__ W2a,
    const float* __restrict__ W1b, const float* __restrict__ W2b,
    float* __restrict__ twa, float* __restrict__ dta,
    float* __restrict__ twb, float* __restrict__ dtb)
{
    int gid = blockIdx.x * 256 + threadIdx.x;
    if (gid >= (TBL + 1) * 16) return;
    int cg = gid & 7;            // 4-channel group
    int l  = (gid >> 3) & 1;     // layer
    int t  = gid >> 4;           // table index
    float u = fmaxf((float)t / (float)TBL, 1e-4f);
    float L = u * R_MAX;
    float invL = 1.f / L;
    float ef[8], dd[8], efu[8];
    radial_ef_d(u, invL, ef, dd);
#pragma unroll
    for (int k = 0; k < 8; k++) efu[k] = dd[k] * R_MAX;   // d ef/du

    const float* W1 = l ? W1b : W1a;
    const float* W2 = l ? W2b : W2a;
    float*     tw_o = l ? twb : twa;
    float*     dt_o = l ? dtb : dta;
    float tw[4] = {0.f, 0.f, 0.f, 0.f};
    float dt[4] = {0.f, 0.f, 0.f, 0.f};
    for (int j = 0; j < 64; j++) {
        float s1 = 0.f, du = 0.f;
#pragma unroll
        for (int k = 0; k < 8; k++) {
            float w = W1[k * 64 + j];
            s1 += ef[k] * w; du += efu[k] * w;
        }
        float sg  = sigm(s1);
        float act = s1 * sg;
        float dj  = sg * (1.f + s1 * (1.f - sg)) * du;
        const float* w2 = W2 + j * 96 + cg * 4;
#pragma unroll
        for (int q = 0; q < 4; q++) {
            tw[q] += act * w2[q];
            dt[q] += dj * w2[q];
        }
    }
#pragma unroll
    for (int q = 0; q < 4; q++) {
        tw_o[(size_t)t * 32 + cg * 4 + q] = tw[q];
        dt_o[(size_t)t * 32 + cg * 4 + q] = dt[q];
    }
}

__global__ __launch_bounds__(256) void k_embed(
    const float* __restrict__ attrs, const float* __restrict__ ae,
    const float* __restrict__ Wemb, float* __restrict__ h,
    unsigned short* __restrict__ h_bf, float* __restrict__ e0, int N)
{
    int i = blockIdx.x * blockDim.x + threadIdx.x;
    if (i >= N) return;
    float a[10];
#pragma unroll
    for (int k = 0; k < 10; k++) a[k] = attrs[i * 10 + k];
    float e = 0.f;
#pragma unroll
    for (int k = 0; k < 10; k++) e += a[k] * ae[k];
    e0[i] = e;
    float v[32];
#pragma unroll
    for (int c = 0; c < 32; c++) {
        float t = 0.f;
#pragma unroll
        for (int k = 0; k < 10; k++) t += a[k] * Wemb[k * 32 + c];
        v[c] = t;
        h[i * 32 + c] = t;
    }
    store_bf_row(h_bf + (size_t)i * 32, v);
}

// pass 0: histogram + materialize unsorted edge records (coalesced), so
// k_sort never re-gathers pos. urec aliases the A2g2+g1 region (memset after).
__global__ __launch_bounds__(256) void k_build(
    const float* __restrict__ pos, const float* __restrict__ shifts,
    const int* __restrict__ ei, int E,
    int* __restrict__ hist_r, int* __restrict__ hist_s,
    float4* __restrict__ urec)
{
    int e = blockIdx.x * 256 + threadIdx.x;
    if (e >= E) return;
    int s = ei[e], r = ei[E + e];
    float vx = pos[3 * r + 0] - pos[3 * s + 0] + shifts[3 * e + 0];
    float vy = pos[3 * r + 1] - pos[3 * s + 1] + shifts[3 * e + 1];
    float vz = pos[3 * r + 2] - pos[3 * s + 2] + shifts[3 * e + 2];
    float ss2 = vx * vx + vy * vy + vz * vz;
    float L = sqrtf(fmaxf(ss2, 1e-12f));
    if (L * INV_R < 1.f) {
        atomicAdd(&hist_r[r], 1);
        atomicAdd(&hist_s[s], 1);
        urec[e] = make_float4(vx, vy, vz,
                  __uint_as_float(((unsigned)s << 16) | (unsigned)r));
    } else {
        urec[e] = make_float4(0.f, 0.f, 0.f, __uint_as_float(0xFFFFFFFFu));
    }
}

// exclusive prefix sums of both histograms -> cursor arrays (1 block each).
// Block 0 additionally writes the total active count to cnt.
__global__ __launch_bounds__(1024) void k_scan(
    const int* __restrict__ hist_r, int* __restrict__ cur_r,
    const int* __restrict__ hist_s, int* __restrict__ cur_s, int n,
    int* __restrict__ cnt)
{
    const int* hist = blockIdx.x ? hist_s : hist_r;
    int*       cur  = blockIdx.x ? cur_s  : cur_r;
    __shared__ int part[1024];
    int tid = threadIdx.x;
    int per = (n + 1023) >> 10;
    int start = tid * per;
    int end = min(start + per, n);
    int sum = 0;
    for (int k = start; k < end; k++) sum += hist[k];
    part[tid] = sum;
    __syncthreads();
    for (int off = 1; off < 1024; off <<= 1) {
        int v = (tid >= off) ? part[tid - off] : 0;
        __syncthreads();
        part[tid] += v;
        __syncthreads();
    }
    if (blockIdx.x == 0 && tid == 1023) *cnt = part[1023];  // total active
    int run = part[tid] - sum;           // exclusive base of this chunk
    for (int k = start; k < end; k++) { cur[k] = run; run += hist[k]; }
}

// pass 0b: scatter urec into receiver-sorted and sender-sorted records.
// Reads are fully coalesced; no pos/shifts/ei re-gather.
__global__ __launch_bounds__(256) void k_sort(
    const float4* __restrict__ urec, int E,
    int* __restrict__ cur_r, int* __restrict__ cur_s,
    float4* __restrict__ rrec, float4* __restrict__ srec,
    int* __restrict__ map_sr)
{
    int e = blockIdx.x * 256 + threadIdx.x;
    if (e >= E) return;
    float4 uv = urec[e];
    unsigned pk = __float_as_uint(uv.w);
    if (pk == 0xFFFFFFFFu) return;
    int r = (int)(pk & 0xffffu);
    int s = (int)(pk >> 16);
    int rp = atomicAdd(&cur_r[r], 1);
    int sp = atomicAdd(&cur_s[s], 1);
    rrec[rp] = uv;                        // pk already (s<<16 | r)
    srec[sp] = make_float4(uv.x, uv.y, uv.z,
               __uint_as_float(((unsigned)r << 16) | (unsigned)s));
    map_sr[sp] = rp;
}

// table-driven edge MLP: m = bf16feat[gather] * lerp(tw_tbl, u);
// gather rows are 64B bf16 -> half the L1 transactions of f32 rows.
__global__ __launch_bounds__(256) void k_edge_mlp_t(
    const float4* __restrict__ rec, const int* __restrict__ cnt,
    const float* __restrict__ tw_tbl, const unsigned short* __restrict__ feat,
    float* __restrict__ acc)
{
    __shared__ float m_lds[256][33];
    __shared__ int   dst_lds[256];

    int na = *cnt;
    int tid = threadIdx.x;
    int stride = gridDim.x * 256;

    for (int base = blockIdx.x * 256; base < na; base += stride) {
        int i = base + tid;
        int dst = -1;
        if (i < na) {
            float4 rv = rec[i];
            unsigned pk = __float_as_uint(rv.w);
            int gn = pk >> 16;
            dst = (int)(pk & 0xffffu);
            float ss2 = rv.x * rv.x + rv.y * rv.y + rv.z * rv.z;
            float L = sqrtf(fmaxf(ss2, 1e-12f));
            float x = fminf(L * (INV_R * (float)TBL), (float)TBL - 1e-3f);
            int   i0 = (int)x;
            float f  = x - (float)i0;

            float fbuf[32];
            load_bf_row(feat + (size_t)gn * 32, fbuf);

            const float4* r0 = (const float4*)(tw_tbl + (size_t)i0 * 32);
            const float4* r1 = r0 + 8;
#pragma unroll
            for (int q = 0; q < 8; q++) {
                float4 a = r0[q], b = r1[q];
                m_lds[tid][4 * q + 0] = fbuf[4*q+0] * (a.x + f * (b.x - a.x));
                m_lds[tid][4 * q + 1] = fbuf[4*q+1] * (a.y + f * (b.y - a.y));
                m_lds[tid][4 * q + 2] = fbuf[4*q+2] * (a.z + f * (b.z - a.z));
                m_lds[tid][4 * q + 3] = fbuf[4*q+3] * (a.w + f * (b.w - a.w));
            }
        }
        dst_lds[tid] = dst;
        __syncthreads();

        // run-length pre-reduced channel-parallel atomics
        int grp = tid >> 5;
        int c   = tid & 31;
        int b32 = grp * 32;
        int cur = -1; float run = 0.f;
        for (int k = 0; k < 32; k++) {
            int d = dst_lds[b32 + k];
            if (d != cur) {
                if (cur >= 0) unsafeAtomicAdd(&acc[(size_t)cur * 32 + c], run);
                cur = d;
                run = (d >= 0) ? m_lds[b32 + k][c] : 0.f;
            } else if (d >= 0) {
                run += m_lds[b32 + k][c];
            }
        }
        if (cur >= 0) unsafeAtomicAdd(&acc[(size_t)cur * 32 + c], run);
        __syncthreads();
    }
}

__global__ __launch_bounds__(256) void k_node1(
    const float* __restrict__ h, float* __restrict__ A1,
    unsigned short* __restrict__ A1_bf,
    const float* __restrict__ Wr1, float* __restrict__ e1, int N)
{
    int i = blockIdx.x * blockDim.x + threadIdx.x;
    if (i >= N) return;
    float dot = 0.f;
    float v[32];
#pragma unroll
    for (int c = 0; c < 32; c++) {
        float t = A1[i * 32 + c] * INV_AVG + h[i * 32 + c];
        v[c] = t;
        A1[i * 32 + c] = t;
        dot += t * Wr1[c];
    }
    e1[i] = dot;
    store_bf_row(A1_bf + (size_t)i * 32, v);
}

// A2 buffer is read, then overwritten in place with g2 (+ bf16 mirror)
__global__ __launch_bounds__(256) void k_node2(
    float* __restrict__ A2g2, unsigned short* __restrict__ g2_bf,
    const float* __restrict__ A1,
    const float* __restrict__ Wm1, const float* __restrict__ Wm2,
    const float* __restrict__ e0, const float* __restrict__ e1,
    float* __restrict__ node_e, float* __restrict__ total,
    const int* __restrict__ batch, int N)
{
    __shared__ float bins[32];
    if (threadIdx.x < 32) bins[threadIdx.x] = 0.f;
    __syncthreads();
    int i = blockIdx.x * blockDim.x + threadIdx.x;
    if (i < N) {
        float A2[32];
#pragma unroll
        for (int c = 0; c < 32; c++)
            A2[c] = A2g2[i * 32 + c] * INV_AVG + A1[i * 32 + c];
        float z[16];
#pragma unroll
        for (int k = 0; k < 16; k++) {
            float v = 0.f;
#pragma unroll
            for (int c = 0; c < 32; c++) v += A2[c] * Wm1[c * 16 + k];
            z[k] = v;
        }
        float e2 = 0.f;
        float wk[16];
#pragma unroll
        for (int k = 0; k < 16; k++) {
            float sg = sigm(z[k]);
            float m2 = Wm2[k];
            e2 += z[k] * sg * m2;
            wk[k] = m2 * sg * (1.f + z[k] * (1.f - sg));  // Wm2 * silu'(z)
        }
        float g2v[32];
#pragma unroll
        for (int c = 0; c < 32; c++) {
            float v = 0.f;
#pragma unroll
            for (int k = 0; k < 16; k++) v += Wm1[c * 16 + k] * wk[k];
            g2v[c] = v;
            A2g2[i * 32 + c] = v;                          // g2 in place
        }
        store_bf_row(g2_bf + (size_t)i * 32, g2v);
        float ne = e0[i] + e1[i] + e2;
        node_e[i] = ne;
        atomicAdd(&bins[batch[i]], ne);
    }
    __syncthreads();
    if (threadIdx.x < 32) unsafeAtomicAdd(&total[threadIdx.x], bins[threadIdx.x]);
}

__global__ __launch_bounds__(256) void k_node3(
    float* __restrict__ g1, const float* __restrict__ g2,
    const float* __restrict__ Wr1, int N)
{
    int i = blockIdx.x * blockDim.x + threadIdx.x;
    if (i >= N) return;
#pragma unroll
    for (int c = 0; c < 32; c++)
        g1[i * 32 + c] = g1[i * 32 + c] * INV_AVG + g2[i * 32 + c] + Wr1[c];
}

// force pass 1 (receiver-sorted): r-side rows f32 (sorted, L1-hot); s-side
// rows bf16 (random, 64B). Caches scv per rrec slot for the sender pass.
__global__ __launch_bounds__(256) void k_force_r(
    const float4* __restrict__ rec, const int* __restrict__ cnt,
    const float* __restrict__ dta, const float* __restrict__ dtb,
    const unsigned short* __restrict__ h_bf,
    const unsigned short* __restrict__ A1_bf,
    const float* __restrict__ g1, const float* __restrict__ g2,
    float* __restrict__ forces, float* __restrict__ sc_buf)
{
    __shared__ float f_lds[256][4];
    __shared__ int   dst_lds[256];

    int na = *cnt;
    int tid = threadIdx.x;
    int stride = gridDim.x * 256;

    for (int base = blockIdx.x * 256; base < na; base += stride) {
        int i = base + tid;
        int dstf = -1;
        float fx = 0.f, fy = 0.f, fz = 0.f;

        if (i < na) {
            float4 rv = rec[i];
            unsigned pk = __float_as_uint(rv.w);
            int r = (int)(pk & 0xffffu);
            int s = (int)(pk >> 16);
            float vx = rv.x, vy = rv.y, vz = rv.z;
            float ss2 = vx * vx + vy * vy + vz * vz;
            float scv = 0.f;
            if (ss2 > 1e-12f) {          // else grad of maximum() is 0
                float L = sqrtf(ss2);
                float invL = 1.f / L;
                float x = fminf(L * (INV_R * (float)TBL), (float)TBL - 1e-3f);
                int   i0 = (int)x;
                float f  = x - (float)i0;

                float hb[32], ab[32];
                load_bf_row(h_bf  + (size_t)s * 32, hb);
                load_bf_row(A1_bf + (size_t)s * 32, ab);

                const float4* a0 = (const float4*)(dta + (size_t)i0 * 32);
                const float4* a1 = a0 + 8;
                const float4* b0 = (const float4*)(dtb + (size_t)i0 * 32);
                const float4* b1 = b0 + 8;
                const float4* pa = (const float4*)(g1 + (size_t)r * 32);
                const float4* pc = (const float4*)(g2 + (size_t)r * 32);

                float dot = 0.f;
#pragma unroll
                for (int q = 0; q < 8; q++) {
                    float4 xg = pa[q], t0 = a0[q], t1 = a1[q];
                    dot += xg.x * hb[4*q+0] * (t0.x + f * (t1.x - t0.x))
                         + xg.y * hb[4*q+1] * (t0.y + f * (t1.y - t0.y))
                         + xg.z * hb[4*q+2] * (t0.z + f * (t1.z - t0.z))
                         + xg.w * hb[4*q+3] * (t0.w + f * (t1.w - t0.w));
                }
#pragma unroll
                for (int q = 0; q < 8; q++) {
                    float4 xg = pc[q], t0 = b0[q], t1 = b1[q];
                    dot += xg.x * ab[4*q+0] * (t0.x + f * (t1.x - t0.x))
                         + xg.y * ab[4*q+1] * (t0.y + f * (t1.y - t0.y))
                         + xg.z * ab[4*q+2] * (t0.z + f * (t1.z - t0.z))
                         + xg.w * ab[4*q+3] * (t0.w + f * (t1.w - t0.w));
                }

                scv = INV_AVG * INV_R * dot * invL;        // dE/dL / L
                fx = -scv * vx; fy = -scv * vy; fz = -scv * vz;
                dstf = r;
            }
            sc_buf[i] = scv;             // coalesced; consumed by k_force_s2
        }
        f_lds[tid][0] = fx; f_lds[tid][1] = fy; f_lds[tid][2] = fz;
        dst_lds[tid] = dstf;
        __syncthreads();

        // receiver scatter: run-length pre-reduced (records sorted by r)
        int grp = tid >> 5;
        int c   = tid & 31;
        if (c < 3) {
            int b32 = grp * 32;
            int cur = -1; float run = 0.f;
            for (int k = 0; k < 32; k++) {
                int d = dst_lds[b32 + k];
                if (d != cur) {
                    if (cur >= 0) unsafeAtomicAdd(&forces[3 * cur + c], run);
                    cur = d;
                    run = (d >= 0) ? f_lds[b32 + k][c] : 0.f;
                } else if (d >= 0) {
                    run += f_lds[b32 + k][c];
                }
            }
            if (cur >= 0) unsafeAtomicAdd(&forces[3 * cur + c], run);
        }
        __syncthreads();
    }
}

// force pass 2 (sender-sorted): cached scalar via srec->rrec map.
__global__ __launch_bounds__(256) void k_force_s2(
    const float4* __restrict__ rec, const int* __restrict__ cnt,
    const int* __restrict__ map_sr, const float* __restrict__ sc_buf,
    float* __restrict__ forces)
{
    __shared__ float f_lds[256][4];
    __shared__ int   dst_lds[256];

    int na = *cnt;
    int tid = threadIdx.x;
    int stride = gridDim.x * 256;

    for (int base = blockIdx.x * 256; base < na; base += stride) {
        int i = base + tid;
        int dstf = -1;
        float fx = 0.f, fy = 0.f, fz = 0.f;
        if (i < na) {
            float4 rv = rec[i];
            unsigned pk = __float_as_uint(rv.w);
            float scv = sc_buf[map_sr[i]];
            fx = scv * rv.x; fy = scv * rv.y; fz = scv * rv.z;
            dstf = (int)(pk & 0xffffu);   // own = sender
        }
        f_lds[tid][0] = fx; f_lds[tid][1] = fy; f_lds[tid][2] = fz;
        dst_lds[tid] = dstf;
        __syncthreads();

        int grp = tid >> 5;
        int c   = tid & 31;
        if (c < 3) {
            int b32 = grp * 32;
            int cur = -1; float run = 0.f;
            for (int k = 0; k < 32; k++) {
                int d = dst_lds[b32 + k];
                if (d != cur) {
                    if (cur >= 0) unsafeAtomicAdd(&forces[3 * cur + c], run);
                    cur = d;
                    run = (d >= 0) ? f_lds[b32 + k][c] : 0.f;
                } else if (d >= 0) {
                    run += f_lds[b32 + k][c];
                }
            }
            if (cur >= 0) unsafeAtomicAdd(&forces[3 * cur + c], run);
        }
        __syncthreads();
    }
}

extern "C" void kernel_launch(void* const* d_in, const int* in_sizes, int n_in,
                              void* d_out, int out_size, void* d_ws, size_t ws_size,
                              hipStream_t stream)
{
    const float* pos    = (const float*)d_in[0];
    const float* attrs  = (const float*)d_in[1];
    const float* shifts = (const float*)d_in[2];
    const float* ae     = (const float*)d_in[3];
    const float* Wemb   = (const float*)d_in[4];
    const float* W1a    = (const float*)d_in[5];
    const float* W2a    = (const float*)d_in[6];
    const float* Wr1    = (const float*)d_in[7];
    const float* W1b    = (const float*)d_in[8];
    const float* W2b    = (const float*)d_in[9];
    const float* Wm1    = (const float*)d_in[10];
    const float* Wm2    = (const float*)d_in[11];
    const int*   ei     = (const int*)d_in[12];
    const int*   batch  = (const int*)d_in[13];

    int N = in_sizes[13];
    int E = in_sizes[12] / 2;

    float* out    = (float*)d_out;
    float* total  = out;                 // 32
    float* node_e = out + 32;            // N
    float* forces = out + 32 + N;        // 3N

    float* ws = (float*)d_ws;
    size_t NC = (size_t)N * 32;
    float* h    = ws;            // N*32
    float* A1   = h  + NC;       // N*32 : acc then A1_0 in place
    float* A2g2 = A1 + NC;       // N*32 : A2 acc, then g2 in place
    float* g1   = A2g2 + NC;     // N*32 : acc then final in place
    float* e0   = g1 + NC;       // N
    float* e1   = e0 + N;        // N
    int* hist_r = (int*)(e1 + N);   // N
    int* hist_s = hist_r + N;       // N
    int* cur_r  = hist_s + N;       // N
    int* cur_s  = cur_r + N;        // N
    int* cnt    = cur_s + N;        // 1
    // align records to 16 B
    size_t ioff = ((size_t)(cnt + 1 - (int*)ws) + 3) & ~(size_t)3;
    float4* rrec = (float4*)(ws + ioff);   // E float4
    float4* srec = rrec + E;               // E float4
    float* tbl  = (float*)(srec + E);      // 4 tables of (TBL+1)*32
    size_t tstride = (size_t)(TBL + 1) * 32;
    float* twa = tbl;
    float* dta = twa + tstride;
    float* twb = dta + tstride;
    float* dtb = twb + tstride;
    int*   map_sr = (int*)(dtb + tstride);   // E
    float* sc_buf = (float*)(map_sr + E);    // E
    unsigned short* h_bf  = (unsigned short*)(sc_buf + E);  // NC ushorts
    unsigned short* A1_bf = h_bf + NC;                      // NC ushorts
    unsigned short* g2_bf = A1_bf + NC;                     // NC ushorts
    // urec aliases A2g2+g1 (2*NC floats == E float4s when E == 16N);
    // their memsets are issued AFTER k_sort consumes urec.
    float4* urec = (float4*)A2g2;

    hipMemsetAsync(A1, 0, NC * sizeof(float), stream);
    hipMemsetAsync(total, 0, 32 * sizeof(float), stream);
    hipMemsetAsync(forces, 0, (size_t)N * 3 * sizeof(float), stream);
    hipMemsetAsync(hist_r, 0, (size_t)N * 2 * sizeof(int), stream);

    int nb_n = (N + 255) / 256;
    int nb_e = (E + 255) / 256;
    int nb_g = nb_e < 2048 ? nb_e : 2048;   // grid-stride for edge passes
    int nb_t = ((TBL + 1) * 16 + 255) / 256;

    k_table<<<nb_t, 256, 0, stream>>>(W1a, W2a, W1b, W2b, twa, dta, twb, dtb);
    k_embed<<<nb_n, 256, 0, stream>>>(attrs, ae, Wemb, h, h_bf, e0, N);
    k_build<<<nb_e, 256, 0, stream>>>(pos, shifts, ei, E, hist_r, hist_s, urec);
    k_scan<<<2, 1024, 0, stream>>>(hist_r, cur_r, hist_s, cur_s, N, cnt);
    k_sort<<<nb_e, 256, 0, stream>>>(urec, E, cur_r, cur_s, rrec, srec, map_sr);

    // urec dead from here; reclaim the region for A2g2 and g1 accumulators
    hipMemsetAsync(A2g2, 0, NC * sizeof(float), stream);
    hipMemsetAsync(g1, 0, NC * sizeof(float), stream);

    k_edge_mlp_t<<<nb_g, 256, 0, stream>>>(rrec, cnt, twa, h_bf, A1);
    k_node1<<<nb_n, 256, 0, stream>>>(h, A1, A1_bf, Wr1, e1, N);
    k_edge_mlp_t<<<nb_g, 256, 0, stream>>>(rrec, cnt, twb, A1_bf, A2g2);
    k_node2<<<nb_n, 256, 0, stream>>>(A2g2, g2_bf, A1, Wm1, Wm2, e0, e1,
                                      node_e, total, batch, N);
    k_edge_mlp_t<<<nb_g, 256, 0, stream>>>(srec, cnt, twb, g2_bf, g1);
    k_node3<<<nb_n, 256, 0, stream>>>(g1, A2g2, Wr1, N);
    k_force_r<<<nb_g, 256, 0, stream>>>(rrec, cnt, dta, dtb, h_bf, A1_bf,
                                        g1, A2g2, forces, sc_buf);
    k_force_s2<<<nb_g, 256, 0, stream>>>(srec, cnt, map_sr, sc_buf, forces);
}

// Round 11
// 386.443 us; speedup vs baseline: 1.8603x; 1.0359x over previous
//
#include <hip/hip_runtime.h>
#include <math.h>

constexpr float R_MAX   = 5.0f;
constexpr float INV_R   = 0.2f;                     // 1/R_MAX
constexpr float PI_F    = 3.14159265358979323846f;
constexpr float C0      = 0.632455532033675866f;    // sqrt(2/R_MAX)
constexpr float INV_AVG = 1.0f / 16.0f;             // 1/AVG_NEIGH
constexpr int   TBL     = 4096;                     // table resolution

__device__ __forceinline__ float sigm(float x) { return 1.0f / (1.0f + __expf(-x)); }

// f32 -> bf16 (round-to-nearest-even)
__device__ __forceinline__ unsigned f2bf(float x) {
    unsigned u = __float_as_uint(x);
    u += 0x7fffu + ((u >> 16) & 1u);
    return u >> 16;
}
// pack a 32-float row into 64B of bf16 (4x uint4)
__device__ __forceinline__ void store_bf_row(unsigned short* dst, const float* v) {
    uint4* o = (uint4*)dst;
#pragma unroll
    for (int w = 0; w < 4; w++) {
        uint4 t;
        t.x = f2bf(v[8*w+0]) | (f2bf(v[8*w+1]) << 16);
        t.y = f2bf(v[8*w+2]) | (f2bf(v[8*w+3]) << 16);
        t.z = f2bf(v[8*w+4]) | (f2bf(v[8*w+5]) << 16);
        t.w = f2bf(v[8*w+6]) | (f2bf(v[8*w+7]) << 16);
        o[w] = t;
    }
}
// unpack a 64B bf16 row to 32 floats
__device__ __forceinline__ void load_bf_row(const unsigned short* src, float* v) {
    const uint4* p = (const uint4*)src;
#pragma unroll
    for (int w = 0; w < 4; w++) {
        uint4 t = p[w];
        v[8*w+0] = __uint_as_float(t.x << 16);
        v[8*w+1] = __uint_as_float(t.x & 0xffff0000u);
        v[8*w+2] = __uint_as_float(t.y << 16);
        v[8*w+3] = __uint_as_float(t.y & 0xffff0000u);
        v[8*w+4] = __uint_as_float(t.z << 16);
        v[8*w+5] = __uint_as_float(t.z & 0xffff0000u);
        v[8*w+6] = __uint_as_float(t.w << 16);
        v[8*w+7] = __uint_as_float(t.w & 0xffff0000u);
    }
}

// ef plus d(ef)/dL (exact, used only in the table-build kernel)
__device__ __forceinline__ void radial_ef_d(float u, float invL, float* ef, float* dd) {
    float u2 = u * u, u4 = u2 * u2, u5 = u4 * u;
    float fc  = 1.f - 21.f * u5 + 35.f * u5 * u - 15.f * u5 * u2;
    float om  = 1.f - u;
    float fcp = -105.f * u4 * om * om;   // dfc/du
    float sp, cp;
    sincosf(PI_F * u, &sp, &cp);
    float twoc = 2.f * cp;
    float a = C0 * invL;
    float s_nm1 = 0.f, s_n = sp, c_nm1 = 1.f, c_n = cp;
#pragma unroll
    for (int n = 1; n <= 8; n++) {
        ef[n - 1] = a * s_n * fc;
        dd[n - 1] = a * fc * ((float)n * PI_F * INV_R * c_n - s_n * invL)
                  + a * s_n * fcp * INV_R;
        if (n < 8) {
            float sn2 = twoc * s_n - s_nm1; s_nm1 = s_n; s_n = sn2;
            float cn2 = twoc * c_n - c_nm1; c_nm1 = c_n; c_n = cn2;
        }
    }
}

// Build tw(u) and d tw/du tables. One thread per (t, layer, 4-ch group).
// Also zeroes the 32-bin total accumulator (block 0).
__global__ __launch_bounds__(256) void k_table(
    const float* __restrict__ W1a, const float* __restrict__ W2a,
    const float* __restrict__ W1b, const float* __restrict__ W2b,
    float* __restrict__ twa, float* __restrict__ dta,
    float* __restrict__ twb, float* __restrict__ dtb,
    float* __restrict__ total)
{
    if (blockIdx.x == 0 && threadIdx.x < 32) total[threadIdx.x] = 0.f;
    int gid = blockIdx.x * 256 + threadIdx.x;
    if (gid >= (TBL + 1) * 16) return;
    int cg = gid & 7;            // 4-channel group
    int l  = (gid >> 3) & 1;     // layer
    int t  = gid >> 4;           // table index
    float u = fmaxf((float)t / (float)TBL, 1e-4f);
    float L = u * R_MAX;
    float invL = 1.f / L;
    float ef[8], dd[8], efu[8];
    radial_ef_d(u, invL, ef, dd);
#pragma unroll
    for (int k = 0; k < 8; k++) efu[k] = dd[k] * R_MAX;   // d ef/du

    const float* W1 = l ? W1b : W1a;
    const float* W2 = l ? W2b : W2a;
    float*     tw_o = l ? twb : twa;
    float*     dt_o = l ? dtb : dta;
    float tw[4] = {0.f, 0.f, 0.f, 0.f};
    float dt[4] = {0.f, 0.f, 0.f, 0.f};
    for (int j = 0; j < 64; j++) {
        float s1 = 0.f, du = 0.f;
#pragma unroll
        for (int k = 0; k < 8; k++) {
            float w = W1[k * 64 + j];
            s1 += ef[k] * w; du += efu[k] * w;
        }
        float sg  = sigm(s1);
        float act = s1 * sg;
        float dj  = sg * (1.f + s1 * (1.f - sg)) * du;
        const float* w2 = W2 + j * 96 + cg * 4;
#pragma unroll
        for (int q = 0; q < 4; q++) {
            tw[q] += act * w2[q];
            dt[q] += dj * w2[q];
        }
    }
#pragma unroll
    for (int q = 0; q < 4; q++) {
        tw_o[(size_t)t * 32 + cg * 4 + q] = tw[q];
        dt_o[(size_t)t * 32 + cg * 4 + q] = dt[q];
    }
}

// embed + zero-init of A1 accumulator, forces, and both histograms
// (replaces 4 memset dispatches; all consumers are later on the stream)
__global__ __launch_bounds__(256) void k_embed(
    const float* __restrict__ attrs, const float* __restrict__ ae,
    const float* __restrict__ Wemb, float* __restrict__ h,
    unsigned short* __restrict__ hA1_bf, float* __restrict__ e0,
    float* __restrict__ A1, float* __restrict__ forces,
    int* __restrict__ hist_r, int* __restrict__ hist_s, int N)
{
    int i = blockIdx.x * blockDim.x + threadIdx.x;
    if (i >= N) return;
    float a[10];
#pragma unroll
    for (int k = 0; k < 10; k++) a[k] = attrs[i * 10 + k];
    float e = 0.f;
#pragma unroll
    for (int k = 0; k < 10; k++) e += a[k] * ae[k];
    e0[i] = e;
    float v[32];
#pragma unroll
    for (int c = 0; c < 32; c++) {
        float t = 0.f;
#pragma unroll
        for (int k = 0; k < 10; k++) t += a[k] * Wemb[k * 32 + c];
        v[c] = t;
        h[i * 32 + c] = t;
        A1[i * 32 + c] = 0.f;
    }
    store_bf_row(hA1_bf + (size_t)i * 64, v);   // h half of packed row
    forces[3 * i + 0] = 0.f; forces[3 * i + 1] = 0.f; forces[3 * i + 2] = 0.f;
    hist_r[i] = 0; hist_s[i] = 0;
}

// pass 0: histogram + materialize unsorted edge records (coalesced).
// urec aliases the A2g2+g1 region (zeroed later by node1/node2).
__global__ __launch_bounds__(256) void k_build(
    const float* __restrict__ pos, const float* __restrict__ shifts,
    const int* __restrict__ ei, int E,
    int* __restrict__ hist_r, int* __restrict__ hist_s,
    float4* __restrict__ urec)
{
    int e = blockIdx.x * 256 + threadIdx.x;
    if (e >= E) return;
    int s = ei[e], r = ei[E + e];
    float vx = pos[3 * r + 0] - pos[3 * s + 0] + shifts[3 * e + 0];
    float vy = pos[3 * r + 1] - pos[3 * s + 1] + shifts[3 * e + 1];
    float vz = pos[3 * r + 2] - pos[3 * s + 2] + shifts[3 * e + 2];
    float ss2 = vx * vx + vy * vy + vz * vz;
    float L = sqrtf(fmaxf(ss2, 1e-12f));
    if (L * INV_R < 1.f) {
        atomicAdd(&hist_r[r], 1);
        atomicAdd(&hist_s[s], 1);
        urec[e] = make_float4(vx, vy, vz,
                  __uint_as_float(((unsigned)s << 16) | (unsigned)r));
    } else {
        urec[e] = make_float4(0.f, 0.f, 0.f, __uint_as_float(0xFFFFFFFFu));
    }
}

// exclusive prefix sums of both histograms -> cursor arrays (1 block each).
// Block 0 additionally writes the total active count to cnt.
__global__ __launch_bounds__(1024) void k_scan(
    const int* __restrict__ hist_r, int* __restrict__ cur_r,
    const int* __restrict__ hist_s, int* __restrict__ cur_s, int n,
    int* __restrict__ cnt)
{
    const int* hist = blockIdx.x ? hist_s : hist_r;
    int*       cur  = blockIdx.x ? cur_s  : cur_r;
    __shared__ int part[1024];
    int tid = threadIdx.x;
    int per = (n + 1023) >> 10;
    int start = tid * per;
    int end = min(start + per, n);
    int sum = 0;
    for (int k = start; k < end; k++) sum += hist[k];
    part[tid] = sum;
    __syncthreads();
    for (int off = 1; off < 1024; off <<= 1) {
        int v = (tid >= off) ? part[tid - off] : 0;
        __syncthreads();
        part[tid] += v;
        __syncthreads();
    }
    if (blockIdx.x == 0 && tid == 1023) *cnt = part[1023];  // total active
    int run = part[tid] - sum;           // exclusive base of this chunk
    for (int k = start; k < end; k++) { cur[k] = run; run += hist[k]; }
}

// pass 0b: scatter urec into receiver-sorted and sender-sorted records.
__global__ __launch_bounds__(256) void k_sort(
    const float4* __restrict__ urec, int E,
    int* __restrict__ cur_r, int* __restrict__ cur_s,
    float4* __restrict__ rrec, float4* __restrict__ srec,
    int* __restrict__ map_sr)
{
    int e = blockIdx.x * 256 + threadIdx.x;
    if (e >= E) return;
    float4 uv = urec[e];
    unsigned pk = __float_as_uint(uv.w);
    if (pk == 0xFFFFFFFFu) return;
    int r = (int)(pk & 0xffffu);
    int s = (int)(pk >> 16);
    int rp = atomicAdd(&cur_r[r], 1);
    int sp = atomicAdd(&cur_s[s], 1);
    rrec[rp] = uv;                        // pk already (s<<16 | r)
    srec[sp] = make_float4(uv.x, uv.y, uv.z,
               __uint_as_float(((unsigned)r << 16) | (unsigned)s));
    map_sr[sp] = rp;
}

// table-driven edge MLP: m = bf16feat[gather] * lerp(tw_tbl, u);
// feat has row stride fstride ushorts (packed hA1 rows use 64).
__global__ __launch_bounds__(256) void k_edge_mlp_t(
    const float4* __restrict__ rec, const int* __restrict__ cnt,
    const float* __restrict__ tw_tbl, const unsigned short* __restrict__ feat,
    int fstride, float* __restrict__ acc)
{
    __shared__ float m_lds[256][33];
    __shared__ int   dst_lds[256];

    int na = *cnt;
    int tid = threadIdx.x;
    int stride = gridDim.x * 256;

    for (int base = blockIdx.x * 256; base < na; base += stride) {
        int i = base + tid;
        int dst = -1;
        if (i < na) {
            float4 rv = rec[i];
            unsigned pk = __float_as_uint(rv.w);
            int gn = pk >> 16;
            dst = (int)(pk & 0xffffu);
            float ss2 = rv.x * rv.x + rv.y * rv.y + rv.z * rv.z;
            float L = sqrtf(fmaxf(ss2, 1e-12f));
            float x = fminf(L * (INV_R * (float)TBL), (float)TBL - 1e-3f);
            int   i0 = (int)x;
            float f  = x - (float)i0;

            float fbuf[32];
            load_bf_row(feat + (size_t)gn * fstride, fbuf);

            const float4* r0 = (const float4*)(tw_tbl + (size_t)i0 * 32);
            const float4* r1 = r0 + 8;
#pragma unroll
            for (int q = 0; q < 8; q++) {
                float4 a = r0[q], b = r1[q];
                m_lds[tid][4 * q + 0] = fbuf[4*q+0] * (a.x + f * (b.x - a.x));
                m_lds[tid][4 * q + 1] = fbuf[4*q+1] * (a.y + f * (b.y - a.y));
                m_lds[tid][4 * q + 2] = fbuf[4*q+2] * (a.z + f * (b.z - a.z));
                m_lds[tid][4 * q + 3] = fbuf[4*q+3] * (a.w + f * (b.w - a.w));
            }
        }
        dst_lds[tid] = dst;
        __syncthreads();

        // run-length pre-reduced channel-parallel atomics
        int grp = tid >> 5;
        int c   = tid & 31;
        int b32 = grp * 32;
        int cur = -1; float run = 0.f;
        for (int k = 0; k < 32; k++) {
            int d = dst_lds[b32 + k];
            if (d != cur) {
                if (cur >= 0) unsafeAtomicAdd(&acc[(size_t)cur * 32 + c], run);
                cur = d;
                run = (d >= 0) ? m_lds[b32 + k][c] : 0.f;
            } else if (d >= 0) {
                run += m_lds[b32 + k][c];
            }
        }
        if (cur >= 0) unsafeAtomicAdd(&acc[(size_t)cur * 32 + c], run);
        __syncthreads();
    }
}

// node1: finalize A1, write bf16 A1-half of packed row, zero A2g2 row
// (A2g2 region was urec; k_sort has already consumed it by now)
__global__ __launch_bounds__(256) void k_node1(
    const float* __restrict__ h, float* __restrict__ A1,
    unsigned short* __restrict__ hA1_bf,
    const float* __restrict__ Wr1, float* __restrict__ e1,
    float* __restrict__ A2g2, int N)
{
    int i = blockIdx.x * blockDim.x + threadIdx.x;
    if (i >= N) return;
    float dot = 0.f;
    float v[32];
#pragma unroll
    for (int c = 0; c < 32; c++) {
        float t = A1[i * 32 + c] * INV_AVG + h[i * 32 + c];
        v[c] = t;
        A1[i * 32 + c] = t;
        A2g2[i * 32 + c] = 0.f;
        dot += t * Wr1[c];
    }
    e1[i] = dot;
    store_bf_row(hA1_bf + (size_t)i * 64 + 32, v);   // A1 half of packed row
}

// node2: A2 -> energies + g2 (in place) + bf16 mirror; zeroes g1 row
__global__ __launch_bounds__(256) void k_node2(
    float* __restrict__ A2g2, unsigned short* __restrict__ g2_bf,
    const float* __restrict__ A1,
    const float* __restrict__ Wm1, const float* __restrict__ Wm2,
    const float* __restrict__ e0, const float* __restrict__ e1,
    float* __restrict__ node_e, float* __restrict__ total,
    float* __restrict__ g1, const int* __restrict__ batch, int N)
{
    __shared__ float bins[32];
    if (threadIdx.x < 32) bins[threadIdx.x] = 0.f;
    __syncthreads();
    int i = blockIdx.x * blockDim.x + threadIdx.x;
    if (i < N) {
        float A2[32];
#pragma unroll
        for (int c = 0; c < 32; c++) {
            A2[c] = A2g2[i * 32 + c] * INV_AVG + A1[i * 32 + c];
            g1[i * 32 + c] = 0.f;
        }
        float z[16];
#pragma unroll
        for (int k = 0; k < 16; k++) {
            float v = 0.f;
#pragma unroll
            for (int c = 0; c < 32; c++) v += A2[c] * Wm1[c * 16 + k];
            z[k] = v;
        }
        float e2 = 0.f;
        float wk[16];
#pragma unroll
        for (int k = 0; k < 16; k++) {
            float sg = sigm(z[k]);
            float m2 = Wm2[k];
            e2 += z[k] * sg * m2;
            wk[k] = m2 * sg * (1.f + z[k] * (1.f - sg));  // Wm2 * silu'(z)
        }
        float g2v[32];
#pragma unroll
        for (int c = 0; c < 32; c++) {
            float v = 0.f;
#pragma unroll
            for (int k = 0; k < 16; k++) v += Wm1[c * 16 + k] * wk[k];
            g2v[c] = v;
            A2g2[i * 32 + c] = v;                          // g2 in place
        }
        store_bf_row(g2_bf + (size_t)i * 32, g2v);
        float ne = e0[i] + e1[i] + e2;
        node_e[i] = ne;
        atomicAdd(&bins[batch[i]], ne);
    }
    __syncthreads();
    if (threadIdx.x < 32) unsafeAtomicAdd(&total[threadIdx.x], bins[threadIdx.x]);
}

__global__ __launch_bounds__(256) void k_node3(
    float* __restrict__ g1, const float* __restrict__ g2,
    const float* __restrict__ Wr1, int N)
{
    int i = blockIdx.x * blockDim.x + threadIdx.x;
    if (i >= N) return;
#pragma unroll
    for (int c = 0; c < 32; c++)
        g1[i * 32 + c] = g1[i * 32 + c] * INV_AVG + g2[i * 32 + c] + Wr1[c];
}

// force pass 1 (receiver-sorted): r-side rows f32 (sorted, L1-hot); s-side
// is ONE packed 128B bf16 row (h|A1) -> a single random cacheline per edge.
__global__ __launch_bounds__(256) void k_force_r(
    const float4* __restrict__ rec, const int* __restrict__ cnt,
    const float* __restrict__ dta, const float* __restrict__ dtb,
    const unsigned short* __restrict__ hA1_bf,
    const float* __restrict__ g1, const float* __restrict__ g2,
    float* __restrict__ forces, float* __restrict__ sc_buf)
{
    __shared__ float f_lds[256][4];
    __shared__ int   dst_lds[256];

    int na = *cnt;
    int tid = threadIdx.x;
    int stride = gridDim.x * 256;

    for (int base = blockIdx.x * 256; base < na; base += stride) {
        int i = base + tid;
        int dstf = -1;
        float fx = 0.f, fy = 0.f, fz = 0.f;

        if (i < na) {
            float4 rv = rec[i];
            unsigned pk = __float_as_uint(rv.w);
            int r = (int)(pk & 0xffffu);
            int s = (int)(pk >> 16);
            float vx = rv.x, vy = rv.y, vz = rv.z;
            float ss2 = vx * vx + vy * vy + vz * vz;
            float scv = 0.f;
            if (ss2 > 1e-12f) {          // else grad of maximum() is 0
                float L = sqrtf(ss2);
                float invL = 1.f / L;
                float x = fminf(L * (INV_R * (float)TBL), (float)TBL - 1e-3f);
                int   i0 = (int)x;
                float f  = x - (float)i0;

                float hb[32], ab[32];
                const unsigned short* row = hA1_bf + (size_t)s * 64;
                load_bf_row(row, hb);        // h half
                load_bf_row(row + 32, ab);   // A1 half (same cacheline)

                const float4* a0 = (const float4*)(dta + (size_t)i0 * 32);
                const float4* a1 = a0 + 8;
                const float4* b0 = (const float4*)(dtb + (size_t)i0 * 32);
                const float4* b1 = b0 + 8;
                const float4* pa = (const float4*)(g1 + (size_t)r * 32);
                const float4* pc = (const float4*)(g2 + (size_t)r * 32);

                float dot = 0.f;
#pragma unroll
                for (int q = 0; q < 8; q++) {
                    float4 xg = pa[q], t0 = a0[q], t1 = a1[q];
                    dot += xg.x * hb[4*q+0] * (t0.x + f * (t1.x - t0.x))
                         + xg.y * hb[4*q+1] * (t0.y + f * (t1.y - t0.y))
                         + xg.z * hb[4*q+2] * (t0.z + f * (t1.z - t0.z))
                         + xg.w * hb[4*q+3] * (t0.w + f * (t1.w - t0.w));
                }
#pragma unroll
                for (int q = 0; q < 8; q++) {
                    float4 xg = pc[q], t0 = b0[q], t1 = b1[q];
                    dot += xg.x * ab[4*q+0] * (t0.x + f * (t1.x - t0.x))
                         + xg.y * ab[4*q+1] * (t0.y + f * (t1.y - t0.y))
                         + xg.z * ab[4*q+2] * (t0.z + f * (t1.z - t0.z))
                         + xg.w * ab[4*q+3] * (t0.w + f * (t1.w - t0.w));
                }

                scv = INV_AVG * INV_R * dot * invL;        // dE/dL / L
                fx = -scv * vx; fy = -scv * vy; fz = -scv * vz;
                dstf = r;
            }
            sc_buf[i] = scv;             // coalesced; consumed by k_force_s2
        }
        f_lds[tid][0] = fx; f_lds[tid][1] = fy; f_lds[tid][2] = fz;
        dst_lds[tid] = dstf;
        __syncthreads();

        // receiver scatter: run-length pre-reduced (records sorted by r)
        int grp = tid >> 5;
        int c   = tid & 31;
        if (c < 3) {
            int b32 = grp * 32;
            int cur = -1; float run = 0.f;
            for (int k = 0; k < 32; k++) {
                int d = dst_lds[b32 + k];
                if (d != cur) {
                    if (cur >= 0) unsafeAtomicAdd(&forces[3 * cur + c], run);
                    cur = d;
                    run = (d >= 0) ? f_lds[b32 + k][c] : 0.f;
                } else if (d >= 0) {
                    run += f_lds[b32 + k][c];
                }
            }
            if (cur >= 0) unsafeAtomicAdd(&forces[3 * cur + c], run);
        }
        __syncthreads();
    }
}

// force pass 2 (sender-sorted): cached scalar via srec->rrec map.
__global__ __launch_bounds__(256) void k_force_s2(
    const float4* __restrict__ rec, const int* __restrict__ cnt,
    const int* __restrict__ map_sr, const float* __restrict__ sc_buf,
    float* __restrict__ forces)
{
    __shared__ float f_lds[256][4];
    __shared__ int   dst_lds[256];

    int na = *cnt;
    int tid = threadIdx.x;
    int stride = gridDim.x * 256;

    for (int base = blockIdx.x * 256; base < na; base += stride) {
        int i = base + tid;
        int dstf = -1;
        float fx = 0.f, fy = 0.f, fz = 0.f;
        if (i < na) {
            float4 rv = rec[i];
            unsigned pk = __float_as_uint(rv.w);
            float scv = sc_buf[map_sr[i]];
            fx = scv * rv.x; fy = scv * rv.y; fz = scv * rv.z;
            dstf = (int)(pk & 0xffffu);   // own = sender
        }
        f_lds[tid][0] = fx; f_lds[tid][1] = fy; f_lds[tid][2] = fz;
        dst_lds[tid] = dstf;
        __syncthreads();

        int grp = tid >> 5;
        int c   = tid & 31;
        if (c < 3) {
            int b32 = grp * 32;
            int cur = -1; float run = 0.f;
            for (int k = 0; k < 32; k++) {
                int d = dst_lds[b32 + k];
                if (d != cur) {
                    if (cur >= 0) unsafeAtomicAdd(&forces[3 * cur + c], run);
                    cur = d;
                    run = (d >= 0) ? f_lds[b32 + k][c] : 0.f;
                } else if (d >= 0) {
                    run += f_lds[b32 + k][c];
                }
            }
            if (cur >= 0) unsafeAtomicAdd(&forces[3 * cur + c], run);
        }
        __syncthreads();
    }
}

extern "C" void kernel_launch(void* const* d_in, const int* in_sizes, int n_in,
                              void* d_out, int out_size, void* d_ws, size_t ws_size,
                              hipStream_t stream)
{
    const float* pos    = (const float*)d_in[0];
    const float* attrs  = (const float*)d_in[1];
    const float* shifts = (const float*)d_in[2];
    const float* ae     = (const float*)d_in[3];
    const float* Wemb   = (const float*)d_in[4];
    const float* W1a    = (const float*)d_in[5];
    const float* W2a    = (const float*)d_in[6];
    const float* Wr1    = (const float*)d_in[7];
    const float* W1b    = (const float*)d_in[8];
    const float* W2b    = (const float*)d_in[9];
    const float* Wm1    = (const float*)d_in[10];
    const float* Wm2    = (const float*)d_in[11];
    const int*   ei     = (const int*)d_in[12];
    const int*   batch  = (const int*)d_in[13];

    int N = in_sizes[13];
    int E = in_sizes[12] / 2;

    float* out    = (float*)d_out;
    float* total  = out;                 // 32
    float* node_e = out + 32;            // N
    float* forces = out + 32 + N;        // 3N

    float* ws = (float*)d_ws;
    size_t NC = (size_t)N * 32;
    float* h    = ws;            // N*32
    float* A1   = h  + NC;       // N*32 : acc then A1_0 in place
    float* A2g2 = A1 + NC;       // N*32 : A2 acc, then g2 in place
    float* g1   = A2g2 + NC;     // N*32 : acc then final in place
    float* e0   = g1 + NC;       // N
    float* e1   = e0 + N;        // N
    int* hist_r = (int*)(e1 + N);   // N
    int* hist_s = hist_r + N;       // N
    int* cur_r  = hist_s + N;       // N
    int* cur_s  = cur_r + N;        // N
    int* cnt    = cur_s + N;        // 1
    // align records to 16 B
    size_t ioff = ((size_t)(cnt + 1 - (int*)ws) + 3) & ~(size_t)3;
    float4* rrec = (float4*)(ws + ioff);   // E float4
    float4* srec = rrec + E;               // E float4
    float* tbl  = (float*)(srec + E);      // 4 tables of (TBL+1)*32
    size_t tstride = (size_t)(TBL + 1) * 32;
    float* twa = tbl;
    float* dta = twa + tstride;
    float* twb = dta + tstride;
    float* dtb = twb + tstride;
    int*   map_sr = (int*)(dtb + tstride);   // E
    float* sc_buf = (float*)(map_sr + E);    // E
    // packed bf16 rows: hA1_bf[n] = 128B {h row | A1 row}, 128B aligned
    unsigned short* hA1_bf = (unsigned short*)(sc_buf + E);  // 2*NC ushorts
    unsigned short* g2_bf  = hA1_bf + 2 * NC;                // NC ushorts
    // urec aliases A2g2+g1 (2*NC floats == E float4s when E == 16N);
    // those accumulators are zeroed by node1/node2 after k_sort consumes urec
    float4* urec = (float4*)A2g2;

    int nb_n = (N + 255) / 256;
    int nb_e = (E + 255) / 256;
    int nb_g = nb_e < 2048 ? nb_e : 2048;   // grid-stride for edge passes
    int nb_t = ((TBL + 1) * 16 + 255) / 256;

    k_table<<<nb_t, 256, 0, stream>>>(W1a, W2a, W1b, W2b, twa, dta, twb, dtb,
                                      total);
    k_embed<<<nb_n, 256, 0, stream>>>(attrs, ae, Wemb, h, hA1_bf, e0,
                                      A1, forces, hist_r, hist_s, N);
    k_build<<<nb_e, 256, 0, stream>>>(pos, shifts, ei, E, hist_r, hist_s, urec);
    k_scan<<<2, 1024, 0, stream>>>(hist_r, cur_r, hist_s, cur_s, N, cnt);
    k_sort<<<nb_e, 256, 0, stream>>>(urec, E, cur_r, cur_s, rrec, srec, map_sr);

    k_edge_mlp_t<<<nb_g, 256, 0, stream>>>(rrec, cnt, twa, hA1_bf, 64, A1);
    k_node1<<<nb_n, 256, 0, stream>>>(h, A1, hA1_bf, Wr1, e1, A2g2, N);
    k_edge_mlp_t<<<nb_g, 256, 0, stream>>>(rrec, cnt, twb, hA1_bf + 32, 64, A2g2);
    k_node2<<<nb_n, 256, 0, stream>>>(A2g2, g2_bf, A1, Wm1, Wm2, e0, e1,
                                      node_e, total, g1, batch, N);
    k_edge_mlp_t<<<nb_g, 256, 0, stream>>>(srec, cnt, twb, g2_bf, 32, g1);
    k_node3<<<nb_n, 256, 0, stream>>>(g1, A2g2, Wr1, N);
    k_force_r<<<nb_g, 256, 0, stream>>>(rrec, cnt, dta, dtb, hA1_bf,
                                        g1, A2g2, forces, sc_buf);
    k_force_s2<<<nb_g, 256, 0, stream>>>(srec, cnt, map_sr, sc_buf, forces);
}

// Round 12
// 328.206 us; speedup vs baseline: 2.1904x; 1.1774x over previous
//
#include <hip/hip_runtime.h>
#include <math.h>

constexpr float R_MAX   = 5.0f;
constexpr float INV_R   = 0.2f;                     // 1/R_MAX
constexpr float PI_F    = 3.14159265358979323846f;
constexpr float C0      = 0.632455532033675866f;    // sqrt(2/R_MAX)
constexpr float INV_AVG = 1.0f / 16.0f;             // 1/AVG_NEIGH
constexpr int   TBL     = 4096;                     // table resolution
constexpr int   SCHUNK  = 512;                      // scan chunk per block

__device__ __forceinline__ float sigm(float x) { return 1.0f / (1.0f + __expf(-x)); }

// f32 -> bf16 (round-to-nearest-even)
__device__ __forceinline__ unsigned f2bf(float x) {
    unsigned u = __float_as_uint(x);
    u += 0x7fffu + ((u >> 16) & 1u);
    return u >> 16;
}
// pack a 32-float row into 64B of bf16 (4x uint4)
__device__ __forceinline__ void store_bf_row(unsigned short* dst, const float* v) {
    uint4* o = (uint4*)dst;
#pragma unroll
    for (int w = 0; w < 4; w++) {
        uint4 t;
        t.x = f2bf(v[8*w+0]) | (f2bf(v[8*w+1]) << 16);
        t.y = f2bf(v[8*w+2]) | (f2bf(v[8*w+3]) << 16);
        t.z = f2bf(v[8*w+4]) | (f2bf(v[8*w+5]) << 16);
        t.w = f2bf(v[8*w+6]) | (f2bf(v[8*w+7]) << 16);
        o[w] = t;
    }
}
// unpack a 64B bf16 row to 32 floats
__device__ __forceinline__ void load_bf_row(const unsigned short* src, float* v) {
    const uint4* p = (const uint4*)src;
#pragma unroll
    for (int w = 0; w < 4; w++) {
        uint4 t = p[w];
        v[8*w+0] = __uint_as_float(t.x << 16);
        v[8*w+1] = __uint_as_float(t.x & 0xffff0000u);
        v[8*w+2] = __uint_as_float(t.y << 16);
        v[8*w+3] = __uint_as_float(t.y & 0xffff0000u);
        v[8*w+4] = __uint_as_float(t.z << 16);
        v[8*w+5] = __uint_as_float(t.z & 0xffff0000u);
        v[8*w+6] = __uint_as_float(t.w << 16);
        v[8*w+7] = __uint_as_float(t.w & 0xffff0000u);
    }
}

// ef plus d(ef)/dL (exact, used only in the table-build kernel)
__device__ __forceinline__ void radial_ef_d(float u, float invL, float* ef, float* dd) {
    float u2 = u * u, u4 = u2 * u2, u5 = u4 * u;
    float fc  = 1.f - 21.f * u5 + 35.f * u5 * u - 15.f * u5 * u2;
    float om  = 1.f - u;
    float fcp = -105.f * u4 * om * om;   // dfc/du
    float sp, cp;
    sincosf(PI_F * u, &sp, &cp);
    float twoc = 2.f * cp;
    float a = C0 * invL;
    float s_nm1 = 0.f, s_n = sp, c_nm1 = 1.f, c_n = cp;
#pragma unroll
    for (int n = 1; n <= 8; n++) {
        ef[n - 1] = a * s_n * fc;
        dd[n - 1] = a * fc * ((float)n * PI_F * INV_R * c_n - s_n * invL)
                  + a * s_n * fcp * INV_R;
        if (n < 8) {
            float sn2 = twoc * s_n - s_nm1; s_nm1 = s_n; s_n = sn2;
            float cn2 = twoc * c_n - c_nm1; c_nm1 = c_n; c_n = cn2;
        }
    }
}

// Build tw(u) and d tw/du tables. One thread per (t, layer, 4-ch group).
// Also zeroes the 32-bin total accumulator (block 0).
__global__ __launch_bounds__(256) void k_table(
    const float* __restrict__ W1a, const float* __restrict__ W2a,
    const float* __restrict__ W1b, const float* __restrict__ W2b,
    float* __restrict__ twa, float* __restrict__ dta,
    float* __restrict__ twb, float* __restrict__ dtb,
    float* __restrict__ total)
{
    if (blockIdx.x == 0 && threadIdx.x < 32) total[threadIdx.x] = 0.f;
    int gid = blockIdx.x * 256 + threadIdx.x;
    if (gid >= (TBL + 1) * 16) return;
    int cg = gid & 7;            // 4-channel group
    int l  = (gid >> 3) & 1;     // layer
    int t  = gid >> 4;           // table index
    float u = fmaxf((float)t / (float)TBL, 1e-4f);
    float L = u * R_MAX;
    float invL = 1.f / L;
    float ef[8], dd[8], efu[8];
    radial_ef_d(u, invL, ef, dd);
#pragma unroll
    for (int k = 0; k < 8; k++) efu[k] = dd[k] * R_MAX;   // d ef/du

    const float* W1 = l ? W1b : W1a;
    const float* W2 = l ? W2b : W2a;
    float*     tw_o = l ? twb : twa;
    float*     dt_o = l ? dtb : dta;
    float tw[4] = {0.f, 0.f, 0.f, 0.f};
    float dt[4] = {0.f, 0.f, 0.f, 0.f};
    for (int j = 0; j < 64; j++) {
        float s1 = 0.f, du = 0.f;
#pragma unroll
        for (int k = 0; k < 8; k++) {
            float w = W1[k * 64 + j];
            s1 += ef[k] * w; du += efu[k] * w;
        }
        float sg  = sigm(s1);
        float act = s1 * sg;
        float dj  = sg * (1.f + s1 * (1.f - sg)) * du;
        const float* w2 = W2 + j * 96 + cg * 4;
#pragma unroll
        for (int q = 0; q < 4; q++) {
            tw[q] += act * w2[q];
            dt[q] += dj * w2[q];
        }
    }
#pragma unroll
    for (int q = 0; q < 4; q++) {
        tw_o[(size_t)t * 32 + cg * 4 + q] = tw[q];
        dt_o[(size_t)t * 32 + cg * 4 + q] = dt[q];
    }
}

// embed + zero-init of A1 accumulator, forces, and both histograms
__global__ __launch_bounds__(256) void k_embed(
    const float* __restrict__ attrs, const float* __restrict__ ae,
    const float* __restrict__ Wemb, float* __restrict__ h,
    unsigned short* __restrict__ hA1_bf, float* __restrict__ e0,
    float* __restrict__ A1, float* __restrict__ forces,
    int* __restrict__ hist_r, int* __restrict__ hist_s, int N)
{
    int i = blockIdx.x * blockDim.x + threadIdx.x;
    if (i >= N) return;
    float a[10];
#pragma unroll
    for (int k = 0; k < 10; k++) a[k] = attrs[i * 10 + k];
    float e = 0.f;
#pragma unroll
    for (int k = 0; k < 10; k++) e += a[k] * ae[k];
    e0[i] = e;
    float v[32];
#pragma unroll
    for (int c = 0; c < 32; c++) {
        float t = 0.f;
#pragma unroll
        for (int k = 0; k < 10; k++) t += a[k] * Wemb[k * 32 + c];
        v[c] = t;
        h[i * 32 + c] = t;
        A1[i * 32 + c] = 0.f;
    }
    store_bf_row(hA1_bf + (size_t)i * 64, v);   // h half of packed row
    forces[3 * i + 0] = 0.f; forces[3 * i + 1] = 0.f; forces[3 * i + 2] = 0.f;
    hist_r[i] = 0; hist_s[i] = 0;
}

// pass 0: histogram + materialize unsorted edge records (coalesced).
__global__ __launch_bounds__(256) void k_build(
    const float* __restrict__ pos, const float* __restrict__ shifts,
    const int* __restrict__ ei, int E,
    int* __restrict__ hist_r, int* __restrict__ hist_s,
    float4* __restrict__ urec)
{
    int e = blockIdx.x * 256 + threadIdx.x;
    if (e >= E) return;
    int s = ei[e], r = ei[E + e];
    float vx = pos[3 * r + 0] - pos[3 * s + 0] + shifts[3 * e + 0];
    float vy = pos[3 * r + 1] - pos[3 * s + 1] + shifts[3 * e + 1];
    float vz = pos[3 * r + 2] - pos[3 * s + 2] + shifts[3 * e + 2];
    float ss2 = vx * vx + vy * vy + vz * vz;
    float L = sqrtf(fmaxf(ss2, 1e-12f));
    if (L * INV_R < 1.f) {
        atomicAdd(&hist_r[r], 1);
        atomicAdd(&hist_s[s], 1);
        urec[e] = make_float4(vx, vy, vz,
                  __uint_as_float(((unsigned)s << 16) | (unsigned)r));
    } else {
        urec[e] = make_float4(0.f, 0.f, 0.f, __uint_as_float(0xFFFFFFFFu));
    }
}

// hierarchical scan stage A: per-block chunk sums (both hists in one grid)
__global__ __launch_bounds__(256) void k_scan_a(
    const int* __restrict__ hist_r, const int* __restrict__ hist_s,
    int n, int nb, int* __restrict__ part)
{
    __shared__ int red[256];
    int b = blockIdx.x;
    const int* hist = (b < nb) ? hist_r : hist_s;
    int cb = (b < nb) ? b : b - nb;
    int base = cb * SCHUNK;
    int t = threadIdx.x;
    int i0 = base + 2 * t, i1 = i0 + 1;
    int sum = 0;
    if (i0 < n) sum += hist[i0];
    if (i1 < n) sum += hist[i1];
    red[t] = sum;
    __syncthreads();
    for (int off = 128; off > 0; off >>= 1) {
        if (t < off) red[t] += red[t + off];
        __syncthreads();
    }
    if (t == 0) part[b] = red[0];
}

// stage B: exclusive scan of the block sums (in LDS, one block); writes cnt
__global__ __launch_bounds__(256) void k_scan_b(
    const int* __restrict__ part, int nb, int* __restrict__ bbase,
    int* __restrict__ cnt)
{
    __shared__ int buf[512];   // 2*nb <= 512
    int t = threadIdx.x;
    for (int k = t; k < 2 * nb; k += 256) buf[k] = part[k];
    __syncthreads();
    if (t < 2) {
        int base = t * nb;
        int run = 0;
        for (int k = 0; k < nb; k++) {
            int v = buf[base + k];
            buf[base + k] = run;
            run += v;
        }
        if (t == 0) *cnt = run;   // total active (receiver segment)
    }
    __syncthreads();
    for (int k = t; k < 2 * nb; k += 256) bbase[k] = buf[k];
}

// stage C: per-chunk exclusive scan + block base -> cursor arrays
__global__ __launch_bounds__(256) void k_scan_c(
    const int* __restrict__ hist_r, const int* __restrict__ hist_s,
    int n, int nb, const int* __restrict__ bbase,
    int* __restrict__ cur_r, int* __restrict__ cur_s)
{
    __shared__ int sc[256];
    int b = blockIdx.x;
    const int* hist = (b < nb) ? hist_r : hist_s;
    int*       cur  = (b < nb) ? cur_r : cur_s;
    int cb = (b < nb) ? b : b - nb;
    int base = cb * SCHUNK;
    int t = threadIdx.x;
    int i0 = base + 2 * t, i1 = i0 + 1;
    int e0 = (i0 < n) ? hist[i0] : 0;
    int e1 = (i1 < n) ? hist[i1] : 0;
    int ts = e0 + e1;
    sc[t] = ts;
    __syncthreads();
    for (int off = 1; off < 256; off <<= 1) {   // inclusive Hillis-Steele
        int v = (t >= off) ? sc[t - off] : 0;
        __syncthreads();
        sc[t] += v;
        __syncthreads();
    }
    int excl = sc[t] - ts + bbase[b];
    if (i0 < n) cur[i0] = excl;
    if (i1 < n) cur[i1] = excl + e0;
}

// pass 0b: scatter urec into receiver-sorted and sender-sorted records.
__global__ __launch_bounds__(256) void k_sort(
    const float4* __restrict__ urec, int E,
    int* __restrict__ cur_r, int* __restrict__ cur_s,
    float4* __restrict__ rrec, float4* __restrict__ srec,
    int* __restrict__ map_sr)
{
    int e = blockIdx.x * 256 + threadIdx.x;
    if (e >= E) return;
    float4 uv = urec[e];
    unsigned pk = __float_as_uint(uv.w);
    if (pk == 0xFFFFFFFFu) return;
    int r = (int)(pk & 0xffffu);
    int s = (int)(pk >> 16);
    int rp = atomicAdd(&cur_r[r], 1);
    int sp = atomicAdd(&cur_s[s], 1);
    rrec[rp] = uv;                        // pk already (s<<16 | r)
    srec[sp] = make_float4(uv.x, uv.y, uv.z,
               __uint_as_float(((unsigned)r << 16) | (unsigned)s));
    map_sr[sp] = rp;
}

// table-driven edge MLP: m = bf16feat[gather] * lerp(tw_tbl, u);
// feat has row stride fstride ushorts (packed hA1 rows use 64).
__global__ __launch_bounds__(256) void k_edge_mlp_t(
    const float4* __restrict__ rec, const int* __restrict__ cnt,
    const float* __restrict__ tw_tbl, const unsigned short* __restrict__ feat,
    int fstride, float* __restrict__ acc)
{
    __shared__ float m_lds[256][33];
    __shared__ int   dst_lds[256];

    int na = *cnt;
    int tid = threadIdx.x;
    int stride = gridDim.x * 256;

    for (int base = blockIdx.x * 256; base < na; base += stride) {
        int i = base + tid;
        int dst = -1;
        if (i < na) {
            float4 rv = rec[i];
            unsigned pk = __float_as_uint(rv.w);
            int gn = pk >> 16;
            dst = (int)(pk & 0xffffu);
            float ss2 = rv.x * rv.x + rv.y * rv.y + rv.z * rv.z;
            float L = sqrtf(fmaxf(ss2, 1e-12f));
            float x = fminf(L * (INV_R * (float)TBL), (float)TBL - 1e-3f);
            int   i0 = (int)x;
            float f  = x - (float)i0;

            float fbuf[32];
            load_bf_row(feat + (size_t)gn * fstride, fbuf);

            const float4* r0 = (const float4*)(tw_tbl + (size_t)i0 * 32);
            const float4* r1 = r0 + 8;
#pragma unroll
            for (int q = 0; q < 8; q++) {
                float4 a = r0[q], b = r1[q];
                m_lds[tid][4 * q + 0] = fbuf[4*q+0] * (a.x + f * (b.x - a.x));
                m_lds[tid][4 * q + 1] = fbuf[4*q+1] * (a.y + f * (b.y - a.y));
                m_lds[tid][4 * q + 2] = fbuf[4*q+2] * (a.z + f * (b.z - a.z));
                m_lds[tid][4 * q + 3] = fbuf[4*q+3] * (a.w + f * (b.w - a.w));
            }
        }
        dst_lds[tid] = dst;
        __syncthreads();

        // run-length pre-reduced channel-parallel atomics
        int grp = tid >> 5;
        int c   = tid & 31;
        int b32 = grp * 32;
        int cur = -1; float run = 0.f;
        for (int k = 0; k < 32; k++) {
            int d = dst_lds[b32 + k];
            if (d != cur) {
                if (cur >= 0) unsafeAtomicAdd(&acc[(size_t)cur * 32 + c], run);
                cur = d;
                run = (d >= 0) ? m_lds[b32 + k][c] : 0.f;
            } else if (d >= 0) {
                run += m_lds[b32 + k][c];
            }
        }
        if (cur >= 0) unsafeAtomicAdd(&acc[(size_t)cur * 32 + c], run);
        __syncthreads();
    }
}

// node1: finalize A1, write bf16 A1-half of packed row, zero A2g2 row
__global__ __launch_bounds__(256) void k_node1(
    const float* __restrict__ h, float* __restrict__ A1,
    unsigned short* __restrict__ hA1_bf,
    const float* __restrict__ Wr1, float* __restrict__ e1,
    float* __restrict__ A2g2, int N)
{
    int i = blockIdx.x * blockDim.x + threadIdx.x;
    if (i >= N) return;
    float dot = 0.f;
    float v[32];
#pragma unroll
    for (int c = 0; c < 32; c++) {
        float t = A1[i * 32 + c] * INV_AVG + h[i * 32 + c];
        v[c] = t;
        A1[i * 32 + c] = t;
        A2g2[i * 32 + c] = 0.f;
        dot += t * Wr1[c];
    }
    e1[i] = dot;
    store_bf_row(hA1_bf + (size_t)i * 64 + 32, v);   // A1 half of packed row
}

// node2: A2 -> energies + g2 (in place) + bf16 mirror; zeroes g1 row
__global__ __launch_bounds__(256) void k_node2(
    float* __restrict__ A2g2, unsigned short* __restrict__ g2_bf,
    const float* __restrict__ A1,
    const float* __restrict__ Wm1, const float* __restrict__ Wm2,
    const float* __restrict__ e0, const float* __restrict__ e1,
    float* __restrict__ node_e, float* __restrict__ total,
    float* __restrict__ g1, const int* __restrict__ batch, int N)
{
    __shared__ float bins[32];
    if (threadIdx.x < 32) bins[threadIdx.x] = 0.f;
    __syncthreads();
    int i = blockIdx.x * blockDim.x + threadIdx.x;
    if (i < N) {
        float A2[32];
#pragma unroll
        for (int c = 0; c < 32; c++) {
            A2[c] = A2g2[i * 32 + c] * INV_AVG + A1[i * 32 + c];
            g1[i * 32 + c] = 0.f;
        }
        float z[16];
#pragma unroll
        for (int k = 0; k < 16; k++) {
            float v = 0.f;
#pragma unroll
            for (int c = 0; c < 32; c++) v += A2[c] * Wm1[c * 16 + k];
            z[k] = v;
        }
        float e2 = 0.f;
        float wk[16];
#pragma unroll
        for (int k = 0; k < 16; k++) {
            float sg = sigm(z[k]);
            float m2 = Wm2[k];
            e2 += z[k] * sg * m2;
            wk[k] = m2 * sg * (1.f + z[k] * (1.f - sg));  // Wm2 * silu'(z)
        }
        float g2v[32];
#pragma unroll
        for (int c = 0; c < 32; c++) {
            float v = 0.f;
#pragma unroll
            for (int k = 0; k < 16; k++) v += Wm1[c * 16 + k] * wk[k];
            g2v[c] = v;
            A2g2[i * 32 + c] = v;                          // g2 in place
        }
        store_bf_row(g2_bf + (size_t)i * 32, g2v);
        float ne = e0[i] + e1[i] + e2;
        node_e[i] = ne;
        atomicAdd(&bins[batch[i]], ne);
    }
    __syncthreads();
    if (threadIdx.x < 32) unsafeAtomicAdd(&total[threadIdx.x], bins[threadIdx.x]);
}

__global__ __launch_bounds__(256) void k_node3(
    float* __restrict__ g1, const float* __restrict__ g2,
    const float* __restrict__ Wr1, int N)
{
    int i = blockIdx.x * blockDim.x + threadIdx.x;
    if (i >= N) return;
#pragma unroll
    for (int c = 0; c < 32; c++)
        g1[i * 32 + c] = g1[i * 32 + c] * INV_AVG + g2[i * 32 + c] + Wr1[c];
}

// force pass 1 (receiver-sorted): r-side rows f32 (sorted, L1-hot); s-side
// is ONE packed 128B bf16 row (h|A1) -> a single random cacheline per edge.
__global__ __launch_bounds__(256) void k_force_r(
    const float4* __restrict__ rec, const int* __restrict__ cnt,
    const float* __restrict__ dta, const float* __restrict__ dtb,
    const unsigned short* __restrict__ hA1_bf,
    const float* __restrict__ g1, const float* __restrict__ g2,
    float* __restrict__ forces, float* __restrict__ sc_buf)
{
    __shared__ float f_lds[256][4];
    __shared__ int   dst_lds[256];

    int na = *cnt;
    int tid = threadIdx.x;
    int stride = gridDim.x * 256;

    for (int base = blockIdx.x * 256; base < na; base += stride) {
        int i = base + tid;
        int dstf = -1;
        float fx = 0.f, fy = 0.f, fz = 0.f;

        if (i < na) {
            float4 rv = rec[i];
            unsigned pk = __float_as_uint(rv.w);
            int r = (int)(pk & 0xffffu);
            int s = (int)(pk >> 16);
            float vx = rv.x, vy = rv.y, vz = rv.z;
            float ss2 = vx * vx + vy * vy + vz * vz;
            float scv = 0.f;
            if (ss2 > 1e-12f) {          // else grad of maximum() is 0
                float L = sqrtf(ss2);
                float invL = 1.f / L;
                float x = fminf(L * (INV_R * (float)TBL), (float)TBL - 1e-3f);
                int   i0 = (int)x;
                float f  = x - (float)i0;

                float hb[32], ab[32];
                const unsigned short* row = hA1_bf + (size_t)s * 64;
                load_bf_row(row, hb);        // h half
                load_bf_row(row + 32, ab);   // A1 half (same cacheline)

                const float4* a0 = (const float4*)(dta + (size_t)i0 * 32);
                const float4* a1 = a0 + 8;
                const float4* b0 = (const float4*)(dtb + (size_t)i0 * 32);
                const float4* b1 = b0 + 8;
                const float4* pa = (const float4*)(g1 + (size_t)r * 32);
                const float4* pc = (const float4*)(g2 + (size_t)r * 32);

                float dot = 0.f;
#pragma unroll
                for (int q = 0; q < 8; q++) {
                    float4 xg = pa[q], t0 = a0[q], t1 = a1[q];
                    dot += xg.x * hb[4*q+0] * (t0.x + f * (t1.x - t0.x))
                         + xg.y * hb[4*q+1] * (t0.y + f * (t1.y - t0.y))
                         + xg.z * hb[4*q+2] * (t0.z + f * (t1.z - t0.z))
                         + xg.w * hb[4*q+3] * (t0.w + f * (t1.w - t0.w));
                }
#pragma unroll
                for (int q = 0; q < 8; q++) {
                    float4 xg = pc[q], t0 = b0[q], t1 = b1[q];
                    dot += xg.x * ab[4*q+0] * (t0.x + f * (t1.x - t0.x))
                         + xg.y * ab[4*q+1] * (t0.y + f * (t1.y - t0.y))
                         + xg.z * ab[4*q+2] * (t0.z + f * (t1.z - t0.z))
                         + xg.w * ab[4*q+3] * (t0.w + f * (t1.w - t0.w));
                }

                scv = INV_AVG * INV_R * dot * invL;        // dE/dL / L
                fx = -scv * vx; fy = -scv * vy; fz = -scv * vz;
                dstf = r;
            }
            sc_buf[i] = scv;             // coalesced; consumed by k_force_s2
        }
        f_lds[tid][0] = fx; f_lds[tid][1] = fy; f_lds[tid][2] = fz;
        dst_lds[tid] = dstf;
        __syncthreads();

        // receiver scatter: run-length pre-reduced (records sorted by r)
        int grp = tid >> 5;
        int c   = tid & 31;
        if (c < 3) {
            int b32 = grp * 32;
            int cur = -1; float run = 0.f;
            for (int k = 0; k < 32; k++) {
                int d = dst_lds[b32 + k];
                if (d != cur) {
                    if (cur >= 0) unsafeAtomicAdd(&forces[3 * cur + c], run);
                    cur = d;
                    run = (d >= 0) ? f_lds[b32 + k][c] : 0.f;
                } else if (d >= 0) {
                    run += f_lds[b32 + k][c];
                }
            }
            if (cur >= 0) unsafeAtomicAdd(&forces[3 * cur + c], run);
        }
        __syncthreads();
    }
}

// force pass 2 (sender-sorted): cached scalar via srec->rrec map.
__global__ __launch_bounds__(256) void k_force_s2(
    const float4* __restrict__ rec, const int* __restrict__ cnt,
    const int* __restrict__ map_sr, const float* __restrict__ sc_buf,
    float* __restrict__ forces)
{
    __shared__ float f_lds[256][4];
    __shared__ int   dst_lds[256];

    int na = *cnt;
    int tid = threadIdx.x;
    int stride = gridDim.x * 256;

    for (int base = blockIdx.x * 256; base < na; base += stride) {
        int i = base + tid;
        int dstf = -1;
        float fx = 0.f, fy = 0.f, fz = 0.f;
        if (i < na) {
            float4 rv = rec[i];
            unsigned pk = __float_as_uint(rv.w);
            float scv = sc_buf[map_sr[i]];
            fx = scv * rv.x; fy = scv * rv.y; fz = scv * rv.z;
            dstf = (int)(pk & 0xffffu);   // own = sender
        }
        f_lds[tid][0] = fx; f_lds[tid][1] = fy; f_lds[tid][2] = fz;
        dst_lds[tid] = dstf;
        __syncthreads();

        int grp = tid >> 5;
        int c   = tid & 31;
        if (c < 3) {
            int b32 = grp * 32;
            int cur = -1; float run = 0.f;
            for (int k = 0; k < 32; k++) {
                int d = dst_lds[b32 + k];
                if (d != cur) {
                    if (cur >= 0) unsafeAtomicAdd(&forces[3 * cur + c], run);
                    cur = d;
                    run = (d >= 0) ? f_lds[b32 + k][c] : 0.f;
                } else if (d >= 0) {
                    run += f_lds[b32 + k][c];
                }
            }
            if (cur >= 0) unsafeAtomicAdd(&forces[3 * cur + c], run);
        }
        __syncthreads();
    }
}

extern "C" void kernel_launch(void* const* d_in, const int* in_sizes, int n_in,
                              void* d_out, int out_size, void* d_ws, size_t ws_size,
                              hipStream_t stream)
{
    const float* pos    = (const float*)d_in[0];
    const float* attrs  = (const float*)d_in[1];
    const float* shifts = (const float*)d_in[2];
    const float* ae     = (const float*)d_in[3];
    const float* Wemb   = (const float*)d_in[4];
    const float* W1a    = (const float*)d_in[5];
    const float* W2a    = (const float*)d_in[6];
    const float* Wr1    = (const float*)d_in[7];
    const float* W1b    = (const float*)d_in[8];
    const float* W2b    = (const float*)d_in[9];
    const float* Wm1    = (const float*)d_in[10];
    const float* Wm2    = (const float*)d_in[11];
    const int*   ei     = (const int*)d_in[12];
    const int*   batch  = (const int*)d_in[13];

    int N = in_sizes[13];
    int E = in_sizes[12] / 2;

    float* out    = (float*)d_out;
    float* total  = out;                 // 32
    float* node_e = out + 32;            // N
    float* forces = out + 32 + N;        // 3N

    float* ws = (float*)d_ws;
    size_t NC = (size_t)N * 32;
    float* h    = ws;            // N*32
    float* A1   = h  + NC;       // N*32 : acc then A1_0 in place
    float* A2g2 = A1 + NC;       // N*32 : A2 acc, then g2 in place
    float* g1   = A2g2 + NC;     // N*32 : acc then final in place
    float* e0   = g1 + NC;       // N
    float* e1   = e0 + N;        // N
    int* hist_r = (int*)(e1 + N);   // N
    int* hist_s = hist_r + N;       // N
    int* cur_r  = hist_s + N;       // N
    int* cur_s  = cur_r + N;        // N
    int* cnt    = cur_s + N;        // 1
    // align records to 16 B
    size_t ioff = ((size_t)(cnt + 1 - (int*)ws) + 3) & ~(size_t)3;
    float4* rrec = (float4*)(ws + ioff);   // E float4
    float4* srec = rrec + E;               // E float4
    float* tbl  = (float*)(srec + E);      // 4 tables of (TBL+1)*32
    size_t tstride = (size_t)(TBL + 1) * 32;
    float* twa = tbl;
    float* dta = twa + tstride;
    float* twb = dta + tstride;
    float* dtb = twb + tstride;
    int*   map_sr = (int*)(dtb + tstride);   // E
    float* sc_buf = (float*)(map_sr + E);    // E
    // packed bf16 rows: hA1_bf[n] = 128B {h row | A1 row}, 128B aligned
    unsigned short* hA1_bf = (unsigned short*)(sc_buf + E);  // 2*NC ushorts
    unsigned short* g2_bf  = hA1_bf + 2 * NC;                // NC ushorts
    int* part  = (int*)(g2_bf + NC);                         // 2*nbs ints
    int* bbase = part + 1024;                                // 2*nbs ints
    // urec aliases A2g2+g1 (2*NC floats == E float4s when E == 16N);
    // those accumulators are zeroed by node1/node2 after k_sort consumes urec
    float4* urec = (float4*)A2g2;

    int nb_n = (N + 255) / 256;
    int nb_e = (E + 255) / 256;
    int nb_g = nb_e < 2048 ? nb_e : 2048;   // grid-stride for edge passes
    int nb_t = ((TBL + 1) * 16 + 255) / 256;
    int nbs  = (N + SCHUNK - 1) / SCHUNK;   // scan chunks per histogram

    k_table<<<nb_t, 256, 0, stream>>>(W1a, W2a, W1b, W2b, twa, dta, twb, dtb,
                                      total);
    k_embed<<<nb_n, 256, 0, stream>>>(attrs, ae, Wemb, h, hA1_bf, e0,
                                      A1, forces, hist_r, hist_s, N);
    k_build<<<nb_e, 256, 0, stream>>>(pos, shifts, ei, E, hist_r, hist_s, urec);
    k_scan_a<<<2 * nbs, 256, 0, stream>>>(hist_r, hist_s, N, nbs, part);
    k_scan_b<<<1, 256, 0, stream>>>(part, nbs, bbase, cnt);
    k_scan_c<<<2 * nbs, 256, 0, stream>>>(hist_r, hist_s, N, nbs, bbase,
                                          cur_r, cur_s);
    k_sort<<<nb_e, 256, 0, stream>>>(urec, E, cur_r, cur_s, rrec, srec, map_sr);

    k_edge_mlp_t<<<nb_g, 256, 0, stream>>>(rrec, cnt, twa, hA1_bf, 64, A1);
    k_node1<<<nb_n, 256, 0, stream>>>(h, A1, hA1_bf, Wr1, e1, A2g2, N);
    k_edge_mlp_t<<<nb_g, 256, 0, stream>>>(rrec, cnt, twb, hA1_bf + 32, 64, A2g2);
    k_node2<<<nb_n, 256, 0, stream>>>(A2g2, g2_bf, A1, Wm1, Wm2, e0, e1,
                                      node_e, total, g1, batch, N);
    k_edge_mlp_t<<<nb_g, 256, 0, stream>>>(srec, cnt, twb, g2_bf, 32, g1);
    k_node3<<<nb_n, 256, 0, stream>>>(g1, A2g2, Wr1, N);
    k_force_r<<<nb_g, 256, 0, stream>>>(rrec, cnt, dta, dtb, hA1_bf,
                                        g1, A2g2, forces, sc_buf);
    k_force_s2<<<nb_g, 256, 0, stream>>>(srec, cnt, map_sr, sc_buf, forces);
}

// Round 13
// 270.983 us; speedup vs baseline: 2.6529x; 1.2112x over previous
//
#include <hip/hip_runtime.h>
#include <math.h>

constexpr float R_MAX   = 5.0f;
constexpr float INV_R   = 0.2f;                     // 1/R_MAX
constexpr float PI_F    = 3.14159265358979323846f;
constexpr float C0      = 0.632455532033675866f;    // sqrt(2/R_MAX)
constexpr float INV_AVG = 1.0f / 16.0f;             // 1/AVG_NEIGH
constexpr int   TBL     = 4096;                     // table resolution
constexpr int   SCHUNK  = 512;                      // scan chunk per block

__device__ __forceinline__ float sigm(float x) { return 1.0f / (1.0f + __expf(-x)); }

// f32 -> bf16 (round-to-nearest-even)
__device__ __forceinline__ unsigned f2bf(float x) {
    unsigned u = __float_as_uint(x);
    u += 0x7fffu + ((u >> 16) & 1u);
    return u >> 16;
}
__device__ __forceinline__ void store_bf_row(unsigned short* dst, const float* v) {
    uint4* o = (uint4*)dst;
#pragma unroll
    for (int w = 0; w < 4; w++) {
        uint4 t;
        t.x = f2bf(v[8*w+0]) | (f2bf(v[8*w+1]) << 16);
        t.y = f2bf(v[8*w+2]) | (f2bf(v[8*w+3]) << 16);
        t.z = f2bf(v[8*w+4]) | (f2bf(v[8*w+5]) << 16);
        t.w = f2bf(v[8*w+6]) | (f2bf(v[8*w+7]) << 16);
        o[w] = t;
    }
}
__device__ __forceinline__ void load_bf_row(const unsigned short* src, float* v) {
    const uint4* p = (const uint4*)src;
#pragma unroll
    for (int w = 0; w < 4; w++) {
        uint4 t = p[w];
        v[8*w+0] = __uint_as_float(t.x << 16);
        v[8*w+1] = __uint_as_float(t.x & 0xffff0000u);
        v[8*w+2] = __uint_as_float(t.y << 16);
        v[8*w+3] = __uint_as_float(t.y & 0xffff0000u);
        v[8*w+4] = __uint_as_float(t.z << 16);
        v[8*w+5] = __uint_as_float(t.z & 0xffff0000u);
        v[8*w+6] = __uint_as_float(t.w << 16);
        v[8*w+7] = __uint_as_float(t.w & 0xffff0000u);
    }
}

// ef plus d(ef)/dL (exact, used only in the table path)
__device__ __forceinline__ void radial_ef_d(float u, float invL, float* ef, float* dd) {
    float u2 = u * u, u4 = u2 * u2, u5 = u4 * u;
    float fc  = 1.f - 21.f * u5 + 35.f * u5 * u - 15.f * u5 * u2;
    float om  = 1.f - u;
    float fcp = -105.f * u4 * om * om;   // dfc/du
    float sp, cp;
    sincosf(PI_F * u, &sp, &cp);
    float twoc = 2.f * cp;
    float a = C0 * invL;
    float s_nm1 = 0.f, s_n = sp, c_nm1 = 1.f, c_n = cp;
#pragma unroll
    for (int n = 1; n <= 8; n++) {
        ef[n - 1] = a * s_n * fc;
        dd[n - 1] = a * fc * ((float)n * PI_F * INV_R * c_n - s_n * invL)
                  + a * s_n * fcp * INV_R;
        if (n < 8) {
            float sn2 = twoc * s_n - s_nm1; s_nm1 = s_n; s_n = sn2;
            float cn2 = twoc * c_n - c_nm1; c_nm1 = c_n; c_n = cn2;
        }
    }
}

// Fused setup: blocks [0,nbt) build tables, [nbt,nbt+nbn) embed nodes,
// [nbt+nbn, ...) build edge histograms + urec. All three independent.
__global__ __launch_bounds__(256) void k_setup(
    // table args
    const float* __restrict__ W1a, const float* __restrict__ W2a,
    const float* __restrict__ W1b, const float* __restrict__ W2b,
    float* __restrict__ twa, float* __restrict__ dta,
    float* __restrict__ twb, float* __restrict__ dtb,
    float* __restrict__ total,
    // embed args
    const float* __restrict__ attrs, const float* __restrict__ ae,
    const float* __restrict__ Wemb, float* __restrict__ h,
    unsigned short* __restrict__ hA1_bf, float* __restrict__ e0,
    float* __restrict__ A1, float* __restrict__ forces, int N,
    // build args
    const float* __restrict__ pos, const float* __restrict__ shifts,
    const int* __restrict__ ei, int E,
    int* __restrict__ hist_r, int* __restrict__ hist_s,
    float4* __restrict__ urec,
    int nbt, int nbn)
{
    int b = blockIdx.x;
    if (b < nbt) {
        // ---------------- table path ----------------
        if (b == 0 && threadIdx.x < 32) total[threadIdx.x] = 0.f;
        int gid = b * 256 + threadIdx.x;
        if (gid >= (TBL + 1) * 16) return;
        int cg = gid & 7;
        int l  = (gid >> 3) & 1;
        int t  = gid >> 4;
        float u = fmaxf((float)t / (float)TBL, 1e-4f);
        float L = u * R_MAX;
        float invL = 1.f / L;
        float ef[8], dd[8], efu[8];
        radial_ef_d(u, invL, ef, dd);
#pragma unroll
        for (int k = 0; k < 8; k++) efu[k] = dd[k] * R_MAX;
        const float* W1 = l ? W1b : W1a;
        const float* W2 = l ? W2b : W2a;
        float*     tw_o = l ? twb : twa;
        float*     dt_o = l ? dtb : dta;
        float tw[4] = {0.f, 0.f, 0.f, 0.f};
        float dt[4] = {0.f, 0.f, 0.f, 0.f};
        for (int j = 0; j < 64; j++) {
            float s1 = 0.f, du = 0.f;
#pragma unroll
            for (int k = 0; k < 8; k++) {
                float w = W1[k * 64 + j];
                s1 += ef[k] * w; du += efu[k] * w;
            }
            float sg  = sigm(s1);
            float act = s1 * sg;
            float dj  = sg * (1.f + s1 * (1.f - sg)) * du;
            const float* w2 = W2 + j * 96 + cg * 4;
#pragma unroll
            for (int q = 0; q < 4; q++) {
                tw[q] += act * w2[q];
                dt[q] += dj * w2[q];
            }
        }
#pragma unroll
        for (int q = 0; q < 4; q++) {
            tw_o[(size_t)t * 32 + cg * 4 + q] = tw[q];
            dt_o[(size_t)t * 32 + cg * 4 + q] = dt[q];
        }
    } else if (b < nbt + nbn) {
        // ---------------- embed path ----------------
        int i = (b - nbt) * 256 + threadIdx.x;
        if (i >= N) return;
        float a[10];
#pragma unroll
        for (int k = 0; k < 10; k++) a[k] = attrs[i * 10 + k];
        float e = 0.f;
#pragma unroll
        for (int k = 0; k < 10; k++) e += a[k] * ae[k];
        e0[i] = e;
        float v[32];
#pragma unroll
        for (int c = 0; c < 32; c++) {
            float t = 0.f;
#pragma unroll
            for (int k = 0; k < 10; k++) t += a[k] * Wemb[k * 32 + c];
            v[c] = t;
            h[i * 32 + c] = t;
            A1[i * 32 + c] = 0.f;
        }
        store_bf_row(hA1_bf + (size_t)i * 64, v);   // h half of packed row
        forces[3*i+0] = 0.f; forces[3*i+1] = 0.f; forces[3*i+2] = 0.f;
        hist_r[i] = 0; hist_s[i] = 0;
    } else {
        // ---------------- build path ----------------
        int e = (b - nbt - nbn) * 256 + threadIdx.x;
        if (e >= E) return;
        int s = ei[e], r = ei[E + e];
        float vx = pos[3*r+0] - pos[3*s+0] + shifts[3*e+0];
        float vy = pos[3*r+1] - pos[3*s+1] + shifts[3*e+1];
        float vz = pos[3*r+2] - pos[3*s+2] + shifts[3*e+2];
        float ss2 = vx*vx + vy*vy + vz*vz;
        float L = sqrtf(fmaxf(ss2, 1e-12f));
        if (L * INV_R < 1.f) {
            atomicAdd(&hist_r[r], 1);
            atomicAdd(&hist_s[s], 1);
            urec[e] = make_float4(vx, vy, vz,
                      __uint_as_float(((unsigned)s << 16) | (unsigned)r));
        } else {
            urec[e] = make_float4(0.f, 0.f, 0.f, __uint_as_float(0xFFFFFFFFu));
        }
    }
}

// hierarchical scan stage A: per-block chunk sums (both hists in one grid)
__global__ __launch_bounds__(256) void k_scan_a(
    const int* __restrict__ hist_r, const int* __restrict__ hist_s,
    int n, int nb, int* __restrict__ part)
{
    __shared__ int red[256];
    int b = blockIdx.x;
    const int* hist = (b < nb) ? hist_r : hist_s;
    int cb = (b < nb) ? b : b - nb;
    int base = cb * SCHUNK;
    int t = threadIdx.x;
    int i0 = base + 2 * t, i1 = i0 + 1;
    int sum = 0;
    if (i0 < n) sum += hist[i0];
    if (i1 < n) sum += hist[i1];
    red[t] = sum;
    __syncthreads();
    for (int off = 128; off > 0; off >>= 1) {
        if (t < off) red[t] += red[t + off];
        __syncthreads();
    }
    if (t == 0) part[b] = red[0];
}

// stage B: exclusive scan of the block sums (in LDS, one block); writes cnt
__global__ __launch_bounds__(256) void k_scan_b(
    const int* __restrict__ part, int nb, int* __restrict__ bbase,
    int* __restrict__ cnt)
{
    __shared__ int buf[512];   // 2*nb <= 512
    int t = threadIdx.x;
    for (int k = t; k < 2 * nb; k += 256) buf[k] = part[k];
    __syncthreads();
    if (t < 2) {
        int base = t * nb;
        int run = 0;
        for (int k = 0; k < nb; k++) {
            int v = buf[base + k];
            buf[base + k] = run;
            run += v;
        }
        if (t == 0) *cnt = run;   // total active
    }
    __syncthreads();
    for (int k = t; k < 2 * nb; k += 256) bbase[k] = buf[k];
}

// stage C: per-chunk exclusive scan + block base -> cursor arrays
__global__ __launch_bounds__(256) void k_scan_c(
    const int* __restrict__ hist_r, const int* __restrict__ hist_s,
    int n, int nb, const int* __restrict__ bbase,
    int* __restrict__ cur_r, int* __restrict__ cur_s)
{
    __shared__ int sc[256];
    int b = blockIdx.x;
    const int* hist = (b < nb) ? hist_r : hist_s;
    int*       cur  = (b < nb) ? cur_r : cur_s;
    int cb = (b < nb) ? b : b - nb;
    int base = cb * SCHUNK;
    int t = threadIdx.x;
    int i0 = base + 2 * t, i1 = i0 + 1;
    int e0 = (i0 < n) ? hist[i0] : 0;
    int e1 = (i1 < n) ? hist[i1] : 0;
    int ts = e0 + e1;
    sc[t] = ts;
    __syncthreads();
    for (int off = 1; off < 256; off <<= 1) {
        int v = (t >= off) ? sc[t - off] : 0;
        __syncthreads();
        sc[t] += v;
        __syncthreads();
    }
    int excl = sc[t] - ts + bbase[b];
    if (i0 < n) cur[i0] = excl;
    if (i1 < n) cur[i1] = excl + e0;
}

// pass 0b: scatter urec into receiver-sorted and sender-sorted records.
__global__ __launch_bounds__(256) void k_sort(
    const float4* __restrict__ urec, int E,
    int* __restrict__ cur_r, int* __restrict__ cur_s,
    float4* __restrict__ rrec, float4* __restrict__ srec,
    int* __restrict__ map_sr)
{
    int e = blockIdx.x * 256 + threadIdx.x;
    if (e >= E) return;
    float4 uv = urec[e];
    unsigned pk = __float_as_uint(uv.w);
    if (pk == 0xFFFFFFFFu) return;
    int r = (int)(pk & 0xffffu);
    int s = (int)(pk >> 16);
    int rp = atomicAdd(&cur_r[r], 1);
    int sp = atomicAdd(&cur_s[s], 1);
    rrec[rp] = uv;                        // pk already (s<<16 | r)
    srec[sp] = make_float4(uv.x, uv.y, uv.z,
               __uint_as_float(((unsigned)r << 16) | (unsigned)s));
    map_sr[sp] = rp;
}

// table-driven edge MLP (passes 1,2 over rrec): m = bf16feat[gather]*lerp(tw)
__global__ __launch_bounds__(256) void k_edge_mlp_t(
    const float4* __restrict__ rec, const int* __restrict__ cnt,
    const float* __restrict__ tw_tbl, const unsigned short* __restrict__ feat,
    int fstride, float* __restrict__ acc)
{
    __shared__ float m_lds[256][33];
    __shared__ int   dst_lds[256];

    int na = *cnt;
    int tid = threadIdx.x;
    int stride = gridDim.x * 256;

    for (int base = blockIdx.x * 256; base < na; base += stride) {
        int i = base + tid;
        int dst = -1;
        if (i < na) {
            float4 rv = rec[i];
            unsigned pk = __float_as_uint(rv.w);
            int gn = pk >> 16;
            dst = (int)(pk & 0xffffu);
            float ss2 = rv.x * rv.x + rv.y * rv.y + rv.z * rv.z;
            float L = sqrtf(fmaxf(ss2, 1e-12f));
            float x = fminf(L * (INV_R * (float)TBL), (float)TBL - 1e-3f);
            int   i0 = (int)x;
            float f  = x - (float)i0;

            float fbuf[32];
            load_bf_row(feat + (size_t)gn * fstride, fbuf);

            const float4* r0 = (const float4*)(tw_tbl + (size_t)i0 * 32);
            const float4* r1 = r0 + 8;
#pragma unroll
            for (int q = 0; q < 8; q++) {
                float4 a = r0[q], b = r1[q];
                m_lds[tid][4 * q + 0] = fbuf[4*q+0] * (a.x + f * (b.x - a.x));
                m_lds[tid][4 * q + 1] = fbuf[4*q+1] * (a.y + f * (b.y - a.y));
                m_lds[tid][4 * q + 2] = fbuf[4*q+2] * (a.z + f * (b.z - a.z));
                m_lds[tid][4 * q + 3] = fbuf[4*q+3] * (a.w + f * (b.w - a.w));
            }
        }
        dst_lds[tid] = dst;
        __syncthreads();

        int grp = tid >> 5;
        int c   = tid & 31;
        int b32 = grp * 32;
        int cur = -1; float run = 0.f;
        for (int k = 0; k < 32; k++) {
            int d = dst_lds[b32 + k];
            if (d != cur) {
                if (cur >= 0) unsafeAtomicAdd(&acc[(size_t)cur * 32 + c], run);
                cur = d;
                run = (d >= 0) ? m_lds[b32 + k][c] : 0.f;
            } else if (d >= 0) {
                run += m_lds[b32 + k][c];
            }
        }
        if (cur >= 0) unsafeAtomicAdd(&acc[(size_t)cur * 32 + c], run);
        __syncthreads();
    }
}

// node1: finalize A1, write bf16 A1-half of packed row, zero A2g2 row
__global__ __launch_bounds__(256) void k_node1(
    const float* __restrict__ h, float* __restrict__ A1,
    unsigned short* __restrict__ hA1_bf,
    const float* __restrict__ Wr1, float* __restrict__ e1,
    float* __restrict__ A2g2, int N)
{
    int i = blockIdx.x * blockDim.x + threadIdx.x;
    if (i >= N) return;
    float dot = 0.f;
    float v[32];
#pragma unroll
    for (int c = 0; c < 32; c++) {
        float t = A1[i * 32 + c] * INV_AVG + h[i * 32 + c];
        v[c] = t;
        A1[i * 32 + c] = t;
        A2g2[i * 32 + c] = 0.f;
        dot += t * Wr1[c];
    }
    e1[i] = dot;
    store_bf_row(hA1_bf + (size_t)i * 64 + 32, v);   // A1 half of packed row
}

// node2: A2 -> energies + g2 (in place) + bf16 mirror; zeroes g1 row
__global__ __launch_bounds__(256) void k_node2(
    float* __restrict__ A2g2, unsigned short* __restrict__ g2_bf,
    const float* __restrict__ A1,
    const float* __restrict__ Wm1, const float* __restrict__ Wm2,
    const float* __restrict__ e0, const float* __restrict__ e1,
    float* __restrict__ node_e, float* __restrict__ total,
    float* __restrict__ g1, const int* __restrict__ batch, int N)
{
    __shared__ float bins[32];
    if (threadIdx.x < 32) bins[threadIdx.x] = 0.f;
    __syncthreads();
    int i = blockIdx.x * blockDim.x + threadIdx.x;
    if (i < N) {
        float A2[32];
#pragma unroll
        for (int c = 0; c < 32; c++) {
            A2[c] = A2g2[i * 32 + c] * INV_AVG + A1[i * 32 + c];
            g1[i * 32 + c] = 0.f;
        }
        float z[16];
#pragma unroll
        for (int k = 0; k < 16; k++) {
            float v = 0.f;
#pragma unroll
            for (int c = 0; c < 32; c++) v += A2[c] * Wm1[c * 16 + k];
            z[k] = v;
        }
        float e2 = 0.f;
        float wk[16];
#pragma unroll
        for (int k = 0; k < 16; k++) {
            float sg = sigm(z[k]);
            float m2 = Wm2[k];
            e2 += z[k] * sg * m2;
            wk[k] = m2 * sg * (1.f + z[k] * (1.f - sg));  // Wm2 * silu'(z)
        }
        float g2v[32];
#pragma unroll
        for (int c = 0; c < 32; c++) {
            float v = 0.f;
#pragma unroll
            for (int k = 0; k < 16; k++) v += Wm1[c * 16 + k] * wk[k];
            g2v[c] = v;
            A2g2[i * 32 + c] = v;                          // g2 in place
        }
        store_bf_row(g2_bf + (size_t)i * 32, g2v);
        float ne = e0[i] + e1[i] + e2;
        node_e[i] = ne;
        atomicAdd(&bins[batch[i]], ne);
    }
    __syncthreads();
    if (threadIdx.x < 32) unsafeAtomicAdd(&total[threadIdx.x], bins[threadIdx.x]);
}

// mlp pass 3 FUSED with force branch-b (over srec).
// Shares the random g2_bf[r] gather between the g1 message and
// dot_b = g2[r]·A1[s]·lerp(dtb); A1[s] is the SORTED side here (L1-hot).
// dot_b partial goes to dotb_buf[rrec slot] via map_sr.
__global__ __launch_bounds__(256) void k_mlp3fb(
    const float4* __restrict__ rec, const int* __restrict__ cnt,
    const float* __restrict__ tw_tbl, const float* __restrict__ dt_tbl,
    const unsigned short* __restrict__ g2_bf,
    const unsigned short* __restrict__ hA1_bf,
    const int* __restrict__ map_sr,
    float* __restrict__ g1acc, float* __restrict__ dotb_buf)
{
    __shared__ float m_lds[256][33];
    __shared__ int   dst_lds[256];

    int na = *cnt;
    int tid = threadIdx.x;
    int stride = gridDim.x * 256;

    for (int base = blockIdx.x * 256; base < na; base += stride) {
        int i = base + tid;
        int dst = -1;
        if (i < na) {
            float4 rv = rec[i];
            unsigned pk = __float_as_uint(rv.w);
            int r = (int)(pk >> 16);       // gather node (receiver)
            dst = (int)(pk & 0xffffu);     // scatter node (sender)
            float ss2 = rv.x * rv.x + rv.y * rv.y + rv.z * rv.z;
            float L = sqrtf(fmaxf(ss2, 1e-12f));
            float x = fminf(L * (INV_R * (float)TBL), (float)TBL - 1e-3f);
            int   i0 = (int)x;
            float f  = x - (float)i0;

            float gb[32], ab[32];
            load_bf_row(g2_bf + (size_t)r * 32, gb);            // random 64B
            load_bf_row(hA1_bf + (size_t)dst * 64 + 32, ab);    // sorted, L1-hot

            const float4* r0 = (const float4*)(tw_tbl + (size_t)i0 * 32);
            const float4* r1 = r0 + 8;
            const float4* d0 = (const float4*)(dt_tbl + (size_t)i0 * 32);
            const float4* d1 = d0 + 8;
            float dotb = 0.f;
#pragma unroll
            for (int q = 0; q < 8; q++) {
                float4 a = r0[q], b = r1[q], da = d0[q], db = d1[q];
                float t0 = a.x + f * (b.x - a.x);
                float t1 = a.y + f * (b.y - a.y);
                float t2 = a.z + f * (b.z - a.z);
                float t3 = a.w + f * (b.w - a.w);
                m_lds[tid][4*q+0] = gb[4*q+0] * t0;
                m_lds[tid][4*q+1] = gb[4*q+1] * t1;
                m_lds[tid][4*q+2] = gb[4*q+2] * t2;
                m_lds[tid][4*q+3] = gb[4*q+3] * t3;
                dotb += gb[4*q+0] * ab[4*q+0] * (da.x + f * (db.x - da.x))
                      + gb[4*q+1] * ab[4*q+1] * (da.y + f * (db.y - da.y))
                      + gb[4*q+2] * ab[4*q+2] * (da.z + f * (db.z - da.z))
                      + gb[4*q+3] * ab[4*q+3] * (da.w + f * (db.w - da.w));
            }
            dotb_buf[map_sr[i]] = dotb;    // random 4B; consumed by force_ra
        }
        dst_lds[tid] = dst;
        __syncthreads();

        int grp = tid >> 5;
        int c   = tid & 31;
        int b32 = grp * 32;
        int cur = -1; float run = 0.f;
        for (int k = 0; k < 32; k++) {
            int d = dst_lds[b32 + k];
            if (d != cur) {
                if (cur >= 0) unsafeAtomicAdd(&g1acc[(size_t)cur * 32 + c], run);
                cur = d;
                run = (d >= 0) ? m_lds[b32 + k][c] : 0.f;
            } else if (d >= 0) {
                run += m_lds[b32 + k][c];
            }
        }
        if (cur >= 0) unsafeAtomicAdd(&g1acc[(size_t)cur * 32 + c], run);
        __syncthreads();
    }
}

// force pass 1 (receiver-sorted): branch-a dot with INLINE g1 finalize
// (g1f = g1acc/16 + g2 + Wr1, rows sorted/L1-hot; replaces node3).
// Adds dotb partial; scatters -scv*v to receivers; caches scv in sc_buf.
__global__ __launch_bounds__(256) void k_force_ra(
    const float4* __restrict__ rec, const int* __restrict__ cnt,
    const float* __restrict__ dta,
    const unsigned short* __restrict__ hA1_bf,
    const float* __restrict__ g1acc, const float* __restrict__ g2,
    const float* __restrict__ Wr1, const float* __restrict__ dotb_buf,
    float* __restrict__ forces, float* __restrict__ sc_buf)
{
    __shared__ float f_lds[256][4];
    __shared__ int   dst_lds[256];

    int na = *cnt;
    int tid = threadIdx.x;
    int stride = gridDim.x * 256;
    const float4* w4 = (const float4*)Wr1;   // wave-uniform scalar loads

    for (int base = blockIdx.x * 256; base < na; base += stride) {
        int i = base + tid;
        int dstf = -1;
        float fx = 0.f, fy = 0.f, fz = 0.f;

        if (i < na) {
            float4 rv = rec[i];
            unsigned pk = __float_as_uint(rv.w);
            int r = (int)(pk & 0xffffu);
            int s = (int)(pk >> 16);
            float vx = rv.x, vy = rv.y, vz = rv.z;
            float ss2 = vx * vx + vy * vy + vz * vz;
            float scv = 0.f;
            if (ss2 > 1e-12f) {          // else grad of maximum() is 0
                float L = sqrtf(ss2);
                float invL = 1.f / L;
                float x = fminf(L * (INV_R * (float)TBL), (float)TBL - 1e-3f);
                int   i0 = (int)x;
                float f  = x - (float)i0;

                float hb[32];
                load_bf_row(hA1_bf + (size_t)s * 64, hb);   // random 64B (1 sector)

                const float4* a0 = (const float4*)(dta + (size_t)i0 * 32);
                const float4* a1 = a0 + 8;
                const float4* pa = (const float4*)(g1acc + (size_t)r * 32);
                const float4* pc = (const float4*)(g2 + (size_t)r * 32);

                float dot = dotb_buf[i];                    // branch-b partial
#pragma unroll
                for (int q = 0; q < 8; q++) {
                    float4 ga = pa[q], gc = pc[q], wr = w4[q];
                    float4 t0 = a0[q], t1 = a1[q];
                    float g0 = ga.x * INV_AVG + gc.x + wr.x;  // inline node3
                    float g1v = ga.y * INV_AVG + gc.y + wr.y;
                    float g2v = ga.z * INV_AVG + gc.z + wr.z;
                    float g3 = ga.w * INV_AVG + gc.w + wr.w;
                    dot += g0 * hb[4*q+0] * (t0.x + f * (t1.x - t0.x))
                         + g1v * hb[4*q+1] * (t0.y + f * (t1.y - t0.y))
                         + g2v * hb[4*q+2] * (t0.z + f * (t1.z - t0.z))
                         + g3 * hb[4*q+3] * (t0.w + f * (t1.w - t0.w));
                }

                scv = INV_AVG * INV_R * dot * invL;        // dE/dL / L
                fx = -scv * vx; fy = -scv * vy; fz = -scv * vz;
                dstf = r;
            }
            sc_buf[i] = scv;             // coalesced; consumed by k_force_s2
        }
        f_lds[tid][0] = fx; f_lds[tid][1] = fy; f_lds[tid][2] = fz;
        dst_lds[tid] = dstf;
        __syncthreads();

        int grp = tid >> 5;
        int c   = tid & 31;
        if (c < 3) {
            int b32 = grp * 32;
            int cur = -1; float run = 0.f;
            for (int k = 0; k < 32; k++) {
                int d = dst_lds[b32 + k];
                if (d != cur) {
                    if (cur >= 0) unsafeAtomicAdd(&forces[3 * cur + c], run);
                    cur = d;
                    run = (d >= 0) ? f_lds[b32 + k][c] : 0.f;
                } else if (d >= 0) {
                    run += f_lds[b32 + k][c];
                }
            }
            if (cur >= 0) unsafeAtomicAdd(&forces[3 * cur + c], run);
        }
        __syncthreads();
    }
}

// force pass 2 (sender-sorted): cached scalar via srec->rrec map.
__global__ __launch_bounds__(256) void k_force_s2(
    const float4* __restrict__ rec, const int* __restrict__ cnt,
    const int* __restrict__ map_sr, const float* __restrict__ sc_buf,
    float* __restrict__ forces)
{
    __shared__ float f_lds[256][4];
    __shared__ int   dst_lds[256];

    int na = *cnt;
    int tid = threadIdx.x;
    int stride = gridDim.x * 256;

    for (int base = blockIdx.x * 256; base < na; base += stride) {
        int i = base + tid;
        int dstf = -1;
        float fx = 0.f, fy = 0.f, fz = 0.f;
        if (i < na) {
            float4 rv = rec[i];
            unsigned pk = __float_as_uint(rv.w);
            float scv = sc_buf[map_sr[i]];
            fx = scv * rv.x; fy = scv * rv.y; fz = scv * rv.z;
            dstf = (int)(pk & 0xffffu);   // own = sender
        }
        f_lds[tid][0] = fx; f_lds[tid][1] = fy; f_lds[tid][2] = fz;
        dst_lds[tid] = dstf;
        __syncthreads();

        int grp = tid >> 5;
        int c   = tid & 31;
        if (c < 3) {
            int b32 = grp * 32;
            int cur = -1; float run = 0.f;
            for (int k = 0; k < 32; k++) {
                int d = dst_lds[b32 + k];
                if (d != cur) {
                    if (cur >= 0) unsafeAtomicAdd(&forces[3 * cur + c], run);
                    cur = d;
                    run = (d >= 0) ? f_lds[b32 + k][c] : 0.f;
                } else if (d >= 0) {
                    run += f_lds[b32 + k][c];
                }
            }
            if (cur >= 0) unsafeAtomicAdd(&forces[3 * cur + c], run);
        }
        __syncthreads();
    }
}

extern "C" void kernel_launch(void* const* d_in, const int* in_sizes, int n_in,
                              void* d_out, int out_size, void* d_ws, size_t ws_size,
                              hipStream_t stream)
{
    const float* pos    = (const float*)d_in[0];
    const float* attrs  = (const float*)d_in[1];
    const float* shifts = (const float*)d_in[2];
    const float* ae     = (const float*)d_in[3];
    const float* Wemb   = (const float*)d_in[4];
    const float* W1a    = (const float*)d_in[5];
    const float* W2a    = (const float*)d_in[6];
    const float* Wr1    = (const float*)d_in[7];
    const float* W1b    = (const float*)d_in[8];
    const float* W2b    = (const float*)d_in[9];
    const float* Wm1    = (const float*)d_in[10];
    const float* Wm2    = (const float*)d_in[11];
    const int*   ei     = (const int*)d_in[12];
    const int*   batch  = (const int*)d_in[13];

    int N = in_sizes[13];
    int E = in_sizes[12] / 2;

    float* out    = (float*)d_out;
    float* total  = out;                 // 32
    float* node_e = out + 32;            // N
    float* forces = out + 32 + N;        // 3N

    float* ws = (float*)d_ws;
    size_t NC = (size_t)N * 32;
    float* h    = ws;            // N*32
    float* A1   = h  + NC;       // N*32 : acc then A1_0 in place
    float* A2g2 = A1 + NC;       // N*32 : A2 acc, then g2 in place
    float* g1   = A2g2 + NC;     // N*32 : acc (finalized inline in force_ra)
    float* e0   = g1 + NC;       // N
    float* e1   = e0 + N;        // N
    int* hist_r = (int*)(e1 + N);   // N
    int* hist_s = hist_r + N;       // N
    int* cur_r  = hist_s + N;       // N
    int* cur_s  = cur_r + N;        // N
    int* cnt    = cur_s + N;        // 1
    size_t ioff = ((size_t)(cnt + 1 - (int*)ws) + 3) & ~(size_t)3;
    float4* rrec = (float4*)(ws + ioff);   // E float4
    float4* srec = rrec + E;               // E float4
    float* tbl  = (float*)(srec + E);      // 4 tables of (TBL+1)*32
    size_t tstride = (size_t)(TBL + 1) * 32;
    float* twa = tbl;
    float* dta = twa + tstride;
    float* twb = dta + tstride;
    float* dtb = twb + tstride;
    int*   map_sr = (int*)(dtb + tstride);   // E
    float* sc_buf = (float*)(map_sr + E);    // E
    unsigned short* hA1_bf = (unsigned short*)(sc_buf + E);  // 2*NC ushorts
    unsigned short* g2_bf  = hA1_bf + 2 * NC;                // NC ushorts
    int* part  = (int*)(g2_bf + NC);                         // <=1024 ints
    int* bbase = part + 1024;                                // <=1024 ints
    float* dotb_buf = (float*)(bbase + 1024);                // E floats
    // urec aliases A2g2+g1 (2*NC floats == E float4s when E == 16N);
    // those accumulators are zeroed by node1/node2 after k_sort consumes urec
    float4* urec = (float4*)A2g2;

    int nb_n = (N + 255) / 256;
    int nb_e = (E + 255) / 256;
    int nb_g = nb_e < 2048 ? nb_e : 2048;   // grid-stride for edge passes
    int nb_t = ((TBL + 1) * 16 + 255) / 256;
    int nbs  = (N + SCHUNK - 1) / SCHUNK;   // scan chunks per histogram

    k_setup<<<nb_t + nb_n + nb_e, 256, 0, stream>>>(
        W1a, W2a, W1b, W2b, twa, dta, twb, dtb, total,
        attrs, ae, Wemb, h, hA1_bf, e0, A1, forces, N,
        pos, shifts, ei, E, hist_r, hist_s, urec, nb_t, nb_n);
    k_scan_a<<<2 * nbs, 256, 0, stream>>>(hist_r, hist_s, N, nbs, part);
    k_scan_b<<<1, 256, 0, stream>>>(part, nbs, bbase, cnt);
    k_scan_c<<<2 * nbs, 256, 0, stream>>>(hist_r, hist_s, N, nbs, bbase,
                                          cur_r, cur_s);
    k_sort<<<nb_e, 256, 0, stream>>>(urec, E, cur_r, cur_s, rrec, srec, map_sr);

    k_edge_mlp_t<<<nb_g, 256, 0, stream>>>(rrec, cnt, twa, hA1_bf, 64, A1);
    k_node1<<<nb_n, 256, 0, stream>>>(h, A1, hA1_bf, Wr1, e1, A2g2, N);
    k_edge_mlp_t<<<nb_g, 256, 0, stream>>>(rrec, cnt, twb, hA1_bf + 32, 64, A2g2);
    k_node2<<<nb_n, 256, 0, stream>>>(A2g2, g2_bf, A1, Wm1, Wm2, e0, e1,
                                      node_e, total, g1, batch, N);
    k_mlp3fb<<<nb_g, 256, 0, stream>>>(srec, cnt, twb, dtb, g2_bf, hA1_bf,
                                       map_sr, g1, dotb_buf);
    k_force_ra<<<nb_g, 256, 0, stream>>>(rrec, cnt, dta, hA1_bf,
                                         g1, A2g2, Wr1, dotb_buf,
                                         forces, sc_buf);
    k_force_s2<<<nb_g, 256, 0, stream>>>(srec, cnt, map_sr, sc_buf, forces);
}

// Round 14
// 268.583 us; speedup vs baseline: 2.6766x; 1.0089x over previous
//
#include <hip/hip_runtime.h>
#include <math.h>

constexpr float R_MAX   = 5.0f;
constexpr float INV_R   = 0.2f;                     // 1/R_MAX
constexpr float PI_F    = 3.14159265358979323846f;
constexpr float C0      = 0.632455532033675866f;    // sqrt(2/R_MAX)
constexpr float INV_AVG = 1.0f / 16.0f;             // 1/AVG_NEIGH
constexpr int   TBL     = 4096;                     // table resolution
constexpr int   SCHUNK  = 512;                      // scan chunk per block

__device__ __forceinline__ float sigm(float x) { return 1.0f / (1.0f + __expf(-x)); }

// f32 -> bf16 (round-to-nearest-even)
__device__ __forceinline__ unsigned f2bf(float x) {
    unsigned u = __float_as_uint(x);
    u += 0x7fffu + ((u >> 16) & 1u);
    return u >> 16;
}
__device__ __forceinline__ void store_bf_row(unsigned short* dst, const float* v) {
    uint4* o = (uint4*)dst;
#pragma unroll
    for (int w = 0; w < 4; w++) {
        uint4 t;
        t.x = f2bf(v[8*w+0]) | (f2bf(v[8*w+1]) << 16);
        t.y = f2bf(v[8*w+2]) | (f2bf(v[8*w+3]) << 16);
        t.z = f2bf(v[8*w+4]) | (f2bf(v[8*w+5]) << 16);
        t.w = f2bf(v[8*w+6]) | (f2bf(v[8*w+7]) << 16);
        o[w] = t;
    }
}
__device__ __forceinline__ void load_bf_row(const unsigned short* src, float* v) {
    const uint4* p = (const uint4*)src;
#pragma unroll
    for (int w = 0; w < 4; w++) {
        uint4 t = p[w];
        v[8*w+0] = __uint_as_float(t.x << 16);
        v[8*w+1] = __uint_as_float(t.x & 0xffff0000u);
        v[8*w+2] = __uint_as_float(t.y << 16);
        v[8*w+3] = __uint_as_float(t.y & 0xffff0000u);
        v[8*w+4] = __uint_as_float(t.z << 16);
        v[8*w+5] = __uint_as_float(t.z & 0xffff0000u);
        v[8*w+6] = __uint_as_float(t.w << 16);
        v[8*w+7] = __uint_as_float(t.w & 0xffff0000u);
    }
}

// ef plus d(ef)/dL (exact, used only in the table path)
__device__ __forceinline__ void radial_ef_d(float u, float invL, float* ef, float* dd) {
    float u2 = u * u, u4 = u2 * u2, u5 = u4 * u;
    float fc  = 1.f - 21.f * u5 + 35.f * u5 * u - 15.f * u5 * u2;
    float om  = 1.f - u;
    float fcp = -105.f * u4 * om * om;   // dfc/du
    float sp, cp;
    sincosf(PI_F * u, &sp, &cp);
    float twoc = 2.f * cp;
    float a = C0 * invL;
    float s_nm1 = 0.f, s_n = sp, c_nm1 = 1.f, c_n = cp;
#pragma unroll
    for (int n = 1; n <= 8; n++) {
        ef[n - 1] = a * s_n * fc;
        dd[n - 1] = a * fc * ((float)n * PI_F * INV_R * c_n - s_n * invL)
                  + a * s_n * fcp * INV_R;
        if (n < 8) {
            float sn2 = twoc * s_n - s_nm1; s_nm1 = s_n; s_n = sn2;
            float cn2 = twoc * c_n - c_nm1; c_nm1 = c_n; c_n = cn2;
        }
    }
}

// Fused setup: blocks [0,nbt) build tables, [nbt,nbt+nbn) embed nodes,
// [nbt+nbn, ...) build edge histograms + urec. All three independent.
__global__ __launch_bounds__(256) void k_setup(
    const float* __restrict__ W1a, const float* __restrict__ W2a,
    const float* __restrict__ W1b, const float* __restrict__ W2b,
    float* __restrict__ twa, float* __restrict__ dta,
    float* __restrict__ twb, float* __restrict__ dtb,
    float* __restrict__ total,
    const float* __restrict__ attrs, const float* __restrict__ ae,
    const float* __restrict__ Wemb, float* __restrict__ h,
    unsigned short* __restrict__ hA1_bf, float* __restrict__ e0,
    float* __restrict__ A1, float* __restrict__ forces, int N,
    const float* __restrict__ pos, const float* __restrict__ shifts,
    const int* __restrict__ ei, int E,
    int* __restrict__ hist_r, int* __restrict__ hist_s,
    float4* __restrict__ urec,
    int nbt, int nbn)
{
    int b = blockIdx.x;
    if (b < nbt) {
        // ---------------- table path ----------------
        if (b == 0 && threadIdx.x < 32) total[threadIdx.x] = 0.f;
        int gid = b * 256 + threadIdx.x;
        if (gid >= (TBL + 1) * 16) return;
        int cg = gid & 7;
        int l  = (gid >> 3) & 1;
        int t  = gid >> 4;
        float u = fmaxf((float)t / (float)TBL, 1e-4f);
        float L = u * R_MAX;
        float invL = 1.f / L;
        float ef[8], dd[8], efu[8];
        radial_ef_d(u, invL, ef, dd);
#pragma unroll
        for (int k = 0; k < 8; k++) efu[k] = dd[k] * R_MAX;
        const float* W1 = l ? W1b : W1a;
        const float* W2 = l ? W2b : W2a;
        float*     tw_o = l ? twb : twa;
        float*     dt_o = l ? dtb : dta;
        float tw[4] = {0.f, 0.f, 0.f, 0.f};
        float dt[4] = {0.f, 0.f, 0.f, 0.f};
        for (int j = 0; j < 64; j++) {
            float s1 = 0.f, du = 0.f;
#pragma unroll
            for (int k = 0; k < 8; k++) {
                float w = W1[k * 64 + j];
                s1 += ef[k] * w; du += efu[k] * w;
            }
            float sg  = sigm(s1);
            float act = s1 * sg;
            float dj  = sg * (1.f + s1 * (1.f - sg)) * du;
            const float* w2 = W2 + j * 96 + cg * 4;
#pragma unroll
            for (int q = 0; q < 4; q++) {
                tw[q] += act * w2[q];
                dt[q] += dj * w2[q];
            }
        }
#pragma unroll
        for (int q = 0; q < 4; q++) {
            tw_o[(size_t)t * 32 + cg * 4 + q] = tw[q];
            dt_o[(size_t)t * 32 + cg * 4 + q] = dt[q];
        }
    } else if (b < nbt + nbn) {
        // ---------------- embed path ----------------
        int i = (b - nbt) * 256 + threadIdx.x;
        if (i >= N) return;
        float a[10];
#pragma unroll
        for (int k = 0; k < 10; k++) a[k] = attrs[i * 10 + k];
        float e = 0.f;
#pragma unroll
        for (int k = 0; k < 10; k++) e += a[k] * ae[k];
        e0[i] = e;
        float v[32];
#pragma unroll
        for (int c = 0; c < 32; c++) {
            float t = 0.f;
#pragma unroll
            for (int k = 0; k < 10; k++) t += a[k] * Wemb[k * 32 + c];
            v[c] = t;
            h[i * 32 + c] = t;
            A1[i * 32 + c] = 0.f;
        }
        store_bf_row(hA1_bf + (size_t)i * 64, v);   // h half of packed row
        forces[3*i+0] = 0.f; forces[3*i+1] = 0.f; forces[3*i+2] = 0.f;
        hist_r[i] = 0; hist_s[i] = 0;
    } else {
        // ---------------- build path ----------------
        int e = (b - nbt - nbn) * 256 + threadIdx.x;
        if (e >= E) return;
        int s = ei[e], r = ei[E + e];
        float vx = pos[3*r+0] - pos[3*s+0] + shifts[3*e+0];
        float vy = pos[3*r+1] - pos[3*s+1] + shifts[3*e+1];
        float vz = pos[3*r+2] - pos[3*s+2] + shifts[3*e+2];
        float ss2 = vx*vx + vy*vy + vz*vz;
        float L = sqrtf(fmaxf(ss2, 1e-12f));
        if (L * INV_R < 1.f) {
            atomicAdd(&hist_r[r], 1);
            atomicAdd(&hist_s[s], 1);
            urec[e] = make_float4(vx, vy, vz,
                      __uint_as_float(((unsigned)s << 16) | (unsigned)r));
        } else {
            urec[e] = make_float4(0.f, 0.f, 0.f, __uint_as_float(0xFFFFFFFFu));
        }
    }
}

// hierarchical scan stage A: per-block chunk sums (both hists in one grid)
__global__ __launch_bounds__(256) void k_scan_a(
    const int* __restrict__ hist_r, const int* __restrict__ hist_s,
    int n, int nb, int* __restrict__ part)
{
    __shared__ int red[256];
    int b = blockIdx.x;
    const int* hist = (b < nb) ? hist_r : hist_s;
    int cb = (b < nb) ? b : b - nb;
    int base = cb * SCHUNK;
    int t = threadIdx.x;
    int i0 = base + 2 * t, i1 = i0 + 1;
    int sum = 0;
    if (i0 < n) sum += hist[i0];
    if (i1 < n) sum += hist[i1];
    red[t] = sum;
    __syncthreads();
    for (int off = 128; off > 0; off >>= 1) {
        if (t < off) red[t] += red[t + off];
        __syncthreads();
    }
    if (t == 0) part[b] = red[0];
}

// stage B: exclusive scan of the block sums (in LDS, one block); writes cnt
__global__ __launch_bounds__(256) void k_scan_b(
    const int* __restrict__ part, int nb, int* __restrict__ bbase,
    int* __restrict__ cnt)
{
    __shared__ int buf[512];   // 2*nb <= 512
    int t = threadIdx.x;
    for (int k = t; k < 2 * nb; k += 256) buf[k] = part[k];
    __syncthreads();
    if (t < 2) {
        int base = t * nb;
        int run = 0;
        for (int k = 0; k < nb; k++) {
            int v = buf[base + k];
            buf[base + k] = run;
            run += v;
        }
        if (t == 0) *cnt = run;   // total active
    }
    __syncthreads();
    for (int k = t; k < 2 * nb; k += 256) bbase[k] = buf[k];
}

// stage C: per-chunk exclusive scan + block base -> cursor arrays
__global__ __launch_bounds__(256) void k_scan_c(
    const int* __restrict__ hist_r, const int* __restrict__ hist_s,
    int n, int nb, const int* __restrict__ bbase,
    int* __restrict__ cur_r, int* __restrict__ cur_s)
{
    __shared__ int sc[256];
    int b = blockIdx.x;
    const int* hist = (b < nb) ? hist_r : hist_s;
    int*       cur  = (b < nb) ? cur_r : cur_s;
    int cb = (b < nb) ? b : b - nb;
    int base = cb * SCHUNK;
    int t = threadIdx.x;
    int i0 = base + 2 * t, i1 = i0 + 1;
    int e0 = (i0 < n) ? hist[i0] : 0;
    int e1 = (i1 < n) ? hist[i1] : 0;
    int ts = e0 + e1;
    sc[t] = ts;
    __syncthreads();
    for (int off = 1; off < 256; off <<= 1) {
        int v = (t >= off) ? sc[t - off] : 0;
        __syncthreads();
        sc[t] += v;
        __syncthreads();
    }
    int excl = sc[t] - ts + bbase[b];
    if (i0 < n) cur[i0] = excl;
    if (i1 < n) cur[i1] = excl + e0;
}

// receiver-side scatter only: 1 atomic chain per edge, 2 edges per thread
// (ILP: both atomic round-trips in flight). Saves rp per edge (coalesced)
// so the sender pass can build map_sr without a second atomic here.
__global__ __launch_bounds__(256) void k_sort_r(
    const float4* __restrict__ urec, int E,
    int* __restrict__ cur_r, float4* __restrict__ rrec,
    int* __restrict__ rp_of_e)
{
    int base = blockIdx.x * 512;
    int t = threadIdx.x;
    int e0 = base + t, e1 = base + 256 + t;
    float4 u0, u1;
    unsigned p0 = 0xFFFFFFFFu, p1 = 0xFFFFFFFFu;
    if (e0 < E) { u0 = urec[e0]; p0 = __float_as_uint(u0.w); }
    if (e1 < E) { u1 = urec[e1]; p1 = __float_as_uint(u1.w); }
    int rp0 = -1, rp1 = -1;
    if (p0 != 0xFFFFFFFFu) rp0 = atomicAdd(&cur_r[p0 & 0xffffu], 1);
    if (p1 != 0xFFFFFFFFu) rp1 = atomicAdd(&cur_r[p1 & 0xffffu], 1);
    if (rp0 >= 0) { rrec[rp0] = u0; rp_of_e[e0] = rp0; }
    if (rp1 >= 0) { rrec[rp1] = u1; rp_of_e[e1] = rp1; }
}

// mlp pass 1 (blocks [0,nb_g)) FUSED with the sender-side scatter
// (blocks [nb_g, nb_g+nbs2)): srec/map_sr aren't consumed until k_mlp3fb,
// so the sort_s latency hides behind mlp1's gather work on other CUs.
__global__ __launch_bounds__(256) void k_mlp1_sorts(
    const float4* __restrict__ rec, const int* __restrict__ cnt,
    const float* __restrict__ tw_tbl, const unsigned short* __restrict__ feat,
    float* __restrict__ acc,
    const float4* __restrict__ urec, int E, int* __restrict__ cur_s,
    float4* __restrict__ srec, int* __restrict__ map_sr,
    const int* __restrict__ rp_of_e, int nb_g)
{
    __shared__ float m_lds[256][33];
    __shared__ int   dst_lds[256];

    int b = blockIdx.x;
    int tid = threadIdx.x;

    if (b >= nb_g) {
        // ------------- sender-side scatter (sort_s), 512 edges/block -------------
        int base = (b - nb_g) * 512;
        int e0 = base + tid, e1 = base + 256 + tid;
        float4 u0, u1;
        unsigned p0 = 0xFFFFFFFFu, p1 = 0xFFFFFFFFu;
        if (e0 < E) { u0 = urec[e0]; p0 = __float_as_uint(u0.w); }
        if (e1 < E) { u1 = urec[e1]; p1 = __float_as_uint(u1.w); }
        int sp0 = -1, sp1 = -1;
        if (p0 != 0xFFFFFFFFu) sp0 = atomicAdd(&cur_s[p0 >> 16], 1);
        if (p1 != 0xFFFFFFFFu) sp1 = atomicAdd(&cur_s[p1 >> 16], 1);
        if (sp0 >= 0) {
            unsigned r = p0 & 0xffffu, s = p0 >> 16;
            srec[sp0] = make_float4(u0.x, u0.y, u0.z,
                        __uint_as_float((r << 16) | s));
            map_sr[sp0] = rp_of_e[e0];
        }
        if (sp1 >= 0) {
            unsigned r = p1 & 0xffffu, s = p1 >> 16;
            srec[sp1] = make_float4(u1.x, u1.y, u1.z,
                        __uint_as_float((r << 16) | s));
            map_sr[sp1] = rp_of_e[e1];
        }
        return;
    }

    // ------------- mlp pass 1 over rrec -------------
    int na = *cnt;
    int stride = nb_g * 256;
    for (int base = b * 256; base < na; base += stride) {
        int i = base + tid;
        int dst = -1;
        if (i < na) {
            float4 rv = rec[i];
            unsigned pk = __float_as_uint(rv.w);
            int gn = pk >> 16;
            dst = (int)(pk & 0xffffu);
            float ss2 = rv.x * rv.x + rv.y * rv.y + rv.z * rv.z;
            float L = sqrtf(fmaxf(ss2, 1e-12f));
            float x = fminf(L * (INV_R * (float)TBL), (float)TBL - 1e-3f);
            int   i0 = (int)x;
            float f  = x - (float)i0;

            float fbuf[32];
            load_bf_row(feat + (size_t)gn * 64, fbuf);

            const float4* r0 = (const float4*)(tw_tbl + (size_t)i0 * 32);
            const float4* r1 = r0 + 8;
#pragma unroll
            for (int q = 0; q < 8; q++) {
                float4 a = r0[q], bb = r1[q];
                m_lds[tid][4 * q + 0] = fbuf[4*q+0] * (a.x + f * (bb.x - a.x));
                m_lds[tid][4 * q + 1] = fbuf[4*q+1] * (a.y + f * (bb.y - a.y));
                m_lds[tid][4 * q + 2] = fbuf[4*q+2] * (a.z + f * (bb.z - a.z));
                m_lds[tid][4 * q + 3] = fbuf[4*q+3] * (a.w + f * (bb.w - a.w));
            }
        }
        dst_lds[tid] = dst;
        __syncthreads();

        int grp = tid >> 5;
        int c   = tid & 31;
        int b32 = grp * 32;
        int cur = -1; float run = 0.f;
        for (int k = 0; k < 32; k++) {
            int d = dst_lds[b32 + k];
            if (d != cur) {
                if (cur >= 0) unsafeAtomicAdd(&acc[(size_t)cur * 32 + c], run);
                cur = d;
                run = (d >= 0) ? m_lds[b32 + k][c] : 0.f;
            } else if (d >= 0) {
                run += m_lds[b32 + k][c];
            }
        }
        if (cur >= 0) unsafeAtomicAdd(&acc[(size_t)cur * 32 + c], run);
        __syncthreads();
    }
}

// table-driven edge MLP (pass 2 over rrec): m = bf16feat[gather]*lerp(tw)
__global__ __launch_bounds__(256) void k_edge_mlp_t(
    const float4* __restrict__ rec, const int* __restrict__ cnt,
    const float* __restrict__ tw_tbl, const unsigned short* __restrict__ feat,
    int fstride, float* __restrict__ acc)
{
    __shared__ float m_lds[256][33];
    __shared__ int   dst_lds[256];

    int na = *cnt;
    int tid = threadIdx.x;
    int stride = gridDim.x * 256;

    for (int base = blockIdx.x * 256; base < na; base += stride) {
        int i = base + tid;
        int dst = -1;
        if (i < na) {
            float4 rv = rec[i];
            unsigned pk = __float_as_uint(rv.w);
            int gn = pk >> 16;
            dst = (int)(pk & 0xffffu);
            float ss2 = rv.x * rv.x + rv.y * rv.y + rv.z * rv.z;
            float L = sqrtf(fmaxf(ss2, 1e-12f));
            float x = fminf(L * (INV_R * (float)TBL), (float)TBL - 1e-3f);
            int   i0 = (int)x;
            float f  = x - (float)i0;

            float fbuf[32];
            load_bf_row(feat + (size_t)gn * fstride, fbuf);

            const float4* r0 = (const float4*)(tw_tbl + (size_t)i0 * 32);
            const float4* r1 = r0 + 8;
#pragma unroll
            for (int q = 0; q < 8; q++) {
                float4 a = r0[q], b = r1[q];
                m_lds[tid][4 * q + 0] = fbuf[4*q+0] * (a.x + f * (b.x - a.x));
                m_lds[tid][4 * q + 1] = fbuf[4*q+1] * (a.y + f * (b.y - a.y));
                m_lds[tid][4 * q + 2] = fbuf[4*q+2] * (a.z + f * (b.z - a.z));
                m_lds[tid][4 * q + 3] = fbuf[4*q+3] * (a.w + f * (b.w - a.w));
            }
        }
        dst_lds[tid] = dst;
        __syncthreads();

        int grp = tid >> 5;
        int c   = tid & 31;
        int b32 = grp * 32;
        int cur = -1; float run = 0.f;
        for (int k = 0; k < 32; k++) {
            int d = dst_lds[b32 + k];
            if (d != cur) {
                if (cur >= 0) unsafeAtomicAdd(&acc[(size_t)cur * 32 + c], run);
                cur = d;
                run = (d >= 0) ? m_lds[b32 + k][c] : 0.f;
            } else if (d >= 0) {
                run += m_lds[b32 + k][c];
            }
        }
        if (cur >= 0) unsafeAtomicAdd(&acc[(size_t)cur * 32 + c], run);
        __syncthreads();
    }
}

// node1: finalize A1, write bf16 A1-half of packed row, zero A2g2 row
__global__ __launch_bounds__(256) void k_node1(
    const float* __restrict__ h, float* __restrict__ A1,
    unsigned short* __restrict__ hA1_bf,
    const float* __restrict__ Wr1, float* __restrict__ e1,
    float* __restrict__ A2g2, int N)
{
    int i = blockIdx.x * blockDim.x + threadIdx.x;
    if (i >= N) return;
    float dot = 0.f;
    float v[32];
#pragma unroll
    for (int c = 0; c < 32; c++) {
        float t = A1[i * 32 + c] * INV_AVG + h[i * 32 + c];
        v[c] = t;
        A1[i * 32 + c] = t;
        A2g2[i * 32 + c] = 0.f;
        dot += t * Wr1[c];
    }
    e1[i] = dot;
    store_bf_row(hA1_bf + (size_t)i * 64 + 32, v);   // A1 half of packed row
}

// node2: A2 -> energies + g2 (in place) + bf16 mirror; zeroes g1 row
__global__ __launch_bounds__(256) void k_node2(
    float* __restrict__ A2g2, unsigned short* __restrict__ g2_bf,
    const float* __restrict__ A1,
    const float* __restrict__ Wm1, const float* __restrict__ Wm2,
    const float* __restrict__ e0, const float* __restrict__ e1,
    float* __restrict__ node_e, float* __restrict__ total,
    float* __restrict__ g1, const int* __restrict__ batch, int N)
{
    __shared__ float bins[32];
    if (threadIdx.x < 32) bins[threadIdx.x] = 0.f;
    __syncthreads();
    int i = blockIdx.x * blockDim.x + threadIdx.x;
    if (i < N) {
        float A2[32];
#pragma unroll
        for (int c = 0; c < 32; c++) {
            A2[c] = A2g2[i * 32 + c] * INV_AVG + A1[i * 32 + c];
            g1[i * 32 + c] = 0.f;
        }
        float z[16];
#pragma unroll
        for (int k = 0; k < 16; k++) {
            float v = 0.f;
#pragma unroll
            for (int c = 0; c < 32; c++) v += A2[c] * Wm1[c * 16 + k];
            z[k] = v;
        }
        float e2 = 0.f;
        float wk[16];
#pragma unroll
        for (int k = 0; k < 16; k++) {
            float sg = sigm(z[k]);
            float m2 = Wm2[k];
            e2 += z[k] * sg * m2;
            wk[k] = m2 * sg * (1.f + z[k] * (1.f - sg));  // Wm2 * silu'(z)
        }
        float g2v[32];
#pragma unroll
        for (int c = 0; c < 32; c++) {
            float v = 0.f;
#pragma unroll
            for (int k = 0; k < 16; k++) v += Wm1[c * 16 + k] * wk[k];
            g2v[c] = v;
            A2g2[i * 32 + c] = v;                          // g2 in place
        }
        store_bf_row(g2_bf + (size_t)i * 32, g2v);
        float ne = e0[i] + e1[i] + e2;
        node_e[i] = ne;
        atomicAdd(&bins[batch[i]], ne);
    }
    __syncthreads();
    if (threadIdx.x < 32) unsafeAtomicAdd(&total[threadIdx.x], bins[threadIdx.x]);
}

// mlp pass 3 FUSED with force branch-b (over srec).
__global__ __launch_bounds__(256) void k_mlp3fb(
    const float4* __restrict__ rec, const int* __restrict__ cnt,
    const float* __restrict__ tw_tbl, const float* __restrict__ dt_tbl,
    const unsigned short* __restrict__ g2_bf,
    const unsigned short* __restrict__ hA1_bf,
    const int* __restrict__ map_sr,
    float* __restrict__ g1acc, float* __restrict__ dotb_buf)
{
    __shared__ float m_lds[256][33];
    __shared__ int   dst_lds[256];

    int na = *cnt;
    int tid = threadIdx.x;
    int stride = gridDim.x * 256;

    for (int base = blockIdx.x * 256; base < na; base += stride) {
        int i = base + tid;
        int dst = -1;
        if (i < na) {
            float4 rv = rec[i];
            unsigned pk = __float_as_uint(rv.w);
            int r = (int)(pk >> 16);       // gather node (receiver)
            dst = (int)(pk & 0xffffu);     // scatter node (sender)
            float ss2 = rv.x * rv.x + rv.y * rv.y + rv.z * rv.z;
            float L = sqrtf(fmaxf(ss2, 1e-12f));
            float x = fminf(L * (INV_R * (float)TBL), (float)TBL - 1e-3f);
            int   i0 = (int)x;
            float f  = x - (float)i0;

            float gb[32], ab[32];
            load_bf_row(g2_bf + (size_t)r * 32, gb);            // random 64B
            load_bf_row(hA1_bf + (size_t)dst * 64 + 32, ab);    // sorted, L1-hot

            const float4* r0 = (const float4*)(tw_tbl + (size_t)i0 * 32);
            const float4* r1 = r0 + 8;
            const float4* d0 = (const float4*)(dt_tbl + (size_t)i0 * 32);
            const float4* d1 = d0 + 8;
            float dotb = 0.f;
#pragma unroll
            for (int q = 0; q < 8; q++) {
                float4 a = r0[q], b = r1[q], da = d0[q], db = d1[q];
                float t0 = a.x + f * (b.x - a.x);
                float t1 = a.y + f * (b.y - a.y);
                float t2 = a.z + f * (b.z - a.z);
                float t3 = a.w + f * (b.w - a.w);
                m_lds[tid][4*q+0] = gb[4*q+0] * t0;
                m_lds[tid][4*q+1] = gb[4*q+1] * t1;
                m_lds[tid][4*q+2] = gb[4*q+2] * t2;
                m_lds[tid][4*q+3] = gb[4*q+3] * t3;
                dotb += gb[4*q+0] * ab[4*q+0] * (da.x + f * (db.x - da.x))
                      + gb[4*q+1] * ab[4*q+1] * (da.y + f * (db.y - da.y))
                      + gb[4*q+2] * ab[4*q+2] * (da.z + f * (db.z - da.z))
                      + gb[4*q+3] * ab[4*q+3] * (da.w + f * (db.w - da.w));
            }
            dotb_buf[map_sr[i]] = dotb;    // random 4B; consumed by force_ra
        }
        dst_lds[tid] = dst;
        __syncthreads();

        int grp = tid >> 5;
        int c   = tid & 31;
        int b32 = grp * 32;
        int cur = -1; float run = 0.f;
        for (int k = 0; k < 32; k++) {
            int d = dst_lds[b32 + k];
            if (d != cur) {
                if (cur >= 0) unsafeAtomicAdd(&g1acc[(size_t)cur * 32 + c], run);
                cur = d;
                run = (d >= 0) ? m_lds[b32 + k][c] : 0.f;
            } else if (d >= 0) {
                run += m_lds[b32 + k][c];
            }
        }
        if (cur >= 0) unsafeAtomicAdd(&g1acc[(size_t)cur * 32 + c], run);
        __syncthreads();
    }
}

// force pass 1 (receiver-sorted): branch-a dot with INLINE g1 finalize.
__global__ __launch_bounds__(256) void k_force_ra(
    const float4* __restrict__ rec, const int* __restrict__ cnt,
    const float* __restrict__ dta,
    const unsigned short* __restrict__ hA1_bf,
    const float* __restrict__ g1acc, const float* __restrict__ g2,
    const float* __restrict__ Wr1, const float* __restrict__ dotb_buf,
    float* __restrict__ forces, float* __restrict__ sc_buf)
{
    __shared__ float f_lds[256][4];
    __shared__ int   dst_lds[256];

    int na = *cnt;
    int tid = threadIdx.x;
    int stride = gridDim.x * 256;
    const float4* w4 = (const float4*)Wr1;

    for (int base = blockIdx.x * 256; base < na; base += stride) {
        int i = base + tid;
        int dstf = -1;
        float fx = 0.f, fy = 0.f, fz = 0.f;

        if (i < na) {
            float4 rv = rec[i];
            unsigned pk = __float_as_uint(rv.w);
            int r = (int)(pk & 0xffffu);
            int s = (int)(pk >> 16);
            float vx = rv.x, vy = rv.y, vz = rv.z;
            float ss2 = vx * vx + vy * vy + vz * vz;
            float scv = 0.f;
            if (ss2 > 1e-12f) {          // else grad of maximum() is 0
                float L = sqrtf(ss2);
                float invL = 1.f / L;
                float x = fminf(L * (INV_R * (float)TBL), (float)TBL - 1e-3f);
                int   i0 = (int)x;
                float f  = x - (float)i0;

                float hb[32];
                load_bf_row(hA1_bf + (size_t)s * 64, hb);   // random 64B

                const float4* a0 = (const float4*)(dta + (size_t)i0 * 32);
                const float4* a1 = a0 + 8;
                const float4* pa = (const float4*)(g1acc + (size_t)r * 32);
                const float4* pc = (const float4*)(g2 + (size_t)r * 32);

                float dot = dotb_buf[i];                    // branch-b partial
#pragma unroll
                for (int q = 0; q < 8; q++) {
                    float4 ga = pa[q], gc = pc[q], wr = w4[q];
                    float4 t0 = a0[q], t1 = a1[q];
                    float g0 = ga.x * INV_AVG + gc.x + wr.x;  // inline node3
                    float g1v = ga.y * INV_AVG + gc.y + wr.y;
                    float g2v = ga.z * INV_AVG + gc.z + wr.z;
                    float g3 = ga.w * INV_AVG + gc.w + wr.w;
                    dot += g0 * hb[4*q+0] * (t0.x + f * (t1.x - t0.x))
                         + g1v * hb[4*q+1] * (t0.y + f * (t1.y - t0.y))
                         + g2v * hb[4*q+2] * (t0.z + f * (t1.z - t0.z))
                         + g3 * hb[4*q+3] * (t0.w + f * (t1.w - t0.w));
                }

                scv = INV_AVG * INV_R * dot * invL;        // dE/dL / L
                fx = -scv * vx; fy = -scv * vy; fz = -scv * vz;
                dstf = r;
            }
            sc_buf[i] = scv;             // coalesced; consumed by k_force_s2
        }
        f_lds[tid][0] = fx; f_lds[tid][1] = fy; f_lds[tid][2] = fz;
        dst_lds[tid] = dstf;
        __syncthreads();

        int grp = tid >> 5;
        int c   = tid & 31;
        if (c < 3) {
            int b32 = grp * 32;
            int cur = -1; float run = 0.f;
            for (int k = 0; k < 32; k++) {
                int d = dst_lds[b32 + k];
                if (d != cur) {
                    if (cur >= 0) unsafeAtomicAdd(&forces[3 * cur + c], run);
                    cur = d;
                    run = (d >= 0) ? f_lds[b32 + k][c] : 0.f;
                } else if (d >= 0) {
                    run += f_lds[b32 + k][c];
                }
            }
            if (cur >= 0) unsafeAtomicAdd(&forces[3 * cur + c], run);
        }
        __syncthreads();
    }
}

// force pass 2 (sender-sorted): cached scalar via srec->rrec map.
__global__ __launch_bounds__(256) void k_force_s2(
    const float4* __restrict__ rec, const int* __restrict__ cnt,
    const int* __restrict__ map_sr, const float* __restrict__ sc_buf,
    float* __restrict__ forces)
{
    __shared__ float f_lds[256][4];
    __shared__ int   dst_lds[256];

    int na = *cnt;
    int tid = threadIdx.x;
    int stride = gridDim.x * 256;

    for (int base = blockIdx.x * 256; base < na; base += stride) {
        int i = base + tid;
        int dstf = -1;
        float fx = 0.f, fy = 0.f, fz = 0.f;
        if (i < na) {
            float4 rv = rec[i];
            unsigned pk = __float_as_uint(rv.w);
            float scv = sc_buf[map_sr[i]];
            fx = scv * rv.x; fy = scv * rv.y; fz = scv * rv.z;
            dstf = (int)(pk & 0xffffu);   // own = sender
        }
        f_lds[tid][0] = fx; f_lds[tid][1] = fy; f_lds[tid][2] = fz;
        dst_lds[tid] = dstf;
        __syncthreads();

        int grp = tid >> 5;
        int c   = tid & 31;
        if (c < 3) {
            int b32 = grp * 32;
            int cur = -1; float run = 0.f;
            for (int k = 0; k < 32; k++) {
                int d = dst_lds[b32 + k];
                if (d != cur) {
                    if (cur >= 0) unsafeAtomicAdd(&forces[3 * cur + c], run);
                    cur = d;
                    run = (d >= 0) ? f_lds[b32 + k][c] : 0.f;
                } else if (d >= 0) {
                    run += f_lds[b32 + k][c];
                }
            }
            if (cur >= 0) unsafeAtomicAdd(&forces[3 * cur + c], run);
        }
        __syncthreads();
    }
}

extern "C" void kernel_launch(void* const* d_in, const int* in_sizes, int n_in,
                              void* d_out, int out_size, void* d_ws, size_t ws_size,
                              hipStream_t stream)
{
    const float* pos    = (const float*)d_in[0];
    const float* attrs  = (const float*)d_in[1];
    const float* shifts = (const float*)d_in[2];
    const float* ae     = (const float*)d_in[3];
    const float* Wemb   = (const float*)d_in[4];
    const float* W1a    = (const float*)d_in[5];
    const float* W2a    = (const float*)d_in[6];
    const float* Wr1    = (const float*)d_in[7];
    const float* W1b    = (const float*)d_in[8];
    const float* W2b    = (const float*)d_in[9];
    const float* Wm1    = (const float*)d_in[10];
    const float* Wm2    = (const float*)d_in[11];
    const int*   ei     = (const int*)d_in[12];
    const int*   batch  = (const int*)d_in[13];

    int N = in_sizes[13];
    int E = in_sizes[12] / 2;

    float* out    = (float*)d_out;
    float* total  = out;                 // 32
    float* node_e = out + 32;            // N
    float* forces = out + 32 + N;        // 3N

    float* ws = (float*)d_ws;
    size_t NC = (size_t)N * 32;
    float* h    = ws;            // N*32
    float* A1   = h  + NC;       // N*32
    float* A2g2 = A1 + NC;       // N*32 : A2 acc, then g2 in place
    float* g1   = A2g2 + NC;     // N*32 : acc (finalized inline in force_ra)
    float* e0   = g1 + NC;       // N
    float* e1   = e0 + N;        // N
    int* hist_r = (int*)(e1 + N);   // N
    int* hist_s = hist_r + N;       // N
    int* cur_r  = hist_s + N;       // N
    int* cur_s  = cur_r + N;        // N
    int* cnt    = cur_s + N;        // 1
    size_t ioff = ((size_t)(cnt + 1 - (int*)ws) + 3) & ~(size_t)3;
    float4* rrec = (float4*)(ws + ioff);   // E float4
    float4* srec = rrec + E;               // E float4
    float* tbl  = (float*)(srec + E);      // 4 tables of (TBL+1)*32
    size_t tstride = (size_t)(TBL + 1) * 32;
    float* twa = tbl;
    float* dta = twa + tstride;
    float* twb = dta + tstride;
    float* dtb = twb + tstride;
    int*   map_sr = (int*)(dtb + tstride);   // E
    float* sc_buf = (float*)(map_sr + E);    // E
    unsigned short* hA1_bf = (unsigned short*)(sc_buf + E);  // 2*NC ushorts
    unsigned short* g2_bf  = hA1_bf + 2 * NC;                // NC ushorts
    int* part  = (int*)(g2_bf + NC);                         // <=1024 ints
    int* bbase = part + 1024;                                // <=1024 ints
    float* dotb_buf = (float*)(bbase + 1024);                // E floats
    int*   rp_of_e  = (int*)(dotb_buf + E);                  // E ints
    // urec aliases A2g2+g1 (2*NC floats == E float4s when E == 16N);
    // those accumulators are zeroed by node1/node2 after urec is consumed
    // (last reader: the sort_s blocks inside k_mlp1_sorts, before node1)
    float4* urec = (float4*)A2g2;

    int nb_n  = (N + 255) / 256;
    int nb_e  = (E + 255) / 256;
    int nb_e2 = (E + 511) / 512;            // ILP-2 sort grids
    int nb_g  = nb_e < 2048 ? nb_e : 2048;  // grid-stride for edge passes
    int nb_t  = ((TBL + 1) * 16 + 255) / 256;
    int nbs   = (N + SCHUNK - 1) / SCHUNK;  // scan chunks per histogram

    k_setup<<<nb_t + nb_n + nb_e, 256, 0, stream>>>(
        W1a, W2a, W1b, W2b, twa, dta, twb, dtb, total,
        attrs, ae, Wemb, h, hA1_bf, e0, A1, forces, N,
        pos, shifts, ei, E, hist_r, hist_s, urec, nb_t, nb_n);
    k_scan_a<<<2 * nbs, 256, 0, stream>>>(hist_r, hist_s, N, nbs, part);
    k_scan_b<<<1, 256, 0, stream>>>(part, nbs, bbase, cnt);
    k_scan_c<<<2 * nbs, 256, 0, stream>>>(hist_r, hist_s, N, nbs, bbase,
                                          cur_r, cur_s);
    k_sort_r<<<nb_e2, 256, 0, stream>>>(urec, E, cur_r, rrec, rp_of_e);

    k_mlp1_sorts<<<nb_g + nb_e2, 256, 0, stream>>>(
        rrec, cnt, twa, hA1_bf, A1,
        urec, E, cur_s, srec, map_sr, rp_of_e, nb_g);
    k_node1<<<nb_n, 256, 0, stream>>>(h, A1, hA1_bf, Wr1, e1, A2g2, N);
    k_edge_mlp_t<<<nb_g, 256, 0, stream>>>(rrec, cnt, twb, hA1_bf + 32, 64, A2g2);
    k_node2<<<nb_n, 256, 0, stream>>>(A2g2, g2_bf, A1, Wm1, Wm2, e0, e1,
                                      node_e, total, g1, batch, N);
    k_mlp3fb<<<nb_g, 256, 0, stream>>>(srec, cnt, twb, dtb, g2_bf, hA1_bf,
                                       map_sr, g1, dotb_buf);
    k_force_ra<<<nb_g, 256, 0, stream>>>(rrec, cnt, dta, hA1_bf,
                                         g1, A2g2, Wr1, dotb_buf,
                                         forces, sc_buf);
    k_force_s2<<<nb_g, 256, 0, stream>>>(srec, cnt, map_sr, sc_buf, forces);
}